// Round 8
// baseline (725.455 us; speedup 1.0000x reference)
//
#include <hip/hip_runtime.h>
#include <math.h>

// Problem constants
constexpr int kN = 25000;
constexpr int kE = 400000;
constexpr int kTaug = kE + kN;        // CSR slots incl self-loops = 425000
constexpr int kTp = 425216;           // padded pe plane stride
constexpr int kIntents = 12;

typedef __attribute__((ext_vector_type(8))) short bf16x8s;   // 8 bf16 (4 VGPRs)
typedef __attribute__((ext_vector_type(4))) float f32x4;

__device__ __forceinline__ unsigned short f2bf(float f) {
    unsigned u = __builtin_bit_cast(unsigned, f);
    unsigned r = (u + 0x7FFFu + ((u >> 16) & 1u)) >> 16;     // RNE
    return (unsigned short)r;
}
__device__ __forceinline__ float bf2f(unsigned short h) {
    unsigned u = ((unsigned)h) << 16;
    return __builtin_bit_cast(float, u);
}

// DPP-based add from permuted lane (VALU pipe, replaces ds_swizzle).
template<int CTRL>
__device__ __forceinline__ float dpp_add(float x) {
    int xi = __builtin_bit_cast(int, x);
    int yi = __builtin_amdgcn_update_dpp(0, xi, CTRL, 0xF, 0xF, true);
    return x + __builtin_bit_cast(float, yi);
}

// ---------------- workspace layout (256B aligned) ----------------
constexpr size_t OFF_EAPART = 0;          // 1024*32 f32 = 131072
constexpr size_t OFF_EAMEAN = 131072;     // 32 f32 (pad 256)
constexpr size_t OFF_COUNTS = 131328;     // N i32
constexpr size_t OFF_OFFS   = 231424;     // N+1 i32
constexpr size_t OFF_CURSOR = 331520;     // N i32
constexpr size_t OFF_CSRSRC = 431616;     // Taug i32
constexpr size_t OFF_CSREID = 2131712;    // Taug i32
constexpr size_t OFF_CSRDST = 3831808;    // Taug i32
constexpr size_t OFF_PE     = 5531904;    // 4*kTp f32 = 6803456 (reused as P after aggr2)
constexpr size_t OFF_HA     = 12335360;   // N*64 f32
constexpr size_t OFF_HB     = 18735360;   // N*64 f32
constexpr size_t OFF_XL     = 25135360;   // N*256 f32
constexpr size_t OFF_XR     = 50735360;   // N*256 f32
constexpr size_t OFF_F1H    = 76335360;   // 4*4*64*8 u16 = 16384 (frag-swizzled We)
constexpr size_t OFF_F1L    = 76351744;
constexpr size_t OFF_F2H    = 76368128;
constexpr size_t OFF_F2L    = 76384512;   // end ~76.4 MB

// ---------------- edge_attr column mean ----------------
__global__ __launch_bounds__(256) void ea_colsum_part(const float* __restrict__ ea,
                                                      float* __restrict__ part)
{
    __shared__ float lds[256];
    const int tid = threadIdx.x;
    const int k = tid & 31, g = tid >> 5;
    float acc = 0.f;
    for (int r = blockIdx.x * 8 + g; r < kE; r += gridDim.x * 8)
        acc += ea[(size_t)r * 32 + k];
    lds[tid] = acc; __syncthreads();
    if (tid < 128) lds[tid] += lds[tid + 128]; __syncthreads();
    if (tid < 64)  lds[tid] += lds[tid + 64];  __syncthreads();
    if (tid < 32)  part[blockIdx.x * 32 + k] = lds[tid] + lds[tid + 32];
}

__global__ __launch_bounds__(256) void ea_colsum_final(const float* __restrict__ part,
                                                       float* __restrict__ ea_mean)
{
    __shared__ float lds[256];
    const int tid = threadIdx.x;
    const int k = tid & 31, g = tid >> 5;
    float acc = 0.f;
    for (int p = g; p < 1024; p += 8) acc += part[p * 32 + k];
    lds[tid] = acc; __syncthreads();
    if (tid < 128) lds[tid] += lds[tid + 128]; __syncthreads();
    if (tid < 64)  lds[tid] += lds[tid + 64];  __syncthreads();
    if (tid < 32)  ea_mean[k] = (lds[tid] + lds[tid + 32]) * (1.0f / (float)kE);
}

// ---------------- We -> frag-swizzled bf16 hi/lo (both layers) ----------------
// frag[nt][w][lane][j]: value = We[k*256 + c], c = w*64+nt*16+(lane&15), k = (lane>>4)*8+j
__global__ __launch_bounds__(256) void we_swizzle(const float* __restrict__ W1,
                                                  const float* __restrict__ W2,
                                                  unsigned short* __restrict__ f1h,
                                                  unsigned short* __restrict__ f1l,
                                                  unsigned short* __restrict__ f2h,
                                                  unsigned short* __restrict__ f2l)
{
    const int b = blockIdx.x;                 // 32 blocks: layer*16 + nt*4 + w
    const int layer = b >> 4, nt = (b >> 2) & 3, w = b & 3;
    const float* W = layer ? W2 : W1;
    unsigned short* H = layer ? f2h : f1h;
    unsigned short* L = layer ? f2l : f1l;
    const int tid = threadIdx.x;
    const int lane = tid & 63, jh = tid >> 6;  // jh 0..3 -> j = 2*jh, 2*jh+1
    const int c = w * 64 + nt * 16 + (lane & 15);
    const int kbase = (lane >> 4) * 8;
#pragma unroll
    for (int t = 0; t < 2; t++) {
        const int j = jh * 2 + t;
        const float f = W[(kbase + j) * 256 + c];
        const unsigned short hb = f2bf(f);
        const int idx = ((nt * 4 + w) * 64 + lane) * 8 + j;
        H[idx] = hb;
        L[idx] = f2bf(f - bf2f(hb));
    }
}

// ---------------- CSR build ----------------
__global__ __launch_bounds__(256) void init_counts(int* __restrict__ counts)
{
    int i = blockIdx.x * 256 + threadIdx.x;
    if (i < kN) counts[i] = 1;   // self-loop pre-counted
}

__global__ __launch_bounds__(256) void count_edges(const int* __restrict__ ei,
                                                   int* __restrict__ counts)
{
    int e = blockIdx.x * 256 + threadIdx.x;
    if (e < kE) atomicAdd(&counts[ei[kE + e]], 1);
}

__global__ __launch_bounds__(1024) void scan_kernel(const int* __restrict__ counts,
                                                    int* __restrict__ offsets,
                                                    int* __restrict__ cursor)
{
    __shared__ int lds[1024];
    const int tid = threadIdx.x;
    const int base = tid * 25;
    int local = 0;
#pragma unroll 5
    for (int i = 0; i < 25; i++) {
        int idx = base + i;
        if (idx < kN) local += counts[idx];
    }
    lds[tid] = local; __syncthreads();
    for (int d = 1; d < 1024; d <<= 1) {
        int t = (tid >= d) ? lds[tid - d] : 0;
        __syncthreads();
        lds[tid] += t;
        __syncthreads();
    }
    int run = lds[tid] - local;   // exclusive prefix
    for (int i = 0; i < 25; i++) {
        int idx = base + i;
        if (idx < kN) {
            offsets[idx] = run;
            cursor[idx]  = run;
            run += counts[idx];
        }
    }
    if (tid == 1023) offsets[kN] = lds[1023];
}

__global__ __launch_bounds__(256) void scatter_kernel(const int* __restrict__ ei,
                                                      int* __restrict__ cursor,
                                                      int* __restrict__ csr_src,
                                                      int* __restrict__ csr_eid,
                                                      int* __restrict__ csr_dst)
{
    int gid = blockIdx.x * 256 + threadIdx.x;
    if (gid < kE) {
        int s = ei[gid];
        int d = ei[kE + gid];
        int p = atomicAdd(&cursor[d], 1);
        csr_src[p] = s;
        csr_eid[p] = gid;
        csr_dst[p] = d;
    } else if (gid < kE + kN) {
        int n = gid - kE;
        int p = atomicAdd(&cursor[n], 1);
        csr_src[p] = n;
        csr_eid[p] = kE;   // sentinel: self-loop
        csr_dst[p] = n;
    }
}

// ---------------- small dense GEMM: out[M,KO] = A[M,KI]@W[KI,KO] + b ----------------
template<int KI, int KO, int RPB>
__global__ __launch_bounds__(256) void gemm_bias(const float* __restrict__ A,
                                                 const float* __restrict__ W,
                                                 const float* __restrict__ bias,
                                                 float* __restrict__ out, int M)
{
    constexpr int CG  = 256 / KO;   // column groups
    constexpr int RPT = RPB / CG;   // rows per thread
    __shared__ __align__(16) float a_lds[RPB * KI];
    const int tid = threadIdx.x;
    const int col = tid % KO;
    const int g   = tid / KO;
    const int row0 = blockIdx.x * RPB;

    const float4* Ab = (const float4*)(A + (size_t)row0 * KI);
    float4* L4 = (float4*)a_lds;
    constexpr int ELEM4 = RPB * KI / 4;
    for (int i = tid; i < ELEM4; i += 256) {
        int r = (i * 4) / KI;
        float4 v = make_float4(0.f, 0.f, 0.f, 0.f);
        if (row0 + r < M) v = Ab[i];
        L4[i] = v;
    }
    __syncthreads();

    float acc[RPT];
#pragma unroll
    for (int r = 0; r < RPT; r++) acc[r] = 0.f;
    const float* arow = a_lds + (size_t)(g * RPT) * KI;
    for (int k0 = 0; k0 < KI; k0 += 4) {
        float w0 = W[(k0 + 0) * KO + col];
        float w1 = W[(k0 + 1) * KO + col];
        float w2 = W[(k0 + 2) * KO + col];
        float w3 = W[(k0 + 3) * KO + col];
#pragma unroll
        for (int r = 0; r < RPT; r++) {
            const float4 a = *(const float4*)(arow + r * KI + k0);
            acc[r] += a.x * w0 + a.y * w1 + a.z * w2 + a.w * w3;
        }
    }
    const float bv = bias[col];
#pragma unroll
    for (int r = 0; r < RPT; r++) {
        int row = row0 + g * RPT + r;
        if (row < M) out[(size_t)row * KO + col] = acc[r] + bv;
    }
}

// ---------------- Pass 1: per-edge attention weights ----------------
// block = 256 threads = 4 waves (head = wave); 128 edges per block (4x 32-edge tiles).
// R7: pre-swizzled We frags (8x b128 loads), 4-tile loop amortizes prologue,
// exp deferred to one call per tile (select reduced logit via cndmask).
__global__ __launch_bounds__(256) void edge_logit_kernel(
    const float* __restrict__ xl, const float* __restrict__ xr,
    const float* __restrict__ ea, const float* __restrict__ eamean,
    const unsigned short* __restrict__ fragh, const unsigned short* __restrict__ fragl,
    const float* __restrict__ att,
    const int* __restrict__ csr_src, const int* __restrict__ csr_dst,
    const int* __restrict__ csr_eid, float* __restrict__ pe_out)
{
    constexpr int ROWS = 40;                       // padded ea row (shorts), 80B
    constexpr int EPP  = 257;                      // padded ep row (floats), 16-edge half
    __shared__ __align__(16) unsigned short ea_hi[32 * ROWS];
    __shared__ __align__(16) unsigned short ea_lo[32 * ROWS];
    __shared__ __align__(16) float ep_lds[16 * EPP];
    __shared__ int s_src[32], s_dst[32];
    const int tid  = threadIdx.x;
    const int w    = tid >> 6;
    const int lane = tid & 63;
    const int blk0 = blockIdx.x * 128;
    const int ntiles = min(4, (kTaug - blk0 + 31) / 32);

    // B fragments: 8 coalesced b128 loads from pre-swizzled tables
    bf16x8s bh[4], bl[4];
#pragma unroll
    for (int nt = 0; nt < 4; nt++) {
        const int idx = ((nt * 4 + w) * 64 + lane) * 8;
        bh[nt] = *(const bf16x8s*)&fragh[idx];
        bl[nt] = *(const bf16x8s*)&fragl[idx];
    }
    const float att_r = att[tid];
    const int aoff = (lane & 15) * ROWS + (lane >> 4) * 8;
    const int cbase = w * 64 + (lane & 15);
    const int rbase = (lane >> 4) * 4;

    for (int t = 0; t < ntiles; t++) {
        const int b0  = blk0 + t * 32;
        const int cnt = min(32, kTaug - b0);

        if (tid < cnt) {
            s_src[tid] = csr_src[b0 + tid];
            s_dst[tid] = csr_dst[b0 + tid];
        }
        {   // stage ea rows as bf16 hi/lo: 8 threads/edge
            const int j = tid >> 3, q = tid & 7;
            if (j < cnt) {
                const int eid = csr_eid[b0 + j];
                const float4* srcp = (eid < kE) ? (const float4*)(ea + (size_t)eid * 32)
                                                : (const float4*)eamean;
                const float4 f = srcp[q];
                const unsigned short h0 = f2bf(f.x), h1 = f2bf(f.y),
                                     h2 = f2bf(f.z), h3 = f2bf(f.w);
                const unsigned short g0 = f2bf(f.x - bf2f(h0)), g1 = f2bf(f.y - bf2f(h1)),
                                     g2 = f2bf(f.z - bf2f(h2)), g3 = f2bf(f.w - bf2f(h3));
                const unsigned long long ph =
                    (unsigned long long)h0 | ((unsigned long long)h1 << 16) |
                    ((unsigned long long)h2 << 32) | ((unsigned long long)h3 << 48);
                const unsigned long long pl =
                    (unsigned long long)g0 | ((unsigned long long)g1 << 16) |
                    ((unsigned long long)g2 << 32) | ((unsigned long long)g3 << 48);
                *(unsigned long long*)&ea_hi[j * ROWS + q * 4] = ph;
                *(unsigned long long*)&ea_lo[j * ROWS + q * 4] = pl;
            }
        }
        __syncthreads();

        // MFMA: ep[32][256] = ea @ We (3-product split-bf16), both row halves
        f32x4 accA[4], accB[4];
        {
            const bf16x8s ah0 = *(const bf16x8s*)&ea_hi[aoff];
            const bf16x8s ah1 = *(const bf16x8s*)&ea_hi[16 * ROWS + aoff];
            const bf16x8s al0 = *(const bf16x8s*)&ea_lo[aoff];
            const bf16x8s al1 = *(const bf16x8s*)&ea_lo[16 * ROWS + aoff];
#pragma unroll
            for (int nt = 0; nt < 4; nt++) {
                f32x4 a0 = {0.f, 0.f, 0.f, 0.f};
                a0 = __builtin_amdgcn_mfma_f32_16x16x32_bf16(ah0, bh[nt], a0, 0, 0, 0);
                a0 = __builtin_amdgcn_mfma_f32_16x16x32_bf16(ah0, bl[nt], a0, 0, 0, 0);
                a0 = __builtin_amdgcn_mfma_f32_16x16x32_bf16(al0, bh[nt], a0, 0, 0, 0);
                accA[nt] = a0;
                f32x4 a1 = {0.f, 0.f, 0.f, 0.f};
                a1 = __builtin_amdgcn_mfma_f32_16x16x32_bf16(ah1, bh[nt], a1, 0, 0, 0);
                a1 = __builtin_amdgcn_mfma_f32_16x16x32_bf16(ah1, bl[nt], a1, 0, 0, 0);
                a1 = __builtin_amdgcn_mfma_f32_16x16x32_bf16(al1, bh[nt], a1, 0, 0, 0);
                accB[nt] = a1;
            }
        }

        const int c0 = min(cnt, 16);
        const int c1 = cnt - c0;
        float keepc = 0.f;                         // reduced logit for edge==lane

#pragma unroll
        for (int half = 0; half < 2; half++) {
#pragma unroll
            for (int nt = 0; nt < 4; nt++) {
                const f32x4 a = half ? accB[nt] : accA[nt];
                const int cc = cbase + nt * 16;
#pragma unroll
                for (int r = 0; r < 4; r++)
                    ep_lds[(rbase + r) * EPP + cc] = a[r];
            }
            __syncthreads();

            const int ebase = half * 16;
            const int ecnt  = half ? c1 : c0;
            int i = 0;
            for (; i + 8 <= ecnt; i += 8) {
                const int e0 = ebase + i;
                float xls[8], c[8];
                int sv[8], dv[8];
#pragma unroll
                for (int u = 0; u < 8; u++) { sv[u] = s_src[e0 + u]; dv[u] = s_dst[e0 + u]; }
#pragma unroll
                for (int u = 0; u < 8; u++) xls[u] = xl[sv[u] * 256 + tid];
                float xrr[8];
#pragma unroll
                for (int u = 0; u < 8; u++) xrr[u] = xr[dv[u] * 256 + tid];
#pragma unroll
                for (int u = 0; u < 8; u++) {
                    float v = xls[u] + xrr[u] + ep_lds[((e0 + u) & 15) * EPP + tid];
                    v = fmaxf(v, 0.f) + 0.2f * fminf(v, 0.f);   // leaky_relu 0.2
                    c[u] = att_r * v;
                }
#pragma unroll
                for (int u = 0; u < 8; u++) c[u] = dpp_add<0xB1>(c[u]);
#pragma unroll
                for (int u = 0; u < 8; u++) c[u] = dpp_add<0x4E>(c[u]);
#pragma unroll
                for (int u = 0; u < 8; u++) c[u] = dpp_add<0x124>(c[u]);
#pragma unroll
                for (int u = 0; u < 8; u++) c[u] = dpp_add<0x128>(c[u]);
#pragma unroll
                for (int u = 0; u < 8; u++) c[u] += __shfl_xor(c[u], 16);
#pragma unroll
                for (int u = 0; u < 8; u++) c[u] += __shfl_xor(c[u], 32);
#pragma unroll
                for (int u = 0; u < 8; u++)
                    keepc = (lane == e0 + u) ? c[u] : keepc;   // defer exp
            }
            for (; i < ecnt; i++) {                // tail
                const int e = ebase + i;
                const float xls = xl[s_src[e] * 256 + tid];
                const float xrr = xr[s_dst[e] * 256 + tid];
                float v = xls + xrr + ep_lds[(e & 15) * EPP + tid];
                v = fmaxf(v, 0.f) + 0.2f * fminf(v, 0.f);
                float cc = att_r * v;
                cc = dpp_add<0xB1>(cc);
                cc = dpp_add<0x4E>(cc);
                cc = dpp_add<0x124>(cc);
                cc = dpp_add<0x128>(cc);
                cc += __shfl_xor(cc, 16);
                cc += __shfl_xor(cc, 32);
                keepc = (lane == e) ? cc : keepc;
            }
            __syncthreads();
        }

        if (lane < cnt)
            pe_out[w * kTp + b0 + lane] = __expf(keepc);   // one exp per tile
    }
}

// ---------------- Pass 2: per-node aggregate ----------------
__global__ __launch_bounds__(256) void gat_aggr_kernel(
    const float* __restrict__ xl, const float* __restrict__ pe,
    const int* __restrict__ csr_src, const int* __restrict__ offsets,
    const float* __restrict__ gbias, float* __restrict__ h_out)
{
    __shared__ float red[256];
    const int tid = threadIdx.x;
    const int w = tid >> 6;
    const int n = blockIdx.x;
    const int o0 = offsets[n], o1 = offsets[n + 1];
    const float* pep = pe + (size_t)w * kTp;

    float den = 0.f, acc = 0.f;
    int i = o0;
    for (; i + 8 <= o1; i += 8) {
        float pv[8], xv[8];
        int sv[8];
#pragma unroll
        for (int u = 0; u < 8; u++) pv[u] = pep[i + u];
#pragma unroll
        for (int u = 0; u < 8; u++) sv[u] = csr_src[i + u];
#pragma unroll
        for (int u = 0; u < 8; u++) xv[u] = xl[sv[u] * 256 + tid];
#pragma unroll
        for (int u = 0; u < 8; u++) {
            den += pv[u];
            acc += pv[u] * xv[u];
        }
    }
    for (; i < o1; i++) {
        const float p = pep[i];
        den += p;
        acc += p * xl[csr_src[i] * 256 + tid];
    }
    red[tid] = acc / den;
    __syncthreads();
    if (tid < 64) {
        float sres = red[tid] + red[tid + 64] + red[tid + 128] + red[tid + 192];
        h_out[n * 64 + tid] = fmaxf(0.25f * sres + gbias[tid], 0.f);
    }
}

// ---------------- node head: P[n][0:16]=h@W13[0:64], P[n][16:32]=h@W13[64:128] ----------------
__global__ __launch_bounds__(256) void node_head_kernel(
    const float* __restrict__ h, const float* __restrict__ intW,
    const float* __restrict__ impW, float* __restrict__ P)
{
    const int tid = threadIdx.x;
    const int w = tid >> 6, lane = tid & 63;
    const int row0 = blockIdx.x * 64 + w * 16;
    const int rr = lane & 15;             // A-row / B-col / C-col
    const int kg = lane >> 4;             // k-group

    bf16x8s Bh[2][2], Bl[2][2];
#pragma unroll
    for (int ct = 0; ct < 2; ct++) {
#pragma unroll
        for (int kk = 0; kk < 2; kk++) {
            const int kbase = ct * 64 + kk * 32 + kg * 8;
#pragma unroll
            for (int j = 0; j < 8; j++) {
                const int k = kbase + j;
                float wv;
                if (rr < 12)       wv = intW[k * 12 + rr];
                else if (rr == 12) wv = impW[k];
                else               wv = 0.f;
                const unsigned short hb = f2bf(wv);
                Bh[ct][kk][j] = (short)hb;
                Bl[ct][kk][j] = (short)f2bf(wv - bf2f(hb));
            }
        }
    }

    const int arow = min(row0 + rr, kN - 1);
    bf16x8s Ah[2], Al[2];
#pragma unroll
    for (int kk = 0; kk < 2; kk++) {
        const float4 f0 = *(const float4*)&h[arow * 64 + kk * 32 + kg * 8];
        const float4 f1 = *(const float4*)&h[arow * 64 + kk * 32 + kg * 8 + 4];
        const float fv[8] = {f0.x, f0.y, f0.z, f0.w, f1.x, f1.y, f1.z, f1.w};
#pragma unroll
        for (int j = 0; j < 8; j++) {
            const unsigned short hb = f2bf(fv[j]);
            Ah[kk][j] = (short)hb;
            Al[kk][j] = (short)f2bf(fv[j] - bf2f(hb));
        }
    }

#pragma unroll
    for (int ct = 0; ct < 2; ct++) {
        f32x4 acc = {0.f, 0.f, 0.f, 0.f};
#pragma unroll
        for (int kk = 0; kk < 2; kk++) {
            acc = __builtin_amdgcn_mfma_f32_16x16x32_bf16(Ah[kk], Bh[ct][kk], acc, 0, 0, 0);
            acc = __builtin_amdgcn_mfma_f32_16x16x32_bf16(Ah[kk], Bl[ct][kk], acc, 0, 0, 0);
            acc = __builtin_amdgcn_mfma_f32_16x16x32_bf16(Al[kk], Bh[ct][kk], acc, 0, 0, 0);
        }
        const int crow0 = kg * 4;
#pragma unroll
        for (int r = 0; r < 4; r++) {
            const int row = row0 + crow0 + r;
            if (row < kN) P[row * 32 + ct * 16 + rr] = acc[r];
        }
    }
}

// ---------------- edge out: Q = relu(ea)@W13[128:160]; out = Q + P_src + P_dst + b ----------------
__global__ __launch_bounds__(256) void edge_out_kernel(
    const float* __restrict__ ea, const int* __restrict__ ei,
    const float* __restrict__ P,
    const float* __restrict__ intW, const float* __restrict__ intb,
    const float* __restrict__ impW, const float* __restrict__ impb,
    float* __restrict__ out)
{
    constexpr int ROWS = 40;
    __shared__ __align__(16) unsigned short ehi[4][16 * ROWS];
    __shared__ __align__(16) unsigned short elo[4][16 * ROWS];
    const int tid = threadIdx.x;
    const int w = tid >> 6, lane = tid & 63;
    const int e0 = blockIdx.x * 64 + w * 16;
    const int rr = lane & 15, kg = lane >> 4;

    bf16x8s Bh, Bl;
#pragma unroll
    for (int j = 0; j < 8; j++) {
        const int k = 128 + kg * 8 + j;
        float wv;
        if (rr < 12)       wv = intW[k * 12 + rr];
        else if (rr == 12) wv = impW[k];
        else               wv = 0.f;
        const unsigned short hb = f2bf(wv);
        Bh[j] = (short)hb;
        Bl[j] = (short)f2bf(wv - bf2f(hb));
    }

    {
        const int j = lane >> 2, q = lane & 3;
        const float4* src = (const float4*)&ea[(size_t)(e0 + j) * 32 + q * 8];
        const float4 f0 = src[0], f1 = src[1];
        const float fv[8] = {fmaxf(f0.x, 0.f), fmaxf(f0.y, 0.f), fmaxf(f0.z, 0.f), fmaxf(f0.w, 0.f),
                             fmaxf(f1.x, 0.f), fmaxf(f1.y, 0.f), fmaxf(f1.z, 0.f), fmaxf(f1.w, 0.f)};
        unsigned long long ph0 = 0, pl0 = 0, ph1 = 0, pl1 = 0;
#pragma unroll
        for (int t = 0; t < 4; t++) {
            const unsigned short hb = f2bf(fv[t]);
            const unsigned short lb = f2bf(fv[t] - bf2f(hb));
            ph0 |= (unsigned long long)hb << (16 * t);
            pl0 |= (unsigned long long)lb << (16 * t);
        }
#pragma unroll
        for (int t = 0; t < 4; t++) {
            const unsigned short hb = f2bf(fv[4 + t]);
            const unsigned short lb = f2bf(fv[4 + t] - bf2f(hb));
            ph1 |= (unsigned long long)hb << (16 * t);
            pl1 |= (unsigned long long)lb << (16 * t);
        }
        *(unsigned long long*)&ehi[w][j * ROWS + q * 8]     = ph0;
        *(unsigned long long*)&ehi[w][j * ROWS + q * 8 + 4] = ph1;
        *(unsigned long long*)&elo[w][j * ROWS + q * 8]     = pl0;
        *(unsigned long long*)&elo[w][j * ROWS + q * 8 + 4] = pl1;
    }
    __syncthreads();

    const int aoff = rr * ROWS + kg * 8;
    const bf16x8s Ah = *(const bf16x8s*)&ehi[w][aoff];
    const bf16x8s Al = *(const bf16x8s*)&elo[w][aoff];
    f32x4 q = {0.f, 0.f, 0.f, 0.f};
    q = __builtin_amdgcn_mfma_f32_16x16x32_bf16(Ah, Bh, q, 0, 0, 0);
    q = __builtin_amdgcn_mfma_f32_16x16x32_bf16(Ah, Bl, q, 0, 0, 0);
    q = __builtin_amdgcn_mfma_f32_16x16x32_bf16(Al, Bh, q, 0, 0, 0);

    if (rr < 13) {
        const float bv = (rr < 12) ? intb[rr] : impb[0];
#pragma unroll
        for (int r = 0; r < 4; r++) {
            const int e = e0 + kg * 4 + r;
            const int s = ei[e], d = ei[kE + e];
            const float val = q[r] + P[s * 32 + rr] + P[d * 32 + 16 + rr] + bv;
            if (rr < 12) out[(size_t)e * 12 + rr] = val;
            else         out[(size_t)kE * 12 + e] = 1.f / (1.f + __expf(-val));
        }
    }
}

// ---------------- launch ----------------
extern "C" void kernel_launch(void* const* d_in, const int* in_sizes, int n_in,
                              void* d_out, int out_size, void* d_ws, size_t ws_size,
                              hipStream_t stream)
{
    (void)in_sizes; (void)n_in; (void)out_size; (void)ws_size;

    const float* x      = (const float*)d_in[0];
    const int*   ei     = (const int*)d_in[1];
    const float* ea     = (const float*)d_in[2];
    const float* emb_W  = (const float*)d_in[3];
    const float* emb_b  = (const float*)d_in[4];
    const float* g1_Wl  = (const float*)d_in[5];
    const float* g1_bl  = (const float*)d_in[6];
    const float* g1_Wr  = (const float*)d_in[7];
    const float* g1_br  = (const float*)d_in[8];
    const float* g1_We  = (const float*)d_in[9];
    const float* g1_att = (const float*)d_in[10];
    const float* g1_bias= (const float*)d_in[11];
    const float* g2_Wl  = (const float*)d_in[12];
    const float* g2_bl  = (const float*)d_in[13];
    const float* g2_Wr  = (const float*)d_in[14];
    const float* g2_br  = (const float*)d_in[15];
    const float* g2_We  = (const float*)d_in[16];
    const float* g2_att = (const float*)d_in[17];
    const float* g2_bias= (const float*)d_in[18];
    const float* int_W  = (const float*)d_in[19];
    const float* int_b  = (const float*)d_in[20];
    const float* imp_W  = (const float*)d_in[21];
    const float* imp_b  = (const float*)d_in[22];

    char* ws = (char*)d_ws;
    float* eapart  = (float*)(ws + OFF_EAPART);
    float* eamean  = (float*)(ws + OFF_EAMEAN);
    int*   counts  = (int*)  (ws + OFF_COUNTS);
    int*   offs    = (int*)  (ws + OFF_OFFS);
    int*   cursor  = (int*)  (ws + OFF_CURSOR);
    int*   csrsrc  = (int*)  (ws + OFF_CSRSRC);
    int*   csreid  = (int*)  (ws + OFF_CSREID);
    int*   csrdst  = (int*)  (ws + OFF_CSRDST);
    float* pe      = (float*)(ws + OFF_PE);
    float* h_a     = (float*)(ws + OFF_HA);
    float* h_b     = (float*)(ws + OFF_HB);
    float* xl      = (float*)(ws + OFF_XL);
    float* xr      = (float*)(ws + OFF_XR);
    unsigned short* f1h = (unsigned short*)(ws + OFF_F1H);
    unsigned short* f1l = (unsigned short*)(ws + OFF_F1L);
    unsigned short* f2h = (unsigned short*)(ws + OFF_F2H);
    unsigned short* f2l = (unsigned short*)(ws + OFF_F2L);
    float* P       = pe;                      // reuse pe region after last aggr
    float* outp    = (float*)d_out;

    constexpr int NB = (kTaug + 127) / 128;   // 3321 edge blocks (128 edges each)

    // edge_attr mean + We frag-swizzled bf16 splits
    ea_colsum_part<<<1024, 256, 0, stream>>>(ea, eapart);
    ea_colsum_final<<<1, 256, 0, stream>>>(eapart, eamean);
    we_swizzle<<<32, 256, 0, stream>>>(g1_We, g2_We, f1h, f1l, f2h, f2l);

    // CSR by destination (self-loops included)
    init_counts<<<(kN + 255) / 256, 256, 0, stream>>>(counts);
    count_edges<<<(kE + 255) / 256, 256, 0, stream>>>(ei, counts);
    scan_kernel<<<1, 1024, 0, stream>>>(counts, offs, cursor);
    scatter_kernel<<<(kE + kN + 255) / 256, 256, 0, stream>>>(ei, cursor, csrsrc, csreid, csrdst);

    // node embedding
    gemm_bias<128, 64, 32><<<(kN + 31) / 32, 256, 0, stream>>>(x, emb_W, emb_b, h_a, kN);

    // ---- GAT layer 1 ----
    gemm_bias<64, 256, 32><<<(kN + 31) / 32, 256, 0, stream>>>(h_a, g1_Wl, g1_bl, xl, kN);
    gemm_bias<64, 256, 32><<<(kN + 31) / 32, 256, 0, stream>>>(h_a, g1_Wr, g1_br, xr, kN);
    edge_logit_kernel<<<NB, 256, 0, stream>>>(xl, xr, ea, eamean, f1h, f1l, g1_att,
                                              csrsrc, csrdst, csreid, pe);
    gat_aggr_kernel<<<kN, 256, 0, stream>>>(xl, pe, csrsrc, offs, g1_bias, h_b);

    // ---- GAT layer 2 ----
    gemm_bias<64, 256, 32><<<(kN + 31) / 32, 256, 0, stream>>>(h_b, g2_Wl, g2_bl, xl, kN);
    gemm_bias<64, 256, 32><<<(kN + 31) / 32, 256, 0, stream>>>(h_b, g2_Wr, g2_br, xr, kN);
    edge_logit_kernel<<<NB, 256, 0, stream>>>(xl, xr, ea, eamean, f2h, f2l, g2_att,
                                              csrsrc, csrdst, csreid, pe);
    gat_aggr_kernel<<<kN, 256, 0, stream>>>(xl, pe, csrsrc, offs, g2_bias, h_a);

    // ---- edge heads (decomposed) ----
    node_head_kernel<<<(kN + 63) / 64, 256, 0, stream>>>(h_a, int_W, imp_W, P);
    edge_out_kernel<<<kE / 64, 256, 0, stream>>>(ea, ei, P, int_W, int_b, imp_W, imp_b, outp);
}

// Round 9
// 616.783 us; speedup vs baseline: 1.1762x; 1.1762x over previous
//
#include <hip/hip_runtime.h>
#include <math.h>

// Problem constants
constexpr int kN = 25000;
constexpr int kE = 400000;
constexpr int kTaug = kE + kN;        // CSR slots incl self-loops = 425000
constexpr int kTp = 425216;           // padded pe plane stride
constexpr int kIntents = 12;

typedef __attribute__((ext_vector_type(8))) short bf16x8s;   // 8 bf16 (4 VGPRs)
typedef __attribute__((ext_vector_type(4))) float f32x4;

__device__ __forceinline__ unsigned short f2bf(float f) {
    unsigned u = __builtin_bit_cast(unsigned, f);
    unsigned r = (u + 0x7FFFu + ((u >> 16) & 1u)) >> 16;     // RNE
    return (unsigned short)r;
}
__device__ __forceinline__ float bf2f(unsigned short h) {
    unsigned u = ((unsigned)h) << 16;
    return __builtin_bit_cast(float, u);
}

// DPP helpers (CTRL must be compile-time constant)
template<int CTRL>
__device__ __forceinline__ float dpp_mov(float x) {
    int yi = __builtin_amdgcn_update_dpp(0, __builtin_bit_cast(int, x), CTRL, 0xF, 0xF, true);
    return __builtin_bit_cast(float, yi);
}
template<int CTRL>
__device__ __forceinline__ float dpp_add(float x) {
    return x + dpp_mov<CTRL>(x);
}

// ---------------- workspace layout (256B aligned) ----------------
constexpr size_t OFF_EAPART = 0;          // 1024*32 f32 = 131072
constexpr size_t OFF_EAMEAN = 131072;     // 32 f32 (pad 256)
constexpr size_t OFF_COUNTS = 131328;     // N i32
constexpr size_t OFF_OFFS   = 231424;     // N+1 i32
constexpr size_t OFF_CURSOR = 331520;     // N i32
constexpr size_t OFF_CSRSRC = 431616;     // Taug i32
constexpr size_t OFF_CSREID = 2131712;    // Taug i32
constexpr size_t OFF_CSRDST = 3831808;    // Taug i32
constexpr size_t OFF_PE     = 5531904;    // 4*kTp f32 (reused as P after aggr2)
constexpr size_t OFF_HA     = 12335360;   // N*64 f32
constexpr size_t OFF_HB     = 18735360;   // N*64 f32
constexpr size_t OFF_XL     = 25135360;   // N*256 f32
constexpr size_t OFF_XR     = 50735360;   // N*256 f32
constexpr size_t OFF_F1H    = 76335360;   // 4*4*64*8 u16 = 16384 (frag-swizzled We)
constexpr size_t OFF_F1L    = 76351744;
constexpr size_t OFF_F2H    = 76368128;
constexpr size_t OFF_F2L    = 76384512;   // end ~76.4 MB

// ---------------- edge_attr column mean ----------------
__global__ __launch_bounds__(256) void ea_colsum_part(const float* __restrict__ ea,
                                                      float* __restrict__ part)
{
    __shared__ float lds[256];
    const int tid = threadIdx.x;
    const int k = tid & 31, g = tid >> 5;
    float acc = 0.f;
    for (int r = blockIdx.x * 8 + g; r < kE; r += gridDim.x * 8)
        acc += ea[(size_t)r * 32 + k];
    lds[tid] = acc; __syncthreads();
    if (tid < 128) lds[tid] += lds[tid + 128]; __syncthreads();
    if (tid < 64)  lds[tid] += lds[tid + 64];  __syncthreads();
    if (tid < 32)  part[blockIdx.x * 32 + k] = lds[tid] + lds[tid + 32];
}

__global__ __launch_bounds__(256) void ea_colsum_final(const float* __restrict__ part,
                                                       float* __restrict__ ea_mean)
{
    __shared__ float lds[256];
    const int tid = threadIdx.x;
    const int k = tid & 31, g = tid >> 5;
    float acc = 0.f;
    for (int p = g; p < 1024; p += 8) acc += part[p * 32 + k];
    lds[tid] = acc; __syncthreads();
    if (tid < 128) lds[tid] += lds[tid + 128]; __syncthreads();
    if (tid < 64)  lds[tid] += lds[tid + 64];  __syncthreads();
    if (tid < 32)  ea_mean[k] = (lds[tid] + lds[tid + 32]) * (1.0f / (float)kE);
}

// ---------------- We -> frag-swizzled bf16 hi/lo (both layers) ----------------
// frag[nt][w][lane][j]: value = We[k*256 + c], c = w*64+nt*16+(lane&15), k = (lane>>4)*8+j
__global__ __launch_bounds__(256) void we_swizzle(const float* __restrict__ W1,
                                                  const float* __restrict__ W2,
                                                  unsigned short* __restrict__ f1h,
                                                  unsigned short* __restrict__ f1l,
                                                  unsigned short* __restrict__ f2h,
                                                  unsigned short* __restrict__ f2l)
{
    const int b = blockIdx.x;                 // 32 blocks: layer*16 + nt*4 + w
    const int layer = b >> 4, nt = (b >> 2) & 3, w = b & 3;
    const float* W = layer ? W2 : W1;
    unsigned short* H = layer ? f2h : f1h;
    unsigned short* L = layer ? f2l : f1l;
    const int tid = threadIdx.x;
    const int lane = tid & 63, jh = tid >> 6;  // jh 0..3 -> j = 2*jh, 2*jh+1
    const int c = w * 64 + nt * 16 + (lane & 15);
    const int kbase = (lane >> 4) * 8;
#pragma unroll
    for (int t = 0; t < 2; t++) {
        const int j = jh * 2 + t;
        const float f = W[(kbase + j) * 256 + c];
        const unsigned short hb = f2bf(f);
        const int idx = ((nt * 4 + w) * 64 + lane) * 8 + j;
        H[idx] = hb;
        L[idx] = f2bf(f - bf2f(hb));
    }
}

// ---------------- CSR build ----------------
__global__ __launch_bounds__(256) void init_counts(int* __restrict__ counts)
{
    int i = blockIdx.x * 256 + threadIdx.x;
    if (i < kN) counts[i] = 1;   // self-loop pre-counted
}

__global__ __launch_bounds__(256) void count_edges(const int* __restrict__ ei,
                                                   int* __restrict__ counts)
{
    int e = blockIdx.x * 256 + threadIdx.x;
    if (e < kE) atomicAdd(&counts[ei[kE + e]], 1);
}

__global__ __launch_bounds__(1024) void scan_kernel(const int* __restrict__ counts,
                                                    int* __restrict__ offsets,
                                                    int* __restrict__ cursor)
{
    __shared__ int lds[1024];
    const int tid = threadIdx.x;
    const int base = tid * 25;
    int local = 0;
#pragma unroll 5
    for (int i = 0; i < 25; i++) {
        int idx = base + i;
        if (idx < kN) local += counts[idx];
    }
    lds[tid] = local; __syncthreads();
    for (int d = 1; d < 1024; d <<= 1) {
        int t = (tid >= d) ? lds[tid - d] : 0;
        __syncthreads();
        lds[tid] += t;
        __syncthreads();
    }
    int run = lds[tid] - local;   // exclusive prefix
    for (int i = 0; i < 25; i++) {
        int idx = base + i;
        if (idx < kN) {
            offsets[idx] = run;
            cursor[idx]  = run;
            run += counts[idx];
        }
    }
    if (tid == 1023) offsets[kN] = lds[1023];
}

__global__ __launch_bounds__(256) void scatter_kernel(const int* __restrict__ ei,
                                                      int* __restrict__ cursor,
                                                      int* __restrict__ csr_src,
                                                      int* __restrict__ csr_eid,
                                                      int* __restrict__ csr_dst)
{
    int gid = blockIdx.x * 256 + threadIdx.x;
    if (gid < kE) {
        int s = ei[gid];
        int d = ei[kE + gid];
        int p = atomicAdd(&cursor[d], 1);
        csr_src[p] = s;
        csr_eid[p] = gid;
        csr_dst[p] = d;
    } else if (gid < kE + kN) {
        int n = gid - kE;
        int p = atomicAdd(&cursor[n], 1);
        csr_src[p] = n;
        csr_eid[p] = kE;   // sentinel: self-loop
        csr_dst[p] = n;
    }
}

// ---------------- small dense GEMM: out[M,KO] = A[M,KI]@W[KI,KO] + b ----------------
template<int KI, int KO, int RPB>
__global__ __launch_bounds__(256) void gemm_bias(const float* __restrict__ A,
                                                 const float* __restrict__ W,
                                                 const float* __restrict__ bias,
                                                 float* __restrict__ out, int M)
{
    constexpr int CG  = 256 / KO;   // column groups
    constexpr int RPT = RPB / CG;   // rows per thread
    __shared__ __align__(16) float a_lds[RPB * KI];
    const int tid = threadIdx.x;
    const int col = tid % KO;
    const int g   = tid / KO;
    const int row0 = blockIdx.x * RPB;

    const float4* Ab = (const float4*)(A + (size_t)row0 * KI);
    float4* L4 = (float4*)a_lds;
    constexpr int ELEM4 = RPB * KI / 4;
    for (int i = tid; i < ELEM4; i += 256) {
        int r = (i * 4) / KI;
        float4 v = make_float4(0.f, 0.f, 0.f, 0.f);
        if (row0 + r < M) v = Ab[i];
        L4[i] = v;
    }
    __syncthreads();

    float acc[RPT];
#pragma unroll
    for (int r = 0; r < RPT; r++) acc[r] = 0.f;
    const float* arow = a_lds + (size_t)(g * RPT) * KI;
    for (int k0 = 0; k0 < KI; k0 += 4) {
        float w0 = W[(k0 + 0) * KO + col];
        float w1 = W[(k0 + 1) * KO + col];
        float w2 = W[(k0 + 2) * KO + col];
        float w3 = W[(k0 + 3) * KO + col];
#pragma unroll
        for (int r = 0; r < RPT; r++) {
            const float4 a = *(const float4*)(arow + r * KI + k0);
            acc[r] += a.x * w0 + a.y * w1 + a.z * w2 + a.w * w3;
        }
    }
    const float bv = bias[col];
#pragma unroll
    for (int r = 0; r < RPT; r++) {
        int row = row0 + g * RPT + r;
        if (row < M) out[(size_t)row * KO + col] = acc[r] + bv;
    }
}

// ---------------- Pass 1: per-edge attention weights (one 32-edge tile per block) ----------------
// R8: multi-value exchange reduce — 8 edge-sums reduced in 6 cross-lane steps
// (3 DS ops) instead of 8 butterflies (48 steps, 16 DS ops). Value-identity bits
// after combines at strides {1,2,32}: idx = (l&3)|((l&32)>>3); remaining strides
// {4,8} via full-coverage row rotations, {16} via shfl_xor.
__global__ __launch_bounds__(256) void edge_logit_kernel(
    const float* __restrict__ xl, const float* __restrict__ xr,
    const float* __restrict__ ea, const float* __restrict__ eamean,
    const unsigned short* __restrict__ fragh, const unsigned short* __restrict__ fragl,
    const float* __restrict__ att,
    const int* __restrict__ csr_src, const int* __restrict__ csr_dst,
    const int* __restrict__ csr_eid, float* __restrict__ pe_out)
{
    constexpr int ROWS = 40;                       // padded ea row (shorts), 80B
    constexpr int EPP  = 257;                      // padded ep row (floats), 16-edge half
    __shared__ __align__(16) unsigned short ea_hi[32 * ROWS];
    __shared__ __align__(16) unsigned short ea_lo[32 * ROWS];
    __shared__ __align__(16) float ep_lds[16 * EPP];
    __shared__ __align__(16) int s_src[32];
    __shared__ __align__(16) int s_dst[32];
    const int tid  = threadIdx.x;
    const int w    = tid >> 6;
    const int lane = tid & 63;
    const int b0   = blockIdx.x * 32;
    const int cnt  = min(32, kTaug - b0);

    // B fragments: 8 coalesced b128 loads from pre-swizzled tables
    bf16x8s bh[4], bl[4];
#pragma unroll
    for (int nt = 0; nt < 4; nt++) {
        const int idx = ((nt * 4 + w) * 64 + lane) * 8;
        bh[nt] = *(const bf16x8s*)&fragh[idx];
        bl[nt] = *(const bf16x8s*)&fragl[idx];
    }
    const float att_r = att[tid];
    const int aoff  = (lane & 15) * ROWS + (lane >> 4) * 8;
    const int cbase = w * 64 + (lane & 15);
    const int rbase = (lane >> 4) * 4;

    // stage indices + ea rows (clamped: tail tile reads duplicate valid slots)
    if (tid < 32) {
        const int p = min(b0 + tid, kTaug - 1);
        s_src[tid] = csr_src[p];
        s_dst[tid] = csr_dst[p];
    }
    {
        const int j = tid >> 3, q = tid & 7;
        const int eid = csr_eid[min(b0 + j, kTaug - 1)];
        const float4* srcp = (eid < kE) ? (const float4*)(ea + (size_t)eid * 32)
                                        : (const float4*)eamean;
        const float4 f = srcp[q];
        const unsigned short h0 = f2bf(f.x), h1 = f2bf(f.y),
                             h2 = f2bf(f.z), h3 = f2bf(f.w);
        const unsigned short g0 = f2bf(f.x - bf2f(h0)), g1 = f2bf(f.y - bf2f(h1)),
                             g2 = f2bf(f.z - bf2f(h2)), g3 = f2bf(f.w - bf2f(h3));
        const unsigned long long ph =
            (unsigned long long)h0 | ((unsigned long long)h1 << 16) |
            ((unsigned long long)h2 << 32) | ((unsigned long long)h3 << 48);
        const unsigned long long pl =
            (unsigned long long)g0 | ((unsigned long long)g1 << 16) |
            ((unsigned long long)g2 << 32) | ((unsigned long long)g3 << 48);
        *(unsigned long long*)&ea_hi[j * ROWS + q * 4] = ph;
        *(unsigned long long*)&ea_lo[j * ROWS + q * 4] = pl;
    }
    __syncthreads();

    // MFMA: ep[32][256] = ea @ We (3-product split-bf16), both row halves
    f32x4 accA[4], accB[4];
    {
        const bf16x8s ah0 = *(const bf16x8s*)&ea_hi[aoff];
        const bf16x8s ah1 = *(const bf16x8s*)&ea_hi[16 * ROWS + aoff];
        const bf16x8s al0 = *(const bf16x8s*)&ea_lo[aoff];
        const bf16x8s al1 = *(const bf16x8s*)&ea_lo[16 * ROWS + aoff];
#pragma unroll
        for (int nt = 0; nt < 4; nt++) {
            f32x4 a0 = {0.f, 0.f, 0.f, 0.f};
            a0 = __builtin_amdgcn_mfma_f32_16x16x32_bf16(ah0, bh[nt], a0, 0, 0, 0);
            a0 = __builtin_amdgcn_mfma_f32_16x16x32_bf16(ah0, bl[nt], a0, 0, 0, 0);
            a0 = __builtin_amdgcn_mfma_f32_16x16x32_bf16(al0, bh[nt], a0, 0, 0, 0);
            accA[nt] = a0;
            f32x4 a1 = {0.f, 0.f, 0.f, 0.f};
            a1 = __builtin_amdgcn_mfma_f32_16x16x32_bf16(ah1, bh[nt], a1, 0, 0, 0);
            a1 = __builtin_amdgcn_mfma_f32_16x16x32_bf16(ah1, bl[nt], a1, 0, 0, 0);
            a1 = __builtin_amdgcn_mfma_f32_16x16x32_bf16(al1, bh[nt], a1, 0, 0, 0);
            accB[nt] = a1;
        }
    }

    float keep = 0.f;                              // reduced logit, lane-mapped

#pragma unroll
    for (int half = 0; half < 2; half++) {
        // scatter this half's ep into LDS
#pragma unroll
        for (int nt = 0; nt < 4; nt++) {
            const f32x4 a = half ? accB[nt] : accA[nt];
            const int cc = cbase + nt * 16;
#pragma unroll
            for (int r = 0; r < 4; r++)
                ep_lds[(rbase + r) * EPP + cc] = a[r];
        }
        __syncthreads();

#pragma unroll
        for (int bb = 0; bb < 2; bb++) {           // 2 batches of 8 edges per half
            const int e0 = half * 16 + bb * 8;
            int sv[8], dv[8];
            {
                const int4 ss0 = *(const int4*)&s_src[e0];
                const int4 ss1 = *(const int4*)&s_src[e0 + 4];
                sv[0]=ss0.x; sv[1]=ss0.y; sv[2]=ss0.z; sv[3]=ss0.w;
                sv[4]=ss1.x; sv[5]=ss1.y; sv[6]=ss1.z; sv[7]=ss1.w;
                const int4 dd0 = *(const int4*)&s_dst[e0];
                const int4 dd1 = *(const int4*)&s_dst[e0 + 4];
                dv[0]=dd0.x; dv[1]=dd0.y; dv[2]=dd0.z; dv[3]=dd0.w;
                dv[4]=dd1.x; dv[5]=dd1.y; dv[6]=dd1.z; dv[7]=dd1.w;
            }
            float xls[8], xrr[8], c[8];
#pragma unroll
            for (int u = 0; u < 8; u++) xls[u] = xl[sv[u] * 256 + tid];
#pragma unroll
            for (int u = 0; u < 8; u++) xrr[u] = xr[dv[u] * 256 + tid];
#pragma unroll
            for (int u = 0; u < 8; u++) {
                float v = xls[u] + xrr[u] + ep_lds[(e0 - half * 16 + u) * EPP + tid];
                v = fmaxf(v, 0.f) + 0.2f * fminf(v, 0.f);   // leaky_relu 0.2
                c[u] = att_r * v;
            }

            // multi-value exchange reduce: 8 sums in 6 cross-lane steps
            float n0, n1, n2, n3;
            {   // stride 1 (quad_perm xor1): 8 -> 4 values
                const bool s = lane & 1;
                n0 = (s ? c[1] : c[0]) + dpp_mov<0xB1>(s ? c[0] : c[1]);
                n1 = (s ? c[3] : c[2]) + dpp_mov<0xB1>(s ? c[2] : c[3]);
                n2 = (s ? c[5] : c[4]) + dpp_mov<0xB1>(s ? c[4] : c[5]);
                n3 = (s ? c[7] : c[6]) + dpp_mov<0xB1>(s ? c[6] : c[7]);
            }
            float m0, m1;
            {   // stride 2 (quad_perm xor2): 4 -> 2 values
                const bool s = lane & 2;
                m0 = (s ? n1 : n0) + dpp_mov<0x4E>(s ? n0 : n1);
                m1 = (s ? n3 : n2) + dpp_mov<0x4E>(s ? n2 : n3);
            }
            float r;
            {   // stride 32 (exact xor via shfl): 2 -> 1 value
                const bool s = lane & 32;
                const float oth = __shfl_xor(s ? m0 : m1, 32);
                r = (s ? m1 : m0) + oth;
            }
            // remaining strides {4,8} via full-coverage rotations, {16} via xor
            r = dpp_add<0x124>(r);                 // row_ror:4
            r = dpp_add<0x128>(r);                 // row_ror:8
            r += __shfl_xor(r, 16);
            // lane holds value idx=(l&3)|((l&32)>>3); batch select on bits 2,3
            keep = (((lane >> 2) & 3) == half * 2 + bb) ? r : keep;
        }
        __syncthreads();
    }

    // write: lanes with bit4==0 cover all 32 edges bijectively
    const int e = ((lane >> 2) & 3) * 8 + (lane & 3) + ((lane >> 3) & 4);
    if (!(lane & 16) && e < cnt)
        pe_out[w * kTp + b0 + e] = __expf(keep);   // one exp per tile
}

// ---------------- Pass 2: per-node aggregate ----------------
__global__ __launch_bounds__(256) void gat_aggr_kernel(
    const float* __restrict__ xl, const float* __restrict__ pe,
    const int* __restrict__ csr_src, const int* __restrict__ offsets,
    const float* __restrict__ gbias, float* __restrict__ h_out)
{
    __shared__ float red[256];
    const int tid = threadIdx.x;
    const int w = tid >> 6;
    const int n = blockIdx.x;
    const int o0 = offsets[n], o1 = offsets[n + 1];
    const float* pep = pe + (size_t)w * kTp;

    float den = 0.f, acc = 0.f;
    int i = o0;
    for (; i + 8 <= o1; i += 8) {
        float pv[8], xv[8];
        int sv[8];
#pragma unroll
        for (int u = 0; u < 8; u++) pv[u] = pep[i + u];
#pragma unroll
        for (int u = 0; u < 8; u++) sv[u] = csr_src[i + u];
#pragma unroll
        for (int u = 0; u < 8; u++) xv[u] = xl[sv[u] * 256 + tid];
#pragma unroll
        for (int u = 0; u < 8; u++) {
            den += pv[u];
            acc += pv[u] * xv[u];
        }
    }
    for (; i < o1; i++) {
        const float p = pep[i];
        den += p;
        acc += p * xl[csr_src[i] * 256 + tid];
    }
    red[tid] = acc / den;
    __syncthreads();
    if (tid < 64) {
        float sres = red[tid] + red[tid + 64] + red[tid + 128] + red[tid + 192];
        h_out[n * 64 + tid] = fmaxf(0.25f * sres + gbias[tid], 0.f);
    }
}

// ---------------- node head: P[n][0:16]=h@W13[0:64], P[n][16:32]=h@W13[64:128] ----------------
__global__ __launch_bounds__(256) void node_head_kernel(
    const float* __restrict__ h, const float* __restrict__ intW,
    const float* __restrict__ impW, float* __restrict__ P)
{
    const int tid = threadIdx.x;
    const int w = tid >> 6, lane = tid & 63;
    const int row0 = blockIdx.x * 64 + w * 16;
    const int rr = lane & 15;             // A-row / B-col / C-col
    const int kg = lane >> 4;             // k-group

    bf16x8s Bh[2][2], Bl[2][2];
#pragma unroll
    for (int ct = 0; ct < 2; ct++) {
#pragma unroll
        for (int kk = 0; kk < 2; kk++) {
            const int kbase = ct * 64 + kk * 32 + kg * 8;
#pragma unroll
            for (int j = 0; j < 8; j++) {
                const int k = kbase + j;
                float wv;
                if (rr < 12)       wv = intW[k * 12 + rr];
                else if (rr == 12) wv = impW[k];
                else               wv = 0.f;
                const unsigned short hb = f2bf(wv);
                Bh[ct][kk][j] = (short)hb;
                Bl[ct][kk][j] = (short)f2bf(wv - bf2f(hb));
            }
        }
    }

    const int arow = min(row0 + rr, kN - 1);
    bf16x8s Ah[2], Al[2];
#pragma unroll
    for (int kk = 0; kk < 2; kk++) {
        const float4 f0 = *(const float4*)&h[arow * 64 + kk * 32 + kg * 8];
        const float4 f1 = *(const float4*)&h[arow * 64 + kk * 32 + kg * 8 + 4];
        const float fv[8] = {f0.x, f0.y, f0.z, f0.w, f1.x, f1.y, f1.z, f1.w};
#pragma unroll
        for (int j = 0; j < 8; j++) {
            const unsigned short hb = f2bf(fv[j]);
            Ah[kk][j] = (short)hb;
            Al[kk][j] = (short)f2bf(fv[j] - bf2f(hb));
        }
    }

#pragma unroll
    for (int ct = 0; ct < 2; ct++) {
        f32x4 acc = {0.f, 0.f, 0.f, 0.f};
#pragma unroll
        for (int kk = 0; kk < 2; kk++) {
            acc = __builtin_amdgcn_mfma_f32_16x16x32_bf16(Ah[kk], Bh[ct][kk], acc, 0, 0, 0);
            acc = __builtin_amdgcn_mfma_f32_16x16x32_bf16(Ah[kk], Bl[ct][kk], acc, 0, 0, 0);
            acc = __builtin_amdgcn_mfma_f32_16x16x32_bf16(Al[kk], Bh[ct][kk], acc, 0, 0, 0);
        }
        const int crow0 = kg * 4;
#pragma unroll
        for (int r = 0; r < 4; r++) {
            const int row = row0 + crow0 + r;
            if (row < kN) P[row * 32 + ct * 16 + rr] = acc[r];
        }
    }
}

// ---------------- edge out: Q = relu(ea)@W13[128:160]; out = Q + P_src + P_dst + b ----------------
__global__ __launch_bounds__(256) void edge_out_kernel(
    const float* __restrict__ ea, const int* __restrict__ ei,
    const float* __restrict__ P,
    const float* __restrict__ intW, const float* __restrict__ intb,
    const float* __restrict__ impW, const float* __restrict__ impb,
    float* __restrict__ out)
{
    constexpr int ROWS = 40;
    __shared__ __align__(16) unsigned short ehi[4][16 * ROWS];
    __shared__ __align__(16) unsigned short elo[4][16 * ROWS];
    const int tid = threadIdx.x;
    const int w = tid >> 6, lane = tid & 63;
    const int e0 = blockIdx.x * 64 + w * 16;
    const int rr = lane & 15, kg = lane >> 4;

    bf16x8s Bh, Bl;
#pragma unroll
    for (int j = 0; j < 8; j++) {
        const int k = 128 + kg * 8 + j;
        float wv;
        if (rr < 12)       wv = intW[k * 12 + rr];
        else if (rr == 12) wv = impW[k];
        else               wv = 0.f;
        const unsigned short hb = f2bf(wv);
        Bh[j] = (short)hb;
        Bl[j] = (short)f2bf(wv - bf2f(hb));
    }

    {
        const int j = lane >> 2, q = lane & 3;
        const float4* src = (const float4*)&ea[(size_t)(e0 + j) * 32 + q * 8];
        const float4 f0 = src[0], f1 = src[1];
        const float fv[8] = {fmaxf(f0.x, 0.f), fmaxf(f0.y, 0.f), fmaxf(f0.z, 0.f), fmaxf(f0.w, 0.f),
                             fmaxf(f1.x, 0.f), fmaxf(f1.y, 0.f), fmaxf(f1.z, 0.f), fmaxf(f1.w, 0.f)};
        unsigned long long ph0 = 0, pl0 = 0, ph1 = 0, pl1 = 0;
#pragma unroll
        for (int t = 0; t < 4; t++) {
            const unsigned short hb = f2bf(fv[t]);
            const unsigned short lb = f2bf(fv[t] - bf2f(hb));
            ph0 |= (unsigned long long)hb << (16 * t);
            pl0 |= (unsigned long long)lb << (16 * t);
        }
#pragma unroll
        for (int t = 0; t < 4; t++) {
            const unsigned short hb = f2bf(fv[4 + t]);
            const unsigned short lb = f2bf(fv[4 + t] - bf2f(hb));
            ph1 |= (unsigned long long)hb << (16 * t);
            pl1 |= (unsigned long long)lb << (16 * t);
        }
        *(unsigned long long*)&ehi[w][j * ROWS + q * 8]     = ph0;
        *(unsigned long long*)&ehi[w][j * ROWS + q * 8 + 4] = ph1;
        *(unsigned long long*)&elo[w][j * ROWS + q * 8]     = pl0;
        *(unsigned long long*)&elo[w][j * ROWS + q * 8 + 4] = pl1;
    }
    __syncthreads();

    const int aoff = rr * ROWS + kg * 8;
    const bf16x8s Ah = *(const bf16x8s*)&ehi[w][aoff];
    const bf16x8s Al = *(const bf16x8s*)&elo[w][aoff];
    f32x4 q = {0.f, 0.f, 0.f, 0.f};
    q = __builtin_amdgcn_mfma_f32_16x16x32_bf16(Ah, Bh, q, 0, 0, 0);
    q = __builtin_amdgcn_mfma_f32_16x16x32_bf16(Ah, Bl, q, 0, 0, 0);
    q = __builtin_amdgcn_mfma_f32_16x16x32_bf16(Al, Bh, q, 0, 0, 0);

    if (rr < 13) {
        const float bv = (rr < 12) ? intb[rr] : impb[0];
#pragma unroll
        for (int r = 0; r < 4; r++) {
            const int e = e0 + kg * 4 + r;
            const int s = ei[e], d = ei[kE + e];
            const float val = q[r] + P[s * 32 + rr] + P[d * 32 + 16 + rr] + bv;
            if (rr < 12) out[(size_t)e * 12 + rr] = val;
            else         out[(size_t)kE * 12 + e] = 1.f / (1.f + __expf(-val));
        }
    }
}

// ---------------- launch ----------------
extern "C" void kernel_launch(void* const* d_in, const int* in_sizes, int n_in,
                              void* d_out, int out_size, void* d_ws, size_t ws_size,
                              hipStream_t stream)
{
    (void)in_sizes; (void)n_in; (void)out_size; (void)ws_size;

    const float* x      = (const float*)d_in[0];
    const int*   ei     = (const int*)d_in[1];
    const float* ea     = (const float*)d_in[2];
    const float* emb_W  = (const float*)d_in[3];
    const float* emb_b  = (const float*)d_in[4];
    const float* g1_Wl  = (const float*)d_in[5];
    const float* g1_bl  = (const float*)d_in[6];
    const float* g1_Wr  = (const float*)d_in[7];
    const float* g1_br  = (const float*)d_in[8];
    const float* g1_We  = (const float*)d_in[9];
    const float* g1_att = (const float*)d_in[10];
    const float* g1_bias= (const float*)d_in[11];
    const float* g2_Wl  = (const float*)d_in[12];
    const float* g2_bl  = (const float*)d_in[13];
    const float* g2_Wr  = (const float*)d_in[14];
    const float* g2_br  = (const float*)d_in[15];
    const float* g2_We  = (const float*)d_in[16];
    const float* g2_att = (const float*)d_in[17];
    const float* g2_bias= (const float*)d_in[18];
    const float* int_W  = (const float*)d_in[19];
    const float* int_b  = (const float*)d_in[20];
    const float* imp_W  = (const float*)d_in[21];
    const float* imp_b  = (const float*)d_in[22];

    char* ws = (char*)d_ws;
    float* eapart  = (float*)(ws + OFF_EAPART);
    float* eamean  = (float*)(ws + OFF_EAMEAN);
    int*   counts  = (int*)  (ws + OFF_COUNTS);
    int*   offs    = (int*)  (ws + OFF_OFFS);
    int*   cursor  = (int*)  (ws + OFF_CURSOR);
    int*   csrsrc  = (int*)  (ws + OFF_CSRSRC);
    int*   csreid  = (int*)  (ws + OFF_CSREID);
    int*   csrdst  = (int*)  (ws + OFF_CSRDST);
    float* pe      = (float*)(ws + OFF_PE);
    float* h_a     = (float*)(ws + OFF_HA);
    float* h_b     = (float*)(ws + OFF_HB);
    float* xl      = (float*)(ws + OFF_XL);
    float* xr      = (float*)(ws + OFF_XR);
    unsigned short* f1h = (unsigned short*)(ws + OFF_F1H);
    unsigned short* f1l = (unsigned short*)(ws + OFF_F1L);
    unsigned short* f2h = (unsigned short*)(ws + OFF_F2H);
    unsigned short* f2l = (unsigned short*)(ws + OFF_F2L);
    float* P       = pe;                      // reuse pe region after last aggr
    float* outp    = (float*)d_out;

    constexpr int NT = (kTaug + 31) / 32;   // 13282 edge tiles

    // edge_attr mean + We frag-swizzled bf16 splits
    ea_colsum_part<<<1024, 256, 0, stream>>>(ea, eapart);
    ea_colsum_final<<<1, 256, 0, stream>>>(eapart, eamean);
    we_swizzle<<<32, 256, 0, stream>>>(g1_We, g2_We, f1h, f1l, f2h, f2l);

    // CSR by destination (self-loops included)
    init_counts<<<(kN + 255) / 256, 256, 0, stream>>>(counts);
    count_edges<<<(kE + 255) / 256, 256, 0, stream>>>(ei, counts);
    scan_kernel<<<1, 1024, 0, stream>>>(counts, offs, cursor);
    scatter_kernel<<<(kE + kN + 255) / 256, 256, 0, stream>>>(ei, cursor, csrsrc, csreid, csrdst);

    // node embedding
    gemm_bias<128, 64, 32><<<(kN + 31) / 32, 256, 0, stream>>>(x, emb_W, emb_b, h_a, kN);

    // ---- GAT layer 1 ----
    gemm_bias<64, 256, 32><<<(kN + 31) / 32, 256, 0, stream>>>(h_a, g1_Wl, g1_bl, xl, kN);
    gemm_bias<64, 256, 32><<<(kN + 31) / 32, 256, 0, stream>>>(h_a, g1_Wr, g1_br, xr, kN);
    edge_logit_kernel<<<NT, 256, 0, stream>>>(xl, xr, ea, eamean, f1h, f1l, g1_att,
                                              csrsrc, csrdst, csreid, pe);
    gat_aggr_kernel<<<kN, 256, 0, stream>>>(xl, pe, csrsrc, offs, g1_bias, h_b);

    // ---- GAT layer 2 ----
    gemm_bias<64, 256, 32><<<(kN + 31) / 32, 256, 0, stream>>>(h_b, g2_Wl, g2_bl, xl, kN);
    gemm_bias<64, 256, 32><<<(kN + 31) / 32, 256, 0, stream>>>(h_b, g2_Wr, g2_br, xr, kN);
    edge_logit_kernel<<<NT, 256, 0, stream>>>(xl, xr, ea, eamean, f2h, f2l, g2_att,
                                              csrsrc, csrdst, csreid, pe);
    gat_aggr_kernel<<<kN, 256, 0, stream>>>(xl, pe, csrsrc, offs, g2_bias, h_a);

    // ---- edge heads (decomposed) ----
    node_head_kernel<<<(kN + 63) / 64, 256, 0, stream>>>(h_a, int_W, imp_W, P);
    edge_out_kernel<<<kE / 64, 256, 0, stream>>>(ea, ei, P, int_W, int_b, imp_W, imp_b, outp);
}

// Round 10
// 571.814 us; speedup vs baseline: 1.2687x; 1.0786x over previous
//
#include <hip/hip_runtime.h>
#include <math.h>

// Problem constants
constexpr int kN = 25000;
constexpr int kE = 400000;
constexpr int kTaug = kE + kN;        // CSR slots incl self-loops = 425000
constexpr int kTp = 425216;           // padded pe plane stride
constexpr int kIntents = 12;

typedef __attribute__((ext_vector_type(8))) short bf16x8s;   // 8 bf16 (4 VGPRs)
typedef __attribute__((ext_vector_type(4))) float f32x4;

__device__ __forceinline__ unsigned short f2bf(float f) {
    unsigned u = __builtin_bit_cast(unsigned, f);
    unsigned r = (u + 0x7FFFu + ((u >> 16) & 1u)) >> 16;     // RNE
    return (unsigned short)r;
}
__device__ __forceinline__ float bf2f(unsigned short h) {
    unsigned u = ((unsigned)h) << 16;
    return __builtin_bit_cast(float, u);
}

// DPP helpers (CTRL must be compile-time constant)
template<int CTRL>
__device__ __forceinline__ float dpp_mov(float x) {
    int yi = __builtin_amdgcn_update_dpp(0, __builtin_bit_cast(int, x), CTRL, 0xF, 0xF, true);
    return __builtin_bit_cast(float, yi);
}
template<int CTRL>
__device__ __forceinline__ float dpp_add(float x) {
    return x + dpp_mov<CTRL>(x);
}

// ---------------- workspace layout (256B aligned) ----------------
constexpr size_t OFF_EAPART = 0;          // 1024*32 f32 = 131072
constexpr size_t OFF_EAMEAN = 131072;     // 32 f32 (pad 256)
constexpr size_t OFF_COUNTS = 131328;     // N i32
constexpr size_t OFF_OFFS   = 231424;     // N+1 i32
constexpr size_t OFF_CURSOR = 331520;     // N i32
constexpr size_t OFF_CSRSRC = 431616;     // Taug i32
constexpr size_t OFF_CSREID = 2131712;    // Taug i32
constexpr size_t OFF_CSRDST = 3831808;    // Taug i32
constexpr size_t OFF_PE     = 5531904;    // 4*kTp f32 (reused as P after aggr2)
constexpr size_t OFF_HA     = 12335360;   // N*64 f32
constexpr size_t OFF_HB     = 18735360;   // N*64 f32
constexpr size_t OFF_XL     = 25135360;   // N*256 f32
constexpr size_t OFF_XR     = 50735360;   // N*256 f32
constexpr size_t OFF_F1H    = 76335360;   // 4*4*64*8 u16 = 16384 (frag-swizzled We)
constexpr size_t OFF_F1L    = 76351744;
constexpr size_t OFF_F2H    = 76368128;
constexpr size_t OFF_F2L    = 76384512;
// GEMM weight frag tables (32KB slots: CT*KCH*64*8 u16 <= 16384 u16)
constexpr size_t OFF_WEMBH  = 76400896;
constexpr size_t OFF_WEMBL  = 76433664;
constexpr size_t OFF_WL1H   = 76466432;
constexpr size_t OFF_WL1L   = 76499200;
constexpr size_t OFF_WR1H   = 76531968;
constexpr size_t OFF_WR1L   = 76564736;
constexpr size_t OFF_WL2H   = 76597504;
constexpr size_t OFF_WL2L   = 76630272;
constexpr size_t OFF_WR2H   = 76663040;
constexpr size_t OFF_WR2L   = 76695808;   // end ~76.73 MB

// ---------------- edge_attr column mean ----------------
__global__ __launch_bounds__(256) void ea_colsum_part(const float* __restrict__ ea,
                                                      float* __restrict__ part)
{
    __shared__ float lds[256];
    const int tid = threadIdx.x;
    const int k = tid & 31, g = tid >> 5;
    float acc = 0.f;
    for (int r = blockIdx.x * 8 + g; r < kE; r += gridDim.x * 8)
        acc += ea[(size_t)r * 32 + k];
    lds[tid] = acc; __syncthreads();
    if (tid < 128) lds[tid] += lds[tid + 128]; __syncthreads();
    if (tid < 64)  lds[tid] += lds[tid + 64];  __syncthreads();
    if (tid < 32)  part[blockIdx.x * 32 + k] = lds[tid] + lds[tid + 32];
}

__global__ __launch_bounds__(256) void ea_colsum_final(const float* __restrict__ part,
                                                       float* __restrict__ ea_mean)
{
    __shared__ float lds[256];
    const int tid = threadIdx.x;
    const int k = tid & 31, g = tid >> 5;
    float acc = 0.f;
    for (int p = g; p < 1024; p += 8) acc += part[p * 32 + k];
    lds[tid] = acc; __syncthreads();
    if (tid < 128) lds[tid] += lds[tid + 128]; __syncthreads();
    if (tid < 64)  lds[tid] += lds[tid + 64];  __syncthreads();
    if (tid < 32)  ea_mean[k] = (lds[tid] + lds[tid + 32]) * (1.0f / (float)kE);
}

// ---------------- We -> frag-swizzled bf16 hi/lo (edge_logit tables) ----------------
__global__ __launch_bounds__(256) void we_swizzle(const float* __restrict__ W1,
                                                  const float* __restrict__ W2,
                                                  unsigned short* __restrict__ f1h,
                                                  unsigned short* __restrict__ f1l,
                                                  unsigned short* __restrict__ f2h,
                                                  unsigned short* __restrict__ f2l)
{
    const int b = blockIdx.x;                 // 32 blocks: layer*16 + nt*4 + w
    const int layer = b >> 4, nt = (b >> 2) & 3, w = b & 3;
    const float* W = layer ? W2 : W1;
    unsigned short* H = layer ? f2h : f1h;
    unsigned short* L = layer ? f2l : f1l;
    const int tid = threadIdx.x;
    const int lane = tid & 63, jh = tid >> 6;
    const int c = w * 64 + nt * 16 + (lane & 15);
    const int kbase = (lane >> 4) * 8;
#pragma unroll
    for (int t = 0; t < 2; t++) {
        const int j = jh * 2 + t;
        const float f = W[(kbase + j) * 256 + c];
        const unsigned short hb = f2bf(f);
        const int idx = ((nt * 4 + w) * 64 + lane) * 8 + j;
        H[idx] = hb;
        L[idx] = f2bf(f - bf2f(hb));
    }
}

// ---------------- generic GEMM-weight frag table ----------------
// table[((ct*KCH + kk)*64 + lane)*8 + j] = W[k*KO + c], c=ct*16+(lane&15), k=kk*32+(lane>>4)*8+j
__global__ __launch_bounds__(256) void w_swizzle_tab(const float* __restrict__ W,
                                                     int KO, int CTILES, int KCH,
                                                     unsigned short* __restrict__ H,
                                                     unsigned short* __restrict__ L)
{
    const int total = CTILES * KCH * 64 * 8;
    for (int idx = blockIdx.x * 256 + threadIdx.x; idx < total; idx += gridDim.x * 256) {
        const int j = idx & 7;
        const int lane = (idx >> 3) & 63;
        const int t = idx >> 9;               // ct*KCH + kk
        const int ct = t / KCH;
        const int c = ct * 16 + (lane & 15);
        const int k = (t - ct * KCH) * 32 + (lane >> 4) * 8 + j;
        const float f = W[k * KO + c];
        const unsigned short hb = f2bf(f);
        H[idx] = hb;
        L[idx] = f2bf(f - bf2f(hb));
    }
}

// ---------------- MFMA dense GEMM: out[M,KO] = A[M,KI]@W + bias (split-bf16 x3) ----------------
template<int KI, int KO>
__global__ __launch_bounds__(256) void mfma_gemm_bias(
    const float* __restrict__ A,
    const unsigned short* __restrict__ WH, const unsigned short* __restrict__ WL,
    const float* __restrict__ bias, float* __restrict__ out, int M)
{
    constexpr int KCH = KI / 32;
    constexpr int CT  = KO / 16;
    const int tid = threadIdx.x;
    const int w = tid >> 6, lane = tid & 63;
    const int row0 = blockIdx.x * 64 + w * 16;
    const int rr = lane & 15, kg = lane >> 4;
    const int arow = min(row0 + rr, M - 1);

    bf16x8s Ah[KCH], Al[KCH];
#pragma unroll
    for (int kk = 0; kk < KCH; kk++) {
        const float4 f0 = *(const float4*)&A[(size_t)arow * KI + kk * 32 + kg * 8];
        const float4 f1 = *(const float4*)&A[(size_t)arow * KI + kk * 32 + kg * 8 + 4];
        const float fv[8] = {f0.x, f0.y, f0.z, f0.w, f1.x, f1.y, f1.z, f1.w};
#pragma unroll
        for (int j = 0; j < 8; j++) {
            const unsigned short hb = f2bf(fv[j]);
            Ah[kk][j] = (short)hb;
            Al[kk][j] = (short)f2bf(fv[j] - bf2f(hb));
        }
    }
    const int rbase = kg * 4;
#pragma unroll
    for (int ct = 0; ct < CT; ct++) {
        f32x4 acc = {0.f, 0.f, 0.f, 0.f};
#pragma unroll
        for (int kk = 0; kk < KCH; kk++) {
            const int bidx = ((ct * KCH + kk) * 64 + lane) * 8;
            const bf16x8s Bh = *(const bf16x8s*)&WH[bidx];
            const bf16x8s Bl = *(const bf16x8s*)&WL[bidx];
            acc = __builtin_amdgcn_mfma_f32_16x16x32_bf16(Ah[kk], Bh, acc, 0, 0, 0);
            acc = __builtin_amdgcn_mfma_f32_16x16x32_bf16(Ah[kk], Bl, acc, 0, 0, 0);
            acc = __builtin_amdgcn_mfma_f32_16x16x32_bf16(Al[kk], Bh, acc, 0, 0, 0);
        }
        const float bv = bias[ct * 16 + rr];
#pragma unroll
        for (int r = 0; r < 4; r++) {
            const int row = row0 + rbase + r;
            if (row < M) out[(size_t)row * KO + ct * 16 + rr] = acc[r] + bv;
        }
    }
}

// ---------------- CSR build ----------------
__global__ __launch_bounds__(256) void init_counts(int* __restrict__ counts)
{
    int i = blockIdx.x * 256 + threadIdx.x;
    if (i < kN) counts[i] = 1;   // self-loop pre-counted
}

__global__ __launch_bounds__(256) void count_edges(const int* __restrict__ ei,
                                                   int* __restrict__ counts)
{
    int e = blockIdx.x * 256 + threadIdx.x;
    if (e < kE) atomicAdd(&counts[ei[kE + e]], 1);
}

__global__ __launch_bounds__(1024) void scan_kernel(const int* __restrict__ counts,
                                                    int* __restrict__ offsets,
                                                    int* __restrict__ cursor)
{
    __shared__ int lds[1024];
    const int tid = threadIdx.x;
    const int base = tid * 25;
    int local = 0;
#pragma unroll 5
    for (int i = 0; i < 25; i++) {
        int idx = base + i;
        if (idx < kN) local += counts[idx];
    }
    lds[tid] = local; __syncthreads();
    for (int d = 1; d < 1024; d <<= 1) {
        int t = (tid >= d) ? lds[tid - d] : 0;
        __syncthreads();
        lds[tid] += t;
        __syncthreads();
    }
    int run = lds[tid] - local;   // exclusive prefix
    for (int i = 0; i < 25; i++) {
        int idx = base + i;
        if (idx < kN) {
            offsets[idx] = run;
            cursor[idx]  = run;
            run += counts[idx];
        }
    }
    if (tid == 1023) offsets[kN] = lds[1023];
}

__global__ __launch_bounds__(256) void scatter_kernel(const int* __restrict__ ei,
                                                      int* __restrict__ cursor,
                                                      int* __restrict__ csr_src,
                                                      int* __restrict__ csr_eid,
                                                      int* __restrict__ csr_dst)
{
    int gid = blockIdx.x * 256 + threadIdx.x;
    if (gid < kE) {
        int s = ei[gid];
        int d = ei[kE + gid];
        int p = atomicAdd(&cursor[d], 1);
        csr_src[p] = s;
        csr_eid[p] = gid;
        csr_dst[p] = d;
    } else if (gid < kE + kN) {
        int n = gid - kE;
        int p = atomicAdd(&cursor[n], 1);
        csr_src[p] = n;
        csr_eid[p] = kE;   // sentinel: self-loop
        csr_dst[p] = n;
    }
}

// ---------------- Pass 1: per-edge attention weights (one 32-edge tile per block) ----------------
// R8: multi-value exchange reduce — 8 edge-sums reduced in 6 cross-lane steps.
__global__ __launch_bounds__(256) void edge_logit_kernel(
    const float* __restrict__ xl, const float* __restrict__ xr,
    const float* __restrict__ ea, const float* __restrict__ eamean,
    const unsigned short* __restrict__ fragh, const unsigned short* __restrict__ fragl,
    const float* __restrict__ att,
    const int* __restrict__ csr_src, const int* __restrict__ csr_dst,
    const int* __restrict__ csr_eid, float* __restrict__ pe_out)
{
    constexpr int ROWS = 40;                       // padded ea row (shorts), 80B
    constexpr int EPP  = 257;                      // padded ep row (floats), 16-edge half
    __shared__ __align__(16) unsigned short ea_hi[32 * ROWS];
    __shared__ __align__(16) unsigned short ea_lo[32 * ROWS];
    __shared__ __align__(16) float ep_lds[16 * EPP];
    __shared__ __align__(16) int s_src[32];
    __shared__ __align__(16) int s_dst[32];
    const int tid  = threadIdx.x;
    const int w    = tid >> 6;
    const int lane = tid & 63;
    const int b0   = blockIdx.x * 32;
    const int cnt  = min(32, kTaug - b0);

    // B fragments: 8 coalesced b128 loads from pre-swizzled tables
    bf16x8s bh[4], bl[4];
#pragma unroll
    for (int nt = 0; nt < 4; nt++) {
        const int idx = ((nt * 4 + w) * 64 + lane) * 8;
        bh[nt] = *(const bf16x8s*)&fragh[idx];
        bl[nt] = *(const bf16x8s*)&fragl[idx];
    }
    const float att_r = att[tid];
    const int aoff  = (lane & 15) * ROWS + (lane >> 4) * 8;
    const int cbase = w * 64 + (lane & 15);
    const int rbase = (lane >> 4) * 4;

    // stage indices + ea rows (clamped: tail tile reads duplicate valid slots)
    if (tid < 32) {
        const int p = min(b0 + tid, kTaug - 1);
        s_src[tid] = csr_src[p];
        s_dst[tid] = csr_dst[p];
    }
    {
        const int j = tid >> 3, q = tid & 7;
        const int eid = csr_eid[min(b0 + j, kTaug - 1)];
        const float4* srcp = (eid < kE) ? (const float4*)(ea + (size_t)eid * 32)
                                        : (const float4*)eamean;
        const float4 f = srcp[q];
        const unsigned short h0 = f2bf(f.x), h1 = f2bf(f.y),
                             h2 = f2bf(f.z), h3 = f2bf(f.w);
        const unsigned short g0 = f2bf(f.x - bf2f(h0)), g1 = f2bf(f.y - bf2f(h1)),
                             g2 = f2bf(f.z - bf2f(h2)), g3 = f2bf(f.w - bf2f(h3));
        const unsigned long long ph =
            (unsigned long long)h0 | ((unsigned long long)h1 << 16) |
            ((unsigned long long)h2 << 32) | ((unsigned long long)h3 << 48);
        const unsigned long long pl =
            (unsigned long long)g0 | ((unsigned long long)g1 << 16) |
            ((unsigned long long)g2 << 32) | ((unsigned long long)g3 << 48);
        *(unsigned long long*)&ea_hi[j * ROWS + q * 4] = ph;
        *(unsigned long long*)&ea_lo[j * ROWS + q * 4] = pl;
    }
    __syncthreads();

    // MFMA: ep[32][256] = ea @ We (3-product split-bf16), both row halves
    f32x4 accA[4], accB[4];
    {
        const bf16x8s ah0 = *(const bf16x8s*)&ea_hi[aoff];
        const bf16x8s ah1 = *(const bf16x8s*)&ea_hi[16 * ROWS + aoff];
        const bf16x8s al0 = *(const bf16x8s*)&ea_lo[aoff];
        const bf16x8s al1 = *(const bf16x8s*)&ea_lo[16 * ROWS + aoff];
#pragma unroll
        for (int nt = 0; nt < 4; nt++) {
            f32x4 a0 = {0.f, 0.f, 0.f, 0.f};
            a0 = __builtin_amdgcn_mfma_f32_16x16x32_bf16(ah0, bh[nt], a0, 0, 0, 0);
            a0 = __builtin_amdgcn_mfma_f32_16x16x32_bf16(ah0, bl[nt], a0, 0, 0, 0);
            a0 = __builtin_amdgcn_mfma_f32_16x16x32_bf16(al0, bh[nt], a0, 0, 0, 0);
            accA[nt] = a0;
            f32x4 a1 = {0.f, 0.f, 0.f, 0.f};
            a1 = __builtin_amdgcn_mfma_f32_16x16x32_bf16(ah1, bh[nt], a1, 0, 0, 0);
            a1 = __builtin_amdgcn_mfma_f32_16x16x32_bf16(ah1, bl[nt], a1, 0, 0, 0);
            a1 = __builtin_amdgcn_mfma_f32_16x16x32_bf16(al1, bh[nt], a1, 0, 0, 0);
            accB[nt] = a1;
        }
    }

    float keep = 0.f;                              // reduced logit, lane-mapped

#pragma unroll
    for (int half = 0; half < 2; half++) {
#pragma unroll
        for (int nt = 0; nt < 4; nt++) {
            const f32x4 a = half ? accB[nt] : accA[nt];
            const int cc = cbase + nt * 16;
#pragma unroll
            for (int r = 0; r < 4; r++)
                ep_lds[(rbase + r) * EPP + cc] = a[r];
        }
        __syncthreads();

#pragma unroll
        for (int bb = 0; bb < 2; bb++) {           // 2 batches of 8 edges per half
            const int e0 = half * 16 + bb * 8;
            int sv[8], dv[8];
            {
                const int4 ss0 = *(const int4*)&s_src[e0];
                const int4 ss1 = *(const int4*)&s_src[e0 + 4];
                sv[0]=ss0.x; sv[1]=ss0.y; sv[2]=ss0.z; sv[3]=ss0.w;
                sv[4]=ss1.x; sv[5]=ss1.y; sv[6]=ss1.z; sv[7]=ss1.w;
                const int4 dd0 = *(const int4*)&s_dst[e0];
                const int4 dd1 = *(const int4*)&s_dst[e0 + 4];
                dv[0]=dd0.x; dv[1]=dd0.y; dv[2]=dd0.z; dv[3]=dd0.w;
                dv[4]=dd1.x; dv[5]=dd1.y; dv[6]=dd1.z; dv[7]=dd1.w;
            }
            float xls[8], xrr[8], c[8];
#pragma unroll
            for (int u = 0; u < 8; u++) xls[u] = xl[sv[u] * 256 + tid];
#pragma unroll
            for (int u = 0; u < 8; u++) xrr[u] = xr[dv[u] * 256 + tid];
#pragma unroll
            for (int u = 0; u < 8; u++) {
                float v = xls[u] + xrr[u] + ep_lds[(e0 - half * 16 + u) * EPP + tid];
                v = fmaxf(v, 0.f) + 0.2f * fminf(v, 0.f);   // leaky_relu 0.2
                c[u] = att_r * v;
            }

            // multi-value exchange reduce: 8 sums in 6 cross-lane steps
            float n0, n1, n2, n3;
            {   // stride 1 (quad_perm xor1): 8 -> 4 values
                const bool s = lane & 1;
                n0 = (s ? c[1] : c[0]) + dpp_mov<0xB1>(s ? c[0] : c[1]);
                n1 = (s ? c[3] : c[2]) + dpp_mov<0xB1>(s ? c[2] : c[3]);
                n2 = (s ? c[5] : c[4]) + dpp_mov<0xB1>(s ? c[4] : c[5]);
                n3 = (s ? c[7] : c[6]) + dpp_mov<0xB1>(s ? c[6] : c[7]);
            }
            float m0, m1;
            {   // stride 2 (quad_perm xor2): 4 -> 2 values
                const bool s = lane & 2;
                m0 = (s ? n1 : n0) + dpp_mov<0x4E>(s ? n0 : n1);
                m1 = (s ? n3 : n2) + dpp_mov<0x4E>(s ? n2 : n3);
            }
            float r;
            {   // stride 32 (exact xor via shfl): 2 -> 1 value
                const bool s = lane & 32;
                const float oth = __shfl_xor(s ? m0 : m1, 32);
                r = (s ? m1 : m0) + oth;
            }
            // remaining strides {4,8} via full-coverage rotations, {16} via xor
            r = dpp_add<0x124>(r);                 // row_ror:4
            r = dpp_add<0x128>(r);                 // row_ror:8
            r += __shfl_xor(r, 16);
            keep = (((lane >> 2) & 3) == half * 2 + bb) ? r : keep;
        }
        __syncthreads();
    }

    // write: lanes with bit4==0 cover all 32 edges bijectively
    const int e = ((lane >> 2) & 3) * 8 + (lane & 3) + ((lane >> 3) & 4);
    if (!(lane & 16) && e < cnt)
        pe_out[w * kTp + b0 + e] = __expf(keep);   // one exp per tile
}

// ---------------- Pass 2: per-node aggregate ----------------
__global__ __launch_bounds__(256) void gat_aggr_kernel(
    const float* __restrict__ xl, const float* __restrict__ pe,
    const int* __restrict__ csr_src, const int* __restrict__ offsets,
    const float* __restrict__ gbias, float* __restrict__ h_out)
{
    __shared__ float red[256];
    const int tid = threadIdx.x;
    const int w = tid >> 6;
    const int n = blockIdx.x;
    const int o0 = offsets[n], o1 = offsets[n + 1];
    const float* pep = pe + (size_t)w * kTp;

    float den = 0.f, acc = 0.f;
    int i = o0;
    for (; i + 8 <= o1; i += 8) {
        float pv[8], xv[8];
        int sv[8];
#pragma unroll
        for (int u = 0; u < 8; u++) pv[u] = pep[i + u];
#pragma unroll
        for (int u = 0; u < 8; u++) sv[u] = csr_src[i + u];
#pragma unroll
        for (int u = 0; u < 8; u++) xv[u] = xl[sv[u] * 256 + tid];
#pragma unroll
        for (int u = 0; u < 8; u++) {
            den += pv[u];
            acc += pv[u] * xv[u];
        }
    }
    for (; i < o1; i++) {
        const float p = pep[i];
        den += p;
        acc += p * xl[csr_src[i] * 256 + tid];
    }
    red[tid] = acc / den;
    __syncthreads();
    if (tid < 64) {
        float sres = red[tid] + red[tid + 64] + red[tid + 128] + red[tid + 192];
        h_out[n * 64 + tid] = fmaxf(0.25f * sres + gbias[tid], 0.f);
    }
}

// ---------------- node head: P[n][0:16]=h@W13[0:64], P[n][16:32]=h@W13[64:128] ----------------
__global__ __launch_bounds__(256) void node_head_kernel(
    const float* __restrict__ h, const float* __restrict__ intW,
    const float* __restrict__ impW, float* __restrict__ P)
{
    const int tid = threadIdx.x;
    const int w = tid >> 6, lane = tid & 63;
    const int row0 = blockIdx.x * 64 + w * 16;
    const int rr = lane & 15;             // A-row / B-col / C-col
    const int kg = lane >> 4;             // k-group

    bf16x8s Bh[2][2], Bl[2][2];
#pragma unroll
    for (int ct = 0; ct < 2; ct++) {
#pragma unroll
        for (int kk = 0; kk < 2; kk++) {
            const int kbase = ct * 64 + kk * 32 + kg * 8;
#pragma unroll
            for (int j = 0; j < 8; j++) {
                const int k = kbase + j;
                float wv;
                if (rr < 12)       wv = intW[k * 12 + rr];
                else if (rr == 12) wv = impW[k];
                else               wv = 0.f;
                const unsigned short hb = f2bf(wv);
                Bh[ct][kk][j] = (short)hb;
                Bl[ct][kk][j] = (short)f2bf(wv - bf2f(hb));
            }
        }
    }

    const int arow = min(row0 + rr, kN - 1);
    bf16x8s Ah[2], Al[2];
#pragma unroll
    for (int kk = 0; kk < 2; kk++) {
        const float4 f0 = *(const float4*)&h[arow * 64 + kk * 32 + kg * 8];
        const float4 f1 = *(const float4*)&h[arow * 64 + kk * 32 + kg * 8 + 4];
        const float fv[8] = {f0.x, f0.y, f0.z, f0.w, f1.x, f1.y, f1.z, f1.w};
#pragma unroll
        for (int j = 0; j < 8; j++) {
            const unsigned short hb = f2bf(fv[j]);
            Ah[kk][j] = (short)hb;
            Al[kk][j] = (short)f2bf(fv[j] - bf2f(hb));
        }
    }

#pragma unroll
    for (int ct = 0; ct < 2; ct++) {
        f32x4 acc = {0.f, 0.f, 0.f, 0.f};
#pragma unroll
        for (int kk = 0; kk < 2; kk++) {
            acc = __builtin_amdgcn_mfma_f32_16x16x32_bf16(Ah[kk], Bh[ct][kk], acc, 0, 0, 0);
            acc = __builtin_amdgcn_mfma_f32_16x16x32_bf16(Ah[kk], Bl[ct][kk], acc, 0, 0, 0);
            acc = __builtin_amdgcn_mfma_f32_16x16x32_bf16(Al[kk], Bh[ct][kk], acc, 0, 0, 0);
        }
        const int crow0 = kg * 4;
#pragma unroll
        for (int r = 0; r < 4; r++) {
            const int row = row0 + crow0 + r;
            if (row < kN) P[row * 32 + ct * 16 + rr] = acc[r];
        }
    }
}

// ---------------- edge out: Q = relu(ea)@W13[128:160]; out = Q + P_src + P_dst + b ----------------
__global__ __launch_bounds__(256) void edge_out_kernel(
    const float* __restrict__ ea, const int* __restrict__ ei,
    const float* __restrict__ P,
    const float* __restrict__ intW, const float* __restrict__ intb,
    const float* __restrict__ impW, const float* __restrict__ impb,
    float* __restrict__ out)
{
    constexpr int ROWS = 40;
    __shared__ __align__(16) unsigned short ehi[4][16 * ROWS];
    __shared__ __align__(16) unsigned short elo[4][16 * ROWS];
    const int tid = threadIdx.x;
    const int w = tid >> 6, lane = tid & 63;
    const int e0 = blockIdx.x * 64 + w * 16;
    const int rr = lane & 15, kg = lane >> 4;

    bf16x8s Bh, Bl;
#pragma unroll
    for (int j = 0; j < 8; j++) {
        const int k = 128 + kg * 8 + j;
        float wv;
        if (rr < 12)       wv = intW[k * 12 + rr];
        else if (rr == 12) wv = impW[k];
        else               wv = 0.f;
        const unsigned short hb = f2bf(wv);
        Bh[j] = (short)hb;
        Bl[j] = (short)f2bf(wv - bf2f(hb));
    }

    {
        const int j = lane >> 2, q = lane & 3;
        const float4* src = (const float4*)&ea[(size_t)(e0 + j) * 32 + q * 8];
        const float4 f0 = src[0], f1 = src[1];
        const float fv[8] = {fmaxf(f0.x, 0.f), fmaxf(f0.y, 0.f), fmaxf(f0.z, 0.f), fmaxf(f0.w, 0.f),
                             fmaxf(f1.x, 0.f), fmaxf(f1.y, 0.f), fmaxf(f1.z, 0.f), fmaxf(f1.w, 0.f)};
        unsigned long long ph0 = 0, pl0 = 0, ph1 = 0, pl1 = 0;
#pragma unroll
        for (int t = 0; t < 4; t++) {
            const unsigned short hb = f2bf(fv[t]);
            const unsigned short lb = f2bf(fv[t] - bf2f(hb));
            ph0 |= (unsigned long long)hb << (16 * t);
            pl0 |= (unsigned long long)lb << (16 * t);
        }
#pragma unroll
        for (int t = 0; t < 4; t++) {
            const unsigned short hb = f2bf(fv[4 + t]);
            const unsigned short lb = f2bf(fv[4 + t] - bf2f(hb));
            ph1 |= (unsigned long long)hb << (16 * t);
            pl1 |= (unsigned long long)lb << (16 * t);
        }
        *(unsigned long long*)&ehi[w][j * ROWS + q * 8]     = ph0;
        *(unsigned long long*)&ehi[w][j * ROWS + q * 8 + 4] = ph1;
        *(unsigned long long*)&elo[w][j * ROWS + q * 8]     = pl0;
        *(unsigned long long*)&elo[w][j * ROWS + q * 8 + 4] = pl1;
    }
    __syncthreads();

    const int aoff = rr * ROWS + kg * 8;
    const bf16x8s Ah = *(const bf16x8s*)&ehi[w][aoff];
    const bf16x8s Al = *(const bf16x8s*)&elo[w][aoff];
    f32x4 q = {0.f, 0.f, 0.f, 0.f};
    q = __builtin_amdgcn_mfma_f32_16x16x32_bf16(Ah, Bh, q, 0, 0, 0);
    q = __builtin_amdgcn_mfma_f32_16x16x32_bf16(Ah, Bl, q, 0, 0, 0);
    q = __builtin_amdgcn_mfma_f32_16x16x32_bf16(Al, Bh, q, 0, 0, 0);

    if (rr < 13) {
        const float bv = (rr < 12) ? intb[rr] : impb[0];
#pragma unroll
        for (int r = 0; r < 4; r++) {
            const int e = e0 + kg * 4 + r;
            const int s = ei[e], d = ei[kE + e];
            const float val = q[r] + P[s * 32 + rr] + P[d * 32 + 16 + rr] + bv;
            if (rr < 12) out[(size_t)e * 12 + rr] = val;
            else         out[(size_t)kE * 12 + e] = 1.f / (1.f + __expf(-val));
        }
    }
}

// ---------------- launch ----------------
extern "C" void kernel_launch(void* const* d_in, const int* in_sizes, int n_in,
                              void* d_out, int out_size, void* d_ws, size_t ws_size,
                              hipStream_t stream)
{
    (void)in_sizes; (void)n_in; (void)out_size; (void)ws_size;

    const float* x      = (const float*)d_in[0];
    const int*   ei     = (const int*)d_in[1];
    const float* ea     = (const float*)d_in[2];
    const float* emb_W  = (const float*)d_in[3];
    const float* emb_b  = (const float*)d_in[4];
    const float* g1_Wl  = (const float*)d_in[5];
    const float* g1_bl  = (const float*)d_in[6];
    const float* g1_Wr  = (const float*)d_in[7];
    const float* g1_br  = (const float*)d_in[8];
    const float* g1_We  = (const float*)d_in[9];
    const float* g1_att = (const float*)d_in[10];
    const float* g1_bias= (const float*)d_in[11];
    const float* g2_Wl  = (const float*)d_in[12];
    const float* g2_bl  = (const float*)d_in[13];
    const float* g2_Wr  = (const float*)d_in[14];
    const float* g2_br  = (const float*)d_in[15];
    const float* g2_We  = (const float*)d_in[16];
    const float* g2_att = (const float*)d_in[17];
    const float* g2_bias= (const float*)d_in[18];
    const float* int_W  = (const float*)d_in[19];
    const float* int_b  = (const float*)d_in[20];
    const float* imp_W  = (const float*)d_in[21];
    const float* imp_b  = (const float*)d_in[22];

    char* ws = (char*)d_ws;
    float* eapart  = (float*)(ws + OFF_EAPART);
    float* eamean  = (float*)(ws + OFF_EAMEAN);
    int*   counts  = (int*)  (ws + OFF_COUNTS);
    int*   offs    = (int*)  (ws + OFF_OFFS);
    int*   cursor  = (int*)  (ws + OFF_CURSOR);
    int*   csrsrc  = (int*)  (ws + OFF_CSRSRC);
    int*   csreid  = (int*)  (ws + OFF_CSREID);
    int*   csrdst  = (int*)  (ws + OFF_CSRDST);
    float* pe      = (float*)(ws + OFF_PE);
    float* h_a     = (float*)(ws + OFF_HA);
    float* h_b     = (float*)(ws + OFF_HB);
    float* xl      = (float*)(ws + OFF_XL);
    float* xr      = (float*)(ws + OFF_XR);
    unsigned short* f1h = (unsigned short*)(ws + OFF_F1H);
    unsigned short* f1l = (unsigned short*)(ws + OFF_F1L);
    unsigned short* f2h = (unsigned short*)(ws + OFF_F2H);
    unsigned short* f2l = (unsigned short*)(ws + OFF_F2L);
    unsigned short* wembh = (unsigned short*)(ws + OFF_WEMBH);
    unsigned short* wembl = (unsigned short*)(ws + OFF_WEMBL);
    unsigned short* wl1h  = (unsigned short*)(ws + OFF_WL1H);
    unsigned short* wl1l  = (unsigned short*)(ws + OFF_WL1L);
    unsigned short* wr1h  = (unsigned short*)(ws + OFF_WR1H);
    unsigned short* wr1l  = (unsigned short*)(ws + OFF_WR1L);
    unsigned short* wl2h  = (unsigned short*)(ws + OFF_WL2H);
    unsigned short* wl2l  = (unsigned short*)(ws + OFF_WL2L);
    unsigned short* wr2h  = (unsigned short*)(ws + OFF_WR2H);
    unsigned short* wr2l  = (unsigned short*)(ws + OFF_WR2L);
    float* P       = pe;                      // reuse pe region after last aggr
    float* outp    = (float*)d_out;

    constexpr int NT = (kTaug + 31) / 32;     // 13282 edge tiles
    constexpr int NGB = (kN + 63) / 64;       // 391 row blocks for MFMA gemms

    // edge_attr mean + We frag-swizzled bf16 splits + GEMM weight tables
    ea_colsum_part<<<1024, 256, 0, stream>>>(ea, eapart);
    ea_colsum_final<<<1, 256, 0, stream>>>(eapart, eamean);
    we_swizzle<<<32, 256, 0, stream>>>(g1_We, g2_We, f1h, f1l, f2h, f2l);
    w_swizzle_tab<<<32, 256, 0, stream>>>(emb_W, 64, 4, 4, wembh, wembl);
    w_swizzle_tab<<<32, 256, 0, stream>>>(g1_Wl, 256, 16, 2, wl1h, wl1l);
    w_swizzle_tab<<<32, 256, 0, stream>>>(g1_Wr, 256, 16, 2, wr1h, wr1l);
    w_swizzle_tab<<<32, 256, 0, stream>>>(g2_Wl, 256, 16, 2, wl2h, wl2l);
    w_swizzle_tab<<<32, 256, 0, stream>>>(g2_Wr, 256, 16, 2, wr2h, wr2l);

    // CSR by destination (self-loops included)
    init_counts<<<(kN + 255) / 256, 256, 0, stream>>>(counts);
    count_edges<<<(kE + 255) / 256, 256, 0, stream>>>(ei, counts);
    scan_kernel<<<1, 1024, 0, stream>>>(counts, offs, cursor);
    scatter_kernel<<<(kE + kN + 255) / 256, 256, 0, stream>>>(ei, cursor, csrsrc, csreid, csrdst);

    // node embedding (MFMA split-bf16)
    mfma_gemm_bias<128, 64><<<NGB, 256, 0, stream>>>(x, wembh, wembl, emb_b, h_a, kN);

    // ---- GAT layer 1 ----
    mfma_gemm_bias<64, 256><<<NGB, 256, 0, stream>>>(h_a, wl1h, wl1l, g1_bl, xl, kN);
    mfma_gemm_bias<64, 256><<<NGB, 256, 0, stream>>>(h_a, wr1h, wr1l, g1_br, xr, kN);
    edge_logit_kernel<<<NT, 256, 0, stream>>>(xl, xr, ea, eamean, f1h, f1l, g1_att,
                                              csrsrc, csrdst, csreid, pe);
    gat_aggr_kernel<<<kN, 256, 0, stream>>>(xl, pe, csrsrc, offs, g1_bias, h_b);

    // ---- GAT layer 2 ----
    mfma_gemm_bias<64, 256><<<NGB, 256, 0, stream>>>(h_b, wl2h, wl2l, g2_bl, xl, kN);
    mfma_gemm_bias<64, 256><<<NGB, 256, 0, stream>>>(h_b, wr2h, wr2l, g2_br, xr, kN);
    edge_logit_kernel<<<NT, 256, 0, stream>>>(xl, xr, ea, eamean, f2h, f2l, g2_att,
                                              csrsrc, csrdst, csreid, pe);
    gat_aggr_kernel<<<kN, 256, 0, stream>>>(xl, pe, csrsrc, offs, g2_bias, h_a);

    // ---- edge heads (decomposed) ----
    node_head_kernel<<<(kN + 63) / 64, 256, 0, stream>>>(h_a, int_W, imp_W, P);
    edge_out_kernel<<<kE / 64, 256, 0, stream>>>(ea, ei, P, int_W, int_b, imp_W, imp_b, outp);
}

// Round 11
// 496.729 us; speedup vs baseline: 1.4605x; 1.1512x over previous
//
#include <hip/hip_runtime.h>
#include <math.h>

// Problem constants
constexpr int kN = 25000;
constexpr int kE = 400000;
constexpr int kTaug = kE + kN;        // CSR slots incl self-loops = 425000

typedef __attribute__((ext_vector_type(8))) short bf16x8s;   // 8 bf16 (4 VGPRs)
typedef __attribute__((ext_vector_type(4))) float f32x4;

__device__ __forceinline__ unsigned short f2bf(float f) {
    unsigned u = __builtin_bit_cast(unsigned, f);
    unsigned r = (u + 0x7FFFu + ((u >> 16) & 1u)) >> 16;     // RNE
    return (unsigned short)r;
}
__device__ __forceinline__ float bf2f(unsigned short h) {
    unsigned u = ((unsigned)h) << 16;
    return __builtin_bit_cast(float, u);
}

// DPP helpers (CTRL must be compile-time constant)
template<int CTRL>
__device__ __forceinline__ float dpp_mov(float x) {
    int yi = __builtin_amdgcn_update_dpp(0, __builtin_bit_cast(int, x), CTRL, 0xF, 0xF, true);
    return __builtin_bit_cast(float, yi);
}
template<int CTRL>
__device__ __forceinline__ float dpp_add(float x) {
    return x + dpp_mov<CTRL>(x);
}

// ---------------- workspace layout (256B aligned) ----------------
constexpr size_t OFF_EAPART = 0;          // 1024*32 f32
constexpr size_t OFF_EAMEAN = 131072;     // 32 f32
constexpr size_t OFF_COUNTS = 131328;     // N i32
constexpr size_t OFF_OFFS   = 231424;     // N+1 i32
constexpr size_t OFF_CURSOR = 331520;     // N i32
constexpr size_t OFF_CSRSRC = 431616;     // Taug i32
constexpr size_t OFF_CSREID = 2131712;    // Taug i32
constexpr size_t OFF_CSRDST = 3831808;    // Taug i32
constexpr size_t OFF_ACC    = 5531904;    // N*256 f32 = 25600000 (atomic acc; reused as P)
constexpr size_t OFF_DEN    = 31131904;   // N*4 f32 (contiguous with ACC for one memset)
constexpr size_t OFF_HA     = 31532032;   // N*64 f32
constexpr size_t OFF_HB     = 37932032;   // N*64 f32
constexpr size_t OFF_XL     = 44332032;   // N*256 f32
constexpr size_t OFF_XR     = 69932032;   // N*256 f32
constexpr size_t OFF_F1H    = 95532032;   // 4*4*64*8 u16 = 16384 (frag-swizzled We)
constexpr size_t OFF_F1L    = 95548416;
constexpr size_t OFF_F2H    = 95564800;
constexpr size_t OFF_F2L    = 95581184;
// GEMM weight frag tables (32KB slots)
constexpr size_t OFF_WEMBH  = 95597568;
constexpr size_t OFF_WEMBL  = 95630336;
constexpr size_t OFF_WL1H   = 95663104;
constexpr size_t OFF_WL1L   = 95695872;
constexpr size_t OFF_WR1H   = 95728640;
constexpr size_t OFF_WR1L   = 95761408;
constexpr size_t OFF_WL2H   = 95794176;
constexpr size_t OFF_WL2L   = 95826944;
constexpr size_t OFF_WR2H   = 95859712;
constexpr size_t OFF_WR2L   = 95892480;   // end ~95.9 MB
constexpr size_t ACCDEN_BYTES = OFF_HA - OFF_ACC;   // acc + den in one memset

// ---------------- edge_attr column mean ----------------
__global__ __launch_bounds__(256) void ea_colsum_part(const float* __restrict__ ea,
                                                      float* __restrict__ part)
{
    __shared__ float lds[256];
    const int tid = threadIdx.x;
    const int k = tid & 31, g = tid >> 5;
    float acc = 0.f;
    for (int r = blockIdx.x * 8 + g; r < kE; r += gridDim.x * 8)
        acc += ea[(size_t)r * 32 + k];
    lds[tid] = acc; __syncthreads();
    if (tid < 128) lds[tid] += lds[tid + 128]; __syncthreads();
    if (tid < 64)  lds[tid] += lds[tid + 64];  __syncthreads();
    if (tid < 32)  part[blockIdx.x * 32 + k] = lds[tid] + lds[tid + 32];
}

__global__ __launch_bounds__(256) void ea_colsum_final(const float* __restrict__ part,
                                                       float* __restrict__ ea_mean)
{
    __shared__ float lds[256];
    const int tid = threadIdx.x;
    const int k = tid & 31, g = tid >> 5;
    float acc = 0.f;
    for (int p = g; p < 1024; p += 8) acc += part[p * 32 + k];
    lds[tid] = acc; __syncthreads();
    if (tid < 128) lds[tid] += lds[tid + 128]; __syncthreads();
    if (tid < 64)  lds[tid] += lds[tid + 64];  __syncthreads();
    if (tid < 32)  ea_mean[k] = (lds[tid] + lds[tid + 32]) * (1.0f / (float)kE);
}

// ---------------- We -> frag-swizzled bf16 hi/lo (edge_logit tables) ----------------
__global__ __launch_bounds__(256) void we_swizzle(const float* __restrict__ W1,
                                                  const float* __restrict__ W2,
                                                  unsigned short* __restrict__ f1h,
                                                  unsigned short* __restrict__ f1l,
                                                  unsigned short* __restrict__ f2h,
                                                  unsigned short* __restrict__ f2l)
{
    const int b = blockIdx.x;                 // 32 blocks: layer*16 + nt*4 + w
    const int layer = b >> 4, nt = (b >> 2) & 3, w = b & 3;
    const float* W = layer ? W2 : W1;
    unsigned short* H = layer ? f2h : f1h;
    unsigned short* L = layer ? f2l : f1l;
    const int tid = threadIdx.x;
    const int lane = tid & 63, jh = tid >> 6;
    const int c = w * 64 + nt * 16 + (lane & 15);
    const int kbase = (lane >> 4) * 8;
#pragma unroll
    for (int t = 0; t < 2; t++) {
        const int j = jh * 2 + t;
        const float f = W[(kbase + j) * 256 + c];
        const unsigned short hb = f2bf(f);
        const int idx = ((nt * 4 + w) * 64 + lane) * 8 + j;
        H[idx] = hb;
        L[idx] = f2bf(f - bf2f(hb));
    }
}

// ---------------- generic GEMM-weight frag table ----------------
__global__ __launch_bounds__(256) void w_swizzle_tab(const float* __restrict__ W,
                                                     int KO, int CTILES, int KCH,
                                                     unsigned short* __restrict__ H,
                                                     unsigned short* __restrict__ L)
{
    const int total = CTILES * KCH * 64 * 8;
    for (int idx = blockIdx.x * 256 + threadIdx.x; idx < total; idx += gridDim.x * 256) {
        const int j = idx & 7;
        const int lane = (idx >> 3) & 63;
        const int t = idx >> 9;               // ct*KCH + kk
        const int ct = t / KCH;
        const int c = ct * 16 + (lane & 15);
        const int k = (t - ct * KCH) * 32 + (lane >> 4) * 8 + j;
        const float f = W[k * KO + c];
        const unsigned short hb = f2bf(f);
        H[idx] = hb;
        L[idx] = f2bf(f - bf2f(hb));
    }
}

// ---------------- MFMA dense GEMM: out[M,KO] = A[M,KI]@W + bias (split-bf16 x3) ----------------
// R10: CSPLIT column groups per row block for grid parallelism (391 blocks was 1.5/CU).
template<int KI, int KO, int CSPLIT>
__global__ __launch_bounds__(256) void mfma_gemm_bias(
    const float* __restrict__ A,
    const unsigned short* __restrict__ WH, const unsigned short* __restrict__ WL,
    const float* __restrict__ bias, float* __restrict__ out, int M)
{
    constexpr int KCH = KI / 32;
    constexpr int CT  = KO / 16;
    constexpr int CTP = CT / CSPLIT;
    const int tid = threadIdx.x;
    const int w = tid >> 6, lane = tid & 63;
    const int rowblk = blockIdx.x / CSPLIT;
    const int csel   = blockIdx.x % CSPLIT;
    const int row0 = rowblk * 64 + w * 16;
    const int rr = lane & 15, kg = lane >> 4;
    const int arow = min(row0 + rr, M - 1);

    bf16x8s Ah[KCH], Al[KCH];
#pragma unroll
    for (int kk = 0; kk < KCH; kk++) {
        const float4 f0 = *(const float4*)&A[(size_t)arow * KI + kk * 32 + kg * 8];
        const float4 f1 = *(const float4*)&A[(size_t)arow * KI + kk * 32 + kg * 8 + 4];
        const float fv[8] = {f0.x, f0.y, f0.z, f0.w, f1.x, f1.y, f1.z, f1.w};
#pragma unroll
        for (int j = 0; j < 8; j++) {
            const unsigned short hb = f2bf(fv[j]);
            Ah[kk][j] = (short)hb;
            Al[kk][j] = (short)f2bf(fv[j] - bf2f(hb));
        }
    }
    const int rbase = kg * 4;
#pragma unroll
    for (int cti = 0; cti < CTP; cti++) {
        const int ct = csel * CTP + cti;
        f32x4 acc = {0.f, 0.f, 0.f, 0.f};
#pragma unroll
        for (int kk = 0; kk < KCH; kk++) {
            const int bidx = ((ct * KCH + kk) * 64 + lane) * 8;
            const bf16x8s Bh = *(const bf16x8s*)&WH[bidx];
            const bf16x8s Bl = *(const bf16x8s*)&WL[bidx];
            acc = __builtin_amdgcn_mfma_f32_16x16x32_bf16(Ah[kk], Bh, acc, 0, 0, 0);
            acc = __builtin_amdgcn_mfma_f32_16x16x32_bf16(Ah[kk], Bl, acc, 0, 0, 0);
            acc = __builtin_amdgcn_mfma_f32_16x16x32_bf16(Al[kk], Bh, acc, 0, 0, 0);
        }
        const float bv = bias[ct * 16 + rr];
#pragma unroll
        for (int r = 0; r < 4; r++) {
            const int row = row0 + rbase + r;
            if (row < M) out[(size_t)row * KO + ct * 16 + rr] = acc[r] + bv;
        }
    }
}

// ---------------- CSR build ----------------
__global__ __launch_bounds__(256) void init_counts(int* __restrict__ counts)
{
    int i = blockIdx.x * 256 + threadIdx.x;
    if (i < kN) counts[i] = 1;   // self-loop pre-counted
}

__global__ __launch_bounds__(256) void count_edges(const int* __restrict__ ei,
                                                   int* __restrict__ counts)
{
    int e = blockIdx.x * 256 + threadIdx.x;
    if (e < kE) atomicAdd(&counts[ei[kE + e]], 1);
}

__global__ __launch_bounds__(1024) void scan_kernel(const int* __restrict__ counts,
                                                    int* __restrict__ offsets,
                                                    int* __restrict__ cursor)
{
    __shared__ int lds[1024];
    const int tid = threadIdx.x;
    const int base = tid * 25;
    int local = 0;
#pragma unroll 5
    for (int i = 0; i < 25; i++) {
        int idx = base + i;
        if (idx < kN) local += counts[idx];
    }
    lds[tid] = local; __syncthreads();
    for (int d = 1; d < 1024; d <<= 1) {
        int t = (tid >= d) ? lds[tid - d] : 0;
        __syncthreads();
        lds[tid] += t;
        __syncthreads();
    }
    int run = lds[tid] - local;   // exclusive prefix
    for (int i = 0; i < 25; i++) {
        int idx = base + i;
        if (idx < kN) {
            offsets[idx] = run;
            cursor[idx]  = run;
            run += counts[idx];
        }
    }
    if (tid == 1023) offsets[kN] = lds[1023];
}

__global__ __launch_bounds__(256) void scatter_kernel(const int* __restrict__ ei,
                                                      int* __restrict__ cursor,
                                                      int* __restrict__ csr_src,
                                                      int* __restrict__ csr_eid,
                                                      int* __restrict__ csr_dst)
{
    int gid = blockIdx.x * 256 + threadIdx.x;
    if (gid < kE) {
        int s = ei[gid];
        int d = ei[kE + gid];
        int p = atomicAdd(&cursor[d], 1);
        csr_src[p] = s;
        csr_eid[p] = gid;
        csr_dst[p] = d;
    } else if (gid < kE + kN) {
        int n = gid - kE;
        int p = atomicAdd(&cursor[n], 1);
        csr_src[p] = n;
        csr_eid[p] = kE;   // sentinel: self-loop
        csr_dst[p] = n;
    }
}

// ---------------- Fused pass: per-edge attention + per-node aggregation ----------------
// R10: while xl[src] rows are in registers, broadcast pe back to all lanes
// (7-op inverse butterfly) and do the segmented scatter-add here — removes the
// gat_aggr kernel's 435MB xl re-gather and the pe round-trip entirely.
// Value identity after exchange reduce: u = (l&3)|((l&32)>>3) (validated R8).
__global__ __launch_bounds__(256) void edge_logit_aggr_kernel(
    const float* __restrict__ xl, const float* __restrict__ xr,
    const float* __restrict__ ea, const float* __restrict__ eamean,
    const unsigned short* __restrict__ fragh, const unsigned short* __restrict__ fragl,
    const float* __restrict__ att,
    const int* __restrict__ csr_src, const int* __restrict__ csr_dst,
    const int* __restrict__ csr_eid,
    float* __restrict__ accbuf, float* __restrict__ denbuf)
{
    constexpr int ROWS = 40;                       // padded ea row (shorts), 80B
    constexpr int EPP  = 257;                      // padded ep row (floats), 16-edge half
    __shared__ __align__(16) unsigned short ea_hi[32 * ROWS];
    __shared__ __align__(16) unsigned short ea_lo[32 * ROWS];
    __shared__ __align__(16) float ep_lds[16 * EPP];
    __shared__ __align__(16) int s_src[32];
    __shared__ __align__(16) int s_dst[32];
    const int tid  = threadIdx.x;
    const int w    = tid >> 6;
    const int lane = tid & 63;
    const int b0   = blockIdx.x * 32;

    // B fragments: 8 coalesced b128 loads from pre-swizzled tables
    bf16x8s bh[4], bl[4];
#pragma unroll
    for (int nt = 0; nt < 4; nt++) {
        const int idx = ((nt * 4 + w) * 64 + lane) * 8;
        bh[nt] = *(const bf16x8s*)&fragh[idx];
        bl[nt] = *(const bf16x8s*)&fragl[idx];
    }
    const float att_r = att[tid];
    const int aoff  = (lane & 15) * ROWS + (lane >> 4) * 8;
    const int cbase = w * 64 + (lane & 15);
    const int rbase = (lane >> 4) * 4;

    // stage indices + ea rows (clamped: tail tile duplicates last valid slot)
    if (tid < 32) {
        const int p = min(b0 + tid, kTaug - 1);
        s_src[tid] = csr_src[p];
        s_dst[tid] = csr_dst[p];
    }
    {
        const int j = tid >> 3, q = tid & 7;
        const int eid = csr_eid[min(b0 + j, kTaug - 1)];
        const float4* srcp = (eid < kE) ? (const float4*)(ea + (size_t)eid * 32)
                                        : (const float4*)eamean;
        const float4 f = srcp[q];
        const unsigned short h0 = f2bf(f.x), h1 = f2bf(f.y),
                             h2 = f2bf(f.z), h3 = f2bf(f.w);
        const unsigned short g0 = f2bf(f.x - bf2f(h0)), g1 = f2bf(f.y - bf2f(h1)),
                             g2 = f2bf(f.z - bf2f(h2)), g3 = f2bf(f.w - bf2f(h3));
        const unsigned long long ph =
            (unsigned long long)h0 | ((unsigned long long)h1 << 16) |
            ((unsigned long long)h2 << 32) | ((unsigned long long)h3 << 48);
        const unsigned long long pl =
            (unsigned long long)g0 | ((unsigned long long)g1 << 16) |
            ((unsigned long long)g2 << 32) | ((unsigned long long)g3 << 48);
        *(unsigned long long*)&ea_hi[j * ROWS + q * 4] = ph;
        *(unsigned long long*)&ea_lo[j * ROWS + q * 4] = pl;
    }
    __syncthreads();

    int   cur_dst = s_dst[0];
    float den_p = 0.f, acc_p = 0.f;

#pragma unroll
    for (int half = 0; half < 2; half++) {
        // MFMA for this half only (keeps acc register pressure at 16)
        const bf16x8s ah = *(const bf16x8s*)&ea_hi[half * 16 * ROWS + aoff];
        const bf16x8s al = *(const bf16x8s*)&ea_lo[half * 16 * ROWS + aoff];
#pragma unroll
        for (int nt = 0; nt < 4; nt++) {
            f32x4 a = {0.f, 0.f, 0.f, 0.f};
            a = __builtin_amdgcn_mfma_f32_16x16x32_bf16(ah, bh[nt], a, 0, 0, 0);
            a = __builtin_amdgcn_mfma_f32_16x16x32_bf16(ah, bl[nt], a, 0, 0, 0);
            a = __builtin_amdgcn_mfma_f32_16x16x32_bf16(al, bh[nt], a, 0, 0, 0);
            const int cc = cbase + nt * 16;
#pragma unroll
            for (int r = 0; r < 4; r++)
                ep_lds[(rbase + r) * EPP + cc] = a[r];
        }
        __syncthreads();

#pragma unroll
        for (int bb = 0; bb < 2; bb++) {           // 2 batches of 8 edges per half
            const int e0 = half * 16 + bb * 8;
            int sv[8], dv[8];
            {
                const int4 ss0 = *(const int4*)&s_src[e0];
                const int4 ss1 = *(const int4*)&s_src[e0 + 4];
                sv[0]=ss0.x; sv[1]=ss0.y; sv[2]=ss0.z; sv[3]=ss0.w;
                sv[4]=ss1.x; sv[5]=ss1.y; sv[6]=ss1.z; sv[7]=ss1.w;
                const int4 dd0 = *(const int4*)&s_dst[e0];
                const int4 dd1 = *(const int4*)&s_dst[e0 + 4];
                dv[0]=dd0.x; dv[1]=dd0.y; dv[2]=dd0.z; dv[3]=dd0.w;
                dv[4]=dd1.x; dv[5]=dd1.y; dv[6]=dd1.z; dv[7]=dd1.w;
            }
            float xls[8], c[8];
#pragma unroll
            for (int u = 0; u < 8; u++) xls[u] = xl[sv[u] * 256 + tid];
#pragma unroll
            for (int u = 0; u < 8; u++) {
                const float xrr = xr[dv[u] * 256 + tid];
                float v = xls[u] + xrr + ep_lds[(bb * 8 + u) * EPP + tid];
                v = fmaxf(v, 0.2f * v);            // leaky_relu 0.2 (slope<1)
                c[u] = att_r * v;
            }

            // multi-value exchange reduce: 8 sums in 6 cross-lane steps (R8)
            float n0, n1, n2, n3;
            {   const bool s = lane & 1;
                n0 = (s ? c[1] : c[0]) + dpp_mov<0xB1>(s ? c[0] : c[1]);
                n1 = (s ? c[3] : c[2]) + dpp_mov<0xB1>(s ? c[2] : c[3]);
                n2 = (s ? c[5] : c[4]) + dpp_mov<0xB1>(s ? c[4] : c[5]);
                n3 = (s ? c[7] : c[6]) + dpp_mov<0xB1>(s ? c[6] : c[7]);
            }
            float m0, m1;
            {   const bool s = lane & 2;
                m0 = (s ? n1 : n0) + dpp_mov<0x4E>(s ? n0 : n1);
                m1 = (s ? n3 : n2) + dpp_mov<0x4E>(s ? n2 : n3);
            }
            float r;
            {   const bool s = lane & 32;
                const float oth = __shfl_xor(s ? m0 : m1, 32);
                r = (s ? m1 : m0) + oth;
            }
            r = dpp_add<0x124>(r);                 // row_ror:4
            r = dpp_add<0x128>(r);                 // row_ror:8
            r += __shfl_xor(r, 16);
            // lane now holds full logit for edge u0 = (l&3)|((l&32)>>3)
            const float pe_r = __expf(r);

            // inverse-butterfly broadcast: all lanes get pe[0..7]
            float pu[8];
            {
                const float o1 = dpp_mov<0xB1>(pe_r);
                const float a0 = (lane & 1) ? o1 : pe_r;   // u bit0 = 0
                const float a1 = (lane & 1) ? pe_r : o1;   // u bit0 = 1
                const float oa0 = dpp_mov<0x4E>(a0);
                const float oa1 = dpp_mov<0x4E>(a1);
                const float b00 = (lane & 2) ? oa0 : a0;   // b1=0,b0=0
                const float b01 = (lane & 2) ? oa1 : a1;   // b1=0,b0=1
                const float b10 = (lane & 2) ? a0 : oa0;   // b1=1,b0=0
                const float b11 = (lane & 2) ? a1 : oa1;   // b1=1,b0=1
                const float ob00 = __shfl_xor(b00, 32);
                const float ob01 = __shfl_xor(b01, 32);
                const float ob10 = __shfl_xor(b10, 32);
                const float ob11 = __shfl_xor(b11, 32);
                const bool hi = lane & 32;
                pu[0] = hi ? ob00 : b00;  pu[4] = hi ? b00 : ob00;
                pu[1] = hi ? ob01 : b01;  pu[5] = hi ? b01 : ob01;
                pu[2] = hi ? ob10 : b10;  pu[6] = hi ? b10 : ob10;
                pu[3] = hi ? ob11 : b11;  pu[7] = hi ? b11 : ob11;
            }
            // tail mask (only the final tile pays this branch)
            if (b0 + e0 + 8 > kTaug) {
#pragma unroll
                for (int u = 0; u < 8; u++)
                    if (b0 + e0 + u >= kTaug) pu[u] = 0.f;
            }
            // segmented accumulate (dst runs are contiguous in CSR order;
            // dv is wave-uniform so the flush branch is uniform)
#pragma unroll
            for (int u = 0; u < 8; u++) {
                if (dv[u] != cur_dst) {
                    atomicAdd(&accbuf[(size_t)cur_dst * 256 + tid], acc_p);
                    if (lane == 0) atomicAdd(&denbuf[cur_dst * 4 + w], den_p);
                    acc_p = 0.f; den_p = 0.f; cur_dst = dv[u];
                }
                acc_p += pu[u] * xls[u];
                den_p += pu[u];
            }
        }
        __syncthreads();                           // ep_lds reuse
    }

    // final flush
    atomicAdd(&accbuf[(size_t)cur_dst * 256 + tid], acc_p);
    if (lane == 0) atomicAdd(&denbuf[cur_dst * 4 + w], den_p);
}

// ---------------- finalize: h = relu(mean_h(acc/den) + bias) ----------------
__global__ __launch_bounds__(256) void gat_finalize(
    const float* __restrict__ accbuf, const float* __restrict__ denbuf,
    const float* __restrict__ gbias, float* __restrict__ h_out)
{
    __shared__ float red[256];
    const int tid = threadIdx.x;
    const int n = blockIdx.x;
    red[tid] = accbuf[(size_t)n * 256 + tid] / denbuf[n * 4 + (tid >> 6)];
    __syncthreads();
    if (tid < 64) {
        float sres = red[tid] + red[tid + 64] + red[tid + 128] + red[tid + 192];
        h_out[n * 64 + tid] = fmaxf(0.25f * sres + gbias[tid], 0.f);
    }
}

// ---------------- node head: P[n][0:16]=h@W13[0:64], P[n][16:32]=h@W13[64:128] ----------------
__global__ __launch_bounds__(256) void node_head_kernel(
    const float* __restrict__ h, const float* __restrict__ intW,
    const float* __restrict__ impW, float* __restrict__ P)
{
    const int tid = threadIdx.x;
    const int w = tid >> 6, lane = tid & 63;
    const int row0 = blockIdx.x * 64 + w * 16;
    const int rr = lane & 15;             // A-row / B-col / C-col
    const int kg = lane >> 4;             // k-group

    bf16x8s Bh[2][2], Bl[2][2];
#pragma unroll
    for (int ct = 0; ct < 2; ct++) {
#pragma unroll
        for (int kk = 0; kk < 2; kk++) {
            const int kbase = ct * 64 + kk * 32 + kg * 8;
#pragma unroll
            for (int j = 0; j < 8; j++) {
                const int k = kbase + j;
                float wv;
                if (rr < 12)       wv = intW[k * 12 + rr];
                else if (rr == 12) wv = impW[k];
                else               wv = 0.f;
                const unsigned short hb = f2bf(wv);
                Bh[ct][kk][j] = (short)hb;
                Bl[ct][kk][j] = (short)f2bf(wv - bf2f(hb));
            }
        }
    }

    const int arow = min(row0 + rr, kN - 1);
    bf16x8s Ah[2], Al[2];
#pragma unroll
    for (int kk = 0; kk < 2; kk++) {
        const float4 f0 = *(const float4*)&h[arow * 64 + kk * 32 + kg * 8];
        const float4 f1 = *(const float4*)&h[arow * 64 + kk * 32 + kg * 8 + 4];
        const float fv[8] = {f0.x, f0.y, f0.z, f0.w, f1.x, f1.y, f1.z, f1.w};
#pragma unroll
        for (int j = 0; j < 8; j++) {
            const unsigned short hb = f2bf(fv[j]);
            Ah[kk][j] = (short)hb;
            Al[kk][j] = (short)f2bf(fv[j] - bf2f(hb));
        }
    }

#pragma unroll
    for (int ct = 0; ct < 2; ct++) {
        f32x4 acc = {0.f, 0.f, 0.f, 0.f};
#pragma unroll
        for (int kk = 0; kk < 2; kk++) {
            acc = __builtin_amdgcn_mfma_f32_16x16x32_bf16(Ah[kk], Bh[ct][kk], acc, 0, 0, 0);
            acc = __builtin_amdgcn_mfma_f32_16x16x32_bf16(Ah[kk], Bl[ct][kk], acc, 0, 0, 0);
            acc = __builtin_amdgcn_mfma_f32_16x16x32_bf16(Al[kk], Bh[ct][kk], acc, 0, 0, 0);
        }
        const int crow0 = kg * 4;
#pragma unroll
        for (int r = 0; r < 4; r++) {
            const int row = row0 + crow0 + r;
            if (row < kN) P[row * 32 + ct * 16 + rr] = acc[r];
        }
    }
}

// ---------------- edge out: Q = relu(ea)@W13[128:160]; out = Q + P_src + P_dst + b ----------------
__global__ __launch_bounds__(256) void edge_out_kernel(
    const float* __restrict__ ea, const int* __restrict__ ei,
    const float* __restrict__ P,
    const float* __restrict__ intW, const float* __restrict__ intb,
    const float* __restrict__ impW, const float* __restrict__ impb,
    float* __restrict__ out)
{
    constexpr int ROWS = 40;
    __shared__ __align__(16) unsigned short ehi[4][16 * ROWS];
    __shared__ __align__(16) unsigned short elo[4][16 * ROWS];
    const int tid = threadIdx.x;
    const int w = tid >> 6, lane = tid & 63;
    const int e0 = blockIdx.x * 64 + w * 16;
    const int rr = lane & 15, kg = lane >> 4;

    bf16x8s Bh, Bl;
#pragma unroll
    for (int j = 0; j < 8; j++) {
        const int k = 128 + kg * 8 + j;
        float wv;
        if (rr < 12)       wv = intW[k * 12 + rr];
        else if (rr == 12) wv = impW[k];
        else               wv = 0.f;
        const unsigned short hb = f2bf(wv);
        Bh[j] = (short)hb;
        Bl[j] = (short)f2bf(wv - bf2f(hb));
    }

    {
        const int j = lane >> 2, q = lane & 3;
        const float4* src = (const float4*)&ea[(size_t)(e0 + j) * 32 + q * 8];
        const float4 f0 = src[0], f1 = src[1];
        const float fv[8] = {fmaxf(f0.x, 0.f), fmaxf(f0.y, 0.f), fmaxf(f0.z, 0.f), fmaxf(f0.w, 0.f),
                             fmaxf(f1.x, 0.f), fmaxf(f1.y, 0.f), fmaxf(f1.z, 0.f), fmaxf(f1.w, 0.f)};
        unsigned long long ph0 = 0, pl0 = 0, ph1 = 0, pl1 = 0;
#pragma unroll
        for (int t = 0; t < 4; t++) {
            const unsigned short hb = f2bf(fv[t]);
            const unsigned short lb = f2bf(fv[t] - bf2f(hb));
            ph0 |= (unsigned long long)hb << (16 * t);
            pl0 |= (unsigned long long)lb << (16 * t);
        }
#pragma unroll
        for (int t = 0; t < 4; t++) {
            const unsigned short hb = f2bf(fv[4 + t]);
            const unsigned short lb = f2bf(fv[4 + t] - bf2f(hb));
            ph1 |= (unsigned long long)hb << (16 * t);
            pl1 |= (unsigned long long)lb << (16 * t);
        }
        *(unsigned long long*)&ehi[w][j * ROWS + q * 8]     = ph0;
        *(unsigned long long*)&ehi[w][j * ROWS + q * 8 + 4] = ph1;
        *(unsigned long long*)&elo[w][j * ROWS + q * 8]     = pl0;
        *(unsigned long long*)&elo[w][j * ROWS + q * 8 + 4] = pl1;
    }
    __syncthreads();

    const int aoff = rr * ROWS + kg * 8;
    const bf16x8s Ah = *(const bf16x8s*)&ehi[w][aoff];
    const bf16x8s Al = *(const bf16x8s*)&elo[w][aoff];
    f32x4 q = {0.f, 0.f, 0.f, 0.f};
    q = __builtin_amdgcn_mfma_f32_16x16x32_bf16(Ah, Bh, q, 0, 0, 0);
    q = __builtin_amdgcn_mfma_f32_16x16x32_bf16(Ah, Bl, q, 0, 0, 0);
    q = __builtin_amdgcn_mfma_f32_16x16x32_bf16(Al, Bh, q, 0, 0, 0);

    if (rr < 13) {
        const float bv = (rr < 12) ? intb[rr] : impb[0];
#pragma unroll
        for (int r = 0; r < 4; r++) {
            const int e = e0 + kg * 4 + r;
            const int s = ei[e], d = ei[kE + e];
            const float val = q[r] + P[s * 32 + rr] + P[d * 32 + 16 + rr] + bv;
            if (rr < 12) out[(size_t)e * 12 + rr] = val;
            else         out[(size_t)kE * 12 + e] = 1.f / (1.f + __expf(-val));
        }
    }
}

// ---------------- launch ----------------
extern "C" void kernel_launch(void* const* d_in, const int* in_sizes, int n_in,
                              void* d_out, int out_size, void* d_ws, size_t ws_size,
                              hipStream_t stream)
{
    (void)in_sizes; (void)n_in; (void)out_size; (void)ws_size;

    const float* x      = (const float*)d_in[0];
    const int*   ei     = (const int*)d_in[1];
    const float* ea     = (const float*)d_in[2];
    const float* emb_W  = (const float*)d_in[3];
    const float* emb_b  = (const float*)d_in[4];
    const float* g1_Wl  = (const float*)d_in[5];
    const float* g1_bl  = (const float*)d_in[6];
    const float* g1_Wr  = (const float*)d_in[7];
    const float* g1_br  = (const float*)d_in[8];
    const float* g1_We  = (const float*)d_in[9];
    const float* g1_att = (const float*)d_in[10];
    const float* g1_bias= (const float*)d_in[11];
    const float* g2_Wl  = (const float*)d_in[12];
    const float* g2_bl  = (const float*)d_in[13];
    const float* g2_Wr  = (const float*)d_in[14];
    const float* g2_br  = (const float*)d_in[15];
    const float* g2_We  = (const float*)d_in[16];
    const float* g2_att = (const float*)d_in[17];
    const float* g2_bias= (const float*)d_in[18];
    const float* int_W  = (const float*)d_in[19];
    const float* int_b  = (const float*)d_in[20];
    const float* imp_W  = (const float*)d_in[21];
    const float* imp_b  = (const float*)d_in[22];

    char* ws = (char*)d_ws;
    float* eapart  = (float*)(ws + OFF_EAPART);
    float* eamean  = (float*)(ws + OFF_EAMEAN);
    int*   counts  = (int*)  (ws + OFF_COUNTS);
    int*   offs    = (int*)  (ws + OFF_OFFS);
    int*   cursor  = (int*)  (ws + OFF_CURSOR);
    int*   csrsrc  = (int*)  (ws + OFF_CSRSRC);
    int*   csreid  = (int*)  (ws + OFF_CSREID);
    int*   csrdst  = (int*)  (ws + OFF_CSRDST);
    float* accbuf  = (float*)(ws + OFF_ACC);
    float* denbuf  = (float*)(ws + OFF_DEN);
    float* h_a     = (float*)(ws + OFF_HA);
    float* h_b     = (float*)(ws + OFF_HB);
    float* xl      = (float*)(ws + OFF_XL);
    float* xr      = (float*)(ws + OFF_XR);
    unsigned short* f1h = (unsigned short*)(ws + OFF_F1H);
    unsigned short* f1l = (unsigned short*)(ws + OFF_F1L);
    unsigned short* f2h = (unsigned short*)(ws + OFF_F2H);
    unsigned short* f2l = (unsigned short*)(ws + OFF_F2L);
    unsigned short* wembh = (unsigned short*)(ws + OFF_WEMBH);
    unsigned short* wembl = (unsigned short*)(ws + OFF_WEMBL);
    unsigned short* wl1h  = (unsigned short*)(ws + OFF_WL1H);
    unsigned short* wl1l  = (unsigned short*)(ws + OFF_WL1L);
    unsigned short* wr1h  = (unsigned short*)(ws + OFF_WR1H);
    unsigned short* wr1l  = (unsigned short*)(ws + OFF_WR1L);
    unsigned short* wl2h  = (unsigned short*)(ws + OFF_WL2H);
    unsigned short* wl2l  = (unsigned short*)(ws + OFF_WL2L);
    unsigned short* wr2h  = (unsigned short*)(ws + OFF_WR2H);
    unsigned short* wr2l  = (unsigned short*)(ws + OFF_WR2L);
    float* P       = accbuf;                  // reuse acc region after finalize2
    float* outp    = (float*)d_out;

    constexpr int NT = (kTaug + 31) / 32;     // 13282 edge tiles
    constexpr int NGB = (kN + 63) / 64;       // 391 row blocks for MFMA gemms

    // zero acc+den for layer 1 (contiguous region, one memset)
    hipMemsetAsync(ws + OFF_ACC, 0, ACCDEN_BYTES, stream);

    // edge_attr mean + We frag-swizzled bf16 splits + GEMM weight tables
    ea_colsum_part<<<1024, 256, 0, stream>>>(ea, eapart);
    ea_colsum_final<<<1, 256, 0, stream>>>(eapart, eamean);
    we_swizzle<<<32, 256, 0, stream>>>(g1_We, g2_We, f1h, f1l, f2h, f2l);
    w_swizzle_tab<<<32, 256, 0, stream>>>(emb_W, 64, 4, 4, wembh, wembl);
    w_swizzle_tab<<<32, 256, 0, stream>>>(g1_Wl, 256, 16, 2, wl1h, wl1l);
    w_swizzle_tab<<<32, 256, 0, stream>>>(g1_Wr, 256, 16, 2, wr1h, wr1l);
    w_swizzle_tab<<<32, 256, 0, stream>>>(g2_Wl, 256, 16, 2, wl2h, wl2l);
    w_swizzle_tab<<<32, 256, 0, stream>>>(g2_Wr, 256, 16, 2, wr2h, wr2l);

    // CSR by destination (self-loops included)
    init_counts<<<(kN + 255) / 256, 256, 0, stream>>>(counts);
    count_edges<<<(kE + 255) / 256, 256, 0, stream>>>(ei, counts);
    scan_kernel<<<1, 1024, 0, stream>>>(counts, offs, cursor);
    scatter_kernel<<<(kE + kN + 255) / 256, 256, 0, stream>>>(ei, cursor, csrsrc, csreid, csrdst);

    // node embedding (MFMA split-bf16, col-split grid)
    mfma_gemm_bias<128, 64, 2><<<NGB * 2, 256, 0, stream>>>(x, wembh, wembl, emb_b, h_a, kN);

    // ---- GAT layer 1 ----
    mfma_gemm_bias<64, 256, 4><<<NGB * 4, 256, 0, stream>>>(h_a, wl1h, wl1l, g1_bl, xl, kN);
    mfma_gemm_bias<64, 256, 4><<<NGB * 4, 256, 0, stream>>>(h_a, wr1h, wr1l, g1_br, xr, kN);
    edge_logit_aggr_kernel<<<NT, 256, 0, stream>>>(xl, xr, ea, eamean, f1h, f1l, g1_att,
                                                   csrsrc, csrdst, csreid, accbuf, denbuf);
    gat_finalize<<<kN, 256, 0, stream>>>(accbuf, denbuf, g1_bias, h_b);

    // ---- GAT layer 2 ----
    hipMemsetAsync(ws + OFF_ACC, 0, ACCDEN_BYTES, stream);
    mfma_gemm_bias<64, 256, 4><<<NGB * 4, 256, 0, stream>>>(h_b, wl2h, wl2l, g2_bl, xl, kN);
    mfma_gemm_bias<64, 256, 4><<<NGB * 4, 256, 0, stream>>>(h_b, wr2h, wr2l, g2_br, xr, kN);
    edge_logit_aggr_kernel<<<NT, 256, 0, stream>>>(xl, xr, ea, eamean, f2h, f2l, g2_att,
                                                   csrsrc, csrdst, csreid, accbuf, denbuf);
    gat_finalize<<<kN, 256, 0, stream>>>(accbuf, denbuf, g2_bias, h_a);

    // ---- edge heads (decomposed) ----
    node_head_kernel<<<(kN + 63) / 64, 256, 0, stream>>>(h_a, int_W, imp_W, P);
    edge_out_kernel<<<kE / 64, 256, 0, stream>>>(ea, ei, P, int_W, int_b, imp_W, imp_b, outp);
}

// Round 12
// 422.603 us; speedup vs baseline: 1.7166x; 1.1754x over previous
//
#include <hip/hip_runtime.h>
#include <math.h>

// Problem constants
constexpr int kN = 25000;
constexpr int kE = 400000;
constexpr int kTaug = kE + kN;        // CSR slots incl self-loops = 425000
constexpr int kNBLK = (kN + 255) / 256;   // 98 scan blocks

typedef __attribute__((ext_vector_type(8))) short bf16x8s;   // 8 bf16 (4 VGPRs)
typedef __attribute__((ext_vector_type(4))) float f32x4;

__device__ __forceinline__ unsigned short f2bf(float f) {
    unsigned u = __builtin_bit_cast(unsigned, f);
    unsigned r = (u + 0x7FFFu + ((u >> 16) & 1u)) >> 16;     // RNE
    return (unsigned short)r;
}
__device__ __forceinline__ float bf2f(unsigned short h) {
    unsigned u = ((unsigned)h) << 16;
    return __builtin_bit_cast(float, u);
}

// DPP helpers (CTRL must be compile-time constant)
template<int CTRL>
__device__ __forceinline__ float dpp_mov(float x) {
    int yi = __builtin_amdgcn_update_dpp(0, __builtin_bit_cast(int, x), CTRL, 0xF, 0xF, true);
    return __builtin_bit_cast(float, yi);
}
template<int CTRL>
__device__ __forceinline__ float dpp_add(float x) {
    return x + dpp_mov<CTRL>(x);
}

// ---------------- workspace layout (256B aligned) ----------------
constexpr size_t OFF_EAPART = 0;            // 1024*32 f32
constexpr size_t OFF_EAMEAN = 131072;       // 32 f32
constexpr size_t OFF_PART   = 131328;       // 98 i32 (scan partials)
constexpr size_t OFF_CURSOR = 131840;       // N i32
constexpr size_t OFF_CSRSRC = 231936;       // Taug i32
constexpr size_t OFF_CSREID = 1932032;      // Taug i32
constexpr size_t OFF_CSRDST = 3632128;      // Taug i32
constexpr size_t OFF_ACC    = 5332224;      // N*256 f32 (atomic acc; reused as P)
constexpr size_t OFF_DEN    = 30932224;     // N*4 f32
constexpr size_t OFF_COUNTS = 31332224;     // N i32 (inside the memset region)
constexpr size_t MEMSET_BYTES = 31332224 + 100000 - 5332224;   // acc+den+counts
constexpr size_t OFF_HA     = 31432448;     // N*64 f32
constexpr size_t OFF_HB     = 37832448;     // N*64 f32
constexpr size_t OFF_XL     = 44232448;     // N*256 f32
constexpr size_t OFF_XR     = 69832448;     // N*256 f32
constexpr size_t OFF_TAB    = 95432448;     // contiguous weight-frag tables (~426KB)
// element (u16) offsets within TAB:
constexpr int T_F1H = 0,      T_F1L = 8192,  T_F2H = 16384, T_F2L = 24576;
constexpr int T_EMBH = 32768, T_EMBL = 49152;
constexpr int T_L1H = 65536,  T_L1L = 81920, T_R1H = 98304, T_R1L = 114688;
constexpr int T_L2H = 131072, T_L2L = 147456, T_R2H = 163840, T_R2L = 180224;

// ---------------- edge_attr column mean ----------------
__global__ __launch_bounds__(256) void ea_colsum_part(const float* __restrict__ ea,
                                                      float* __restrict__ part)
{
    __shared__ float lds[256];
    const int tid = threadIdx.x;
    const int k = tid & 31, g = tid >> 5;
    float acc = 0.f;
    for (int r = blockIdx.x * 8 + g; r < kE; r += gridDim.x * 8)
        acc += ea[(size_t)r * 32 + k];
    lds[tid] = acc; __syncthreads();
    if (tid < 128) lds[tid] += lds[tid + 128]; __syncthreads();
    if (tid < 64)  lds[tid] += lds[tid + 64];  __syncthreads();
    if (tid < 32)  part[blockIdx.x * 32 + k] = lds[tid] + lds[tid + 32];
}

__global__ __launch_bounds__(256) void ea_colsum_final(const float* __restrict__ part,
                                                       float* __restrict__ ea_mean)
{
    __shared__ float lds[256];
    const int tid = threadIdx.x;
    const int k = tid & 31, g = tid >> 5;
    float acc = 0.f;
    for (int p = g; p < 1024; p += 8) acc += part[p * 32 + k];
    lds[tid] = acc; __syncthreads();
    if (tid < 128) lds[tid] += lds[tid + 128]; __syncthreads();
    if (tid < 64)  lds[tid] += lds[tid + 64];  __syncthreads();
    if (tid < 32)  ea_mean[k] = (lds[tid] + lds[tid + 32]) * (1.0f / (float)kE);
}

// ---------------- We -> frag-swizzled bf16 hi/lo (edge_logit tables) ----------------
__global__ __launch_bounds__(256) void we_swizzle(const float* __restrict__ W1,
                                                  const float* __restrict__ W2,
                                                  unsigned short* __restrict__ tab)
{
    const int b = blockIdx.x;                 // 32 blocks: layer*16 + nt*4 + w
    const int layer = b >> 4, nt = (b >> 2) & 3, w = b & 3;
    const float* W = layer ? W2 : W1;
    unsigned short* H = tab + (layer ? T_F2H : T_F1H);
    unsigned short* L = tab + (layer ? T_F2L : T_F1L);
    const int tid = threadIdx.x;
    const int lane = tid & 63, jh = tid >> 6;
    const int c = w * 64 + nt * 16 + (lane & 15);
    const int kbase = (lane >> 4) * 8;
#pragma unroll
    for (int t = 0; t < 2; t++) {
        const int j = jh * 2 + t;
        const float f = W[(kbase + j) * 256 + c];
        const unsigned short hb = f2bf(f);
        const int idx = ((nt * 4 + w) * 64 + lane) * 8 + j;
        H[idx] = hb;
        L[idx] = f2bf(f - bf2f(hb));
    }
}

// ---------------- merged GEMM-weight frag tables (emb + 4 layer weights) ----------------
// table[((ct*KCH+kk)*64+lane)*8+j] = W[k*KO+c], c=ct*16+(lane&15), k=kk*32+(lane>>4)*8+j
__global__ __launch_bounds__(256) void w_tables(const float* __restrict__ embW,
                                                const float* __restrict__ wl1,
                                                const float* __restrict__ wr1,
                                                const float* __restrict__ wl2,
                                                const float* __restrict__ wr2,
                                                unsigned short* __restrict__ tab)
{
    const int b = blockIdx.x, tid = threadIdx.x;
    const float* W; int KO, KCH, idx; unsigned short *H, *L;
    if (b < 32) {                 // emb: 4 ctiles x 4 kchunks = 8192 elems
        W = embW; KO = 64; KCH = 4; idx = b * 256 + tid;
        H = tab + T_EMBH; L = tab + T_EMBL;
    } else {                      // 4 tables of 16 ctiles x 2 kchunks = 16384 elems
        const int t = (b - 32) >> 6, r = (b - 32) & 63;
        idx = r * 256 + tid; KO = 256; KCH = 2;
        if      (t == 0) { W = wl1; H = tab + T_L1H; L = tab + T_L1L; }
        else if (t == 1) { W = wr1; H = tab + T_R1H; L = tab + T_R1L; }
        else if (t == 2) { W = wl2; H = tab + T_L2H; L = tab + T_L2L; }
        else             { W = wr2; H = tab + T_R2H; L = tab + T_R2L; }
    }
    const int j = idx & 7;
    const int lane = (idx >> 3) & 63;
    const int t2 = idx >> 9;
    const int ct = t2 / KCH;
    const int c = ct * 16 + (lane & 15);
    const int k = (t2 - ct * KCH) * 32 + (lane >> 4) * 8 + j;
    const float f = W[k * KO + c];
    const unsigned short hb = f2bf(f);
    H[idx] = hb;
    L[idx] = f2bf(f - bf2f(hb));
}

// ---------------- MFMA dense GEMM (single output) ----------------
template<int KI, int KO, int CSPLIT>
__global__ __launch_bounds__(256) void mfma_gemm_bias(
    const float* __restrict__ A,
    const unsigned short* __restrict__ WH, const unsigned short* __restrict__ WL,
    const float* __restrict__ bias, float* __restrict__ out, int M)
{
    constexpr int KCH = KI / 32;
    constexpr int CT  = KO / 16;
    constexpr int CTP = CT / CSPLIT;
    const int tid = threadIdx.x;
    const int w = tid >> 6, lane = tid & 63;
    const int rowblk = blockIdx.x / CSPLIT;
    const int csel   = blockIdx.x % CSPLIT;
    const int row0 = rowblk * 64 + w * 16;
    const int rr = lane & 15, kg = lane >> 4;
    const int arow = min(row0 + rr, M - 1);

    bf16x8s Ah[KCH], Al[KCH];
#pragma unroll
    for (int kk = 0; kk < KCH; kk++) {
        const float4 f0 = *(const float4*)&A[(size_t)arow * KI + kk * 32 + kg * 8];
        const float4 f1 = *(const float4*)&A[(size_t)arow * KI + kk * 32 + kg * 8 + 4];
        const float fv[8] = {f0.x, f0.y, f0.z, f0.w, f1.x, f1.y, f1.z, f1.w};
#pragma unroll
        for (int j = 0; j < 8; j++) {
            const unsigned short hb = f2bf(fv[j]);
            Ah[kk][j] = (short)hb;
            Al[kk][j] = (short)f2bf(fv[j] - bf2f(hb));
        }
    }
    const int rbase = kg * 4;
#pragma unroll
    for (int cti = 0; cti < CTP; cti++) {
        const int ct = csel * CTP + cti;
        f32x4 acc = {0.f, 0.f, 0.f, 0.f};
#pragma unroll
        for (int kk = 0; kk < KCH; kk++) {
            const int bidx = ((ct * KCH + kk) * 64 + lane) * 8;
            const bf16x8s Bh = *(const bf16x8s*)&WH[bidx];
            const bf16x8s Bl = *(const bf16x8s*)&WL[bidx];
            acc = __builtin_amdgcn_mfma_f32_16x16x32_bf16(Ah[kk], Bh, acc, 0, 0, 0);
            acc = __builtin_amdgcn_mfma_f32_16x16x32_bf16(Ah[kk], Bl, acc, 0, 0, 0);
            acc = __builtin_amdgcn_mfma_f32_16x16x32_bf16(Al[kk], Bh, acc, 0, 0, 0);
        }
        const float bv = bias[ct * 16 + rr];
#pragma unroll
        for (int r = 0; r < 4; r++) {
            const int row = row0 + rbase + r;
            if (row < M) out[(size_t)row * KO + ct * 16 + rr] = acc[r] + bv;
        }
    }
}

// ---------------- MFMA dense GEMM, dual output (Wl,Wr share A; A staged once) ----------------
template<int KI, int KO, int CSPLIT>
__global__ __launch_bounds__(256) void mfma_gemm_bias2(
    const float* __restrict__ A,
    const unsigned short* __restrict__ WHa, const unsigned short* __restrict__ WLa,
    const unsigned short* __restrict__ WHb, const unsigned short* __restrict__ WLb,
    const float* __restrict__ biasA, const float* __restrict__ biasB,
    float* __restrict__ outA, float* __restrict__ outB, int M)
{
    constexpr int KCH = KI / 32;
    constexpr int CT  = KO / 16;
    constexpr int CTP = CT / CSPLIT;
    const int tid = threadIdx.x;
    const int w = tid >> 6, lane = tid & 63;
    const int rowblk = blockIdx.x / CSPLIT;
    const int csel   = blockIdx.x % CSPLIT;
    const int row0 = rowblk * 64 + w * 16;
    const int rr = lane & 15, kg = lane >> 4;
    const int arow = min(row0 + rr, M - 1);

    bf16x8s Ah[KCH], Al[KCH];
#pragma unroll
    for (int kk = 0; kk < KCH; kk++) {
        const float4 f0 = *(const float4*)&A[(size_t)arow * KI + kk * 32 + kg * 8];
        const float4 f1 = *(const float4*)&A[(size_t)arow * KI + kk * 32 + kg * 8 + 4];
        const float fv[8] = {f0.x, f0.y, f0.z, f0.w, f1.x, f1.y, f1.z, f1.w};
#pragma unroll
        for (int j = 0; j < 8; j++) {
            const unsigned short hb = f2bf(fv[j]);
            Ah[kk][j] = (short)hb;
            Al[kk][j] = (short)f2bf(fv[j] - bf2f(hb));
        }
    }
    const int rbase = kg * 4;
#pragma unroll
    for (int cti = 0; cti < CTP; cti++) {
        const int ct = csel * CTP + cti;
#pragma unroll
        for (int which = 0; which < 2; which++) {
            const unsigned short* WH = which ? WHb : WHa;
            const unsigned short* WL = which ? WLb : WLa;
            const float* bias = which ? biasB : biasA;
            float* out = which ? outB : outA;
            f32x4 acc = {0.f, 0.f, 0.f, 0.f};
#pragma unroll
            for (int kk = 0; kk < KCH; kk++) {
                const int bidx = ((ct * KCH + kk) * 64 + lane) * 8;
                const bf16x8s Bh = *(const bf16x8s*)&WH[bidx];
                const bf16x8s Bl = *(const bf16x8s*)&WL[bidx];
                acc = __builtin_amdgcn_mfma_f32_16x16x32_bf16(Ah[kk], Bh, acc, 0, 0, 0);
                acc = __builtin_amdgcn_mfma_f32_16x16x32_bf16(Ah[kk], Bl, acc, 0, 0, 0);
                acc = __builtin_amdgcn_mfma_f32_16x16x32_bf16(Al[kk], Bh, acc, 0, 0, 0);
            }
            const float bv = bias[ct * 16 + rr];
#pragma unroll
            for (int r = 0; r < 4; r++) {
                const int row = row0 + rbase + r;
                if (row < M) out[(size_t)row * KO + ct * 16 + rr] = acc[r] + bv;
            }
        }
    }
}

// ---------------- CSR build ----------------
__global__ __launch_bounds__(256) void count_edges(const int* __restrict__ ei,
                                                   int* __restrict__ counts)
{
    int e = blockIdx.x * 256 + threadIdx.x;
    if (e < kE) atomicAdd(&counts[ei[kE + e]], 1);
}

// 3-phase parallel scan: counts(+1 self-loop) -> exclusive prefix in cursor
__global__ __launch_bounds__(256) void scan_part(const int* __restrict__ counts,
                                                 int* __restrict__ cursor,
                                                 int* __restrict__ partials)
{
    __shared__ int lds[256];
    const int tid = threadIdx.x;
    const int i = blockIdx.x * 256 + tid;
    const int v = (i < kN) ? counts[i] + 1 : 0;   // +1 = self-loop slot
    lds[tid] = v; __syncthreads();
    for (int d = 1; d < 256; d <<= 1) {
        int t = (tid >= d) ? lds[tid - d] : 0;
        __syncthreads();
        lds[tid] += t;
        __syncthreads();
    }
    if (i < kN) cursor[i] = lds[tid] - v;          // block-local exclusive
    if (tid == 255) partials[blockIdx.x] = lds[255];
}

__global__ __launch_bounds__(128) void scan_mid(int* __restrict__ partials)
{
    __shared__ int lds[128];
    const int tid = threadIdx.x;
    const int v = (tid < kNBLK) ? partials[tid] : 0;
    lds[tid] = v; __syncthreads();
    for (int d = 1; d < 128; d <<= 1) {
        int t = (tid >= d) ? lds[tid - d] : 0;
        __syncthreads();
        lds[tid] += t;
        __syncthreads();
    }
    if (tid < kNBLK) partials[tid] = lds[tid] - v; // exclusive block prefix
}

__global__ __launch_bounds__(256) void scan_add(int* __restrict__ cursor,
                                                const int* __restrict__ partials)
{
    const int i = blockIdx.x * 256 + threadIdx.x;
    if (i < kN) cursor[i] += partials[blockIdx.x];
}

__global__ __launch_bounds__(256) void scatter_kernel(const int* __restrict__ ei,
                                                      int* __restrict__ cursor,
                                                      int* __restrict__ csr_src,
                                                      int* __restrict__ csr_eid,
                                                      int* __restrict__ csr_dst)
{
    int gid = blockIdx.x * 256 + threadIdx.x;
    if (gid < kE) {
        int s = ei[gid];
        int d = ei[kE + gid];
        int p = atomicAdd(&cursor[d], 1);
        csr_src[p] = s;
        csr_eid[p] = gid;
        csr_dst[p] = d;
    } else if (gid < kE + kN) {
        int n = gid - kE;
        int p = atomicAdd(&cursor[n], 1);
        csr_src[p] = n;
        csr_eid[p] = kE;   // sentinel: self-loop
        csr_dst[p] = n;
    }
}

// ---------------- Fused pass: per-edge attention + per-node aggregation (R10, validated) ----------------
__global__ __launch_bounds__(256) void edge_logit_aggr_kernel(
    const float* __restrict__ xl, const float* __restrict__ xr,
    const float* __restrict__ ea, const float* __restrict__ eamean,
    const unsigned short* __restrict__ fragh, const unsigned short* __restrict__ fragl,
    const float* __restrict__ att,
    const int* __restrict__ csr_src, const int* __restrict__ csr_dst,
    const int* __restrict__ csr_eid,
    float* __restrict__ accbuf, float* __restrict__ denbuf)
{
    constexpr int ROWS = 40;                       // padded ea row (shorts), 80B
    constexpr int EPP  = 257;                      // padded ep row (floats), 16-edge half
    __shared__ __align__(16) unsigned short ea_hi[32 * ROWS];
    __shared__ __align__(16) unsigned short ea_lo[32 * ROWS];
    __shared__ __align__(16) float ep_lds[16 * EPP];
    __shared__ __align__(16) int s_src[32];
    __shared__ __align__(16) int s_dst[32];
    const int tid  = threadIdx.x;
    const int w    = tid >> 6;
    const int lane = tid & 63;
    const int b0   = blockIdx.x * 32;

    bf16x8s bh[4], bl[4];
#pragma unroll
    for (int nt = 0; nt < 4; nt++) {
        const int idx = ((nt * 4 + w) * 64 + lane) * 8;
        bh[nt] = *(const bf16x8s*)&fragh[idx];
        bl[nt] = *(const bf16x8s*)&fragl[idx];
    }
    const float att_r = att[tid];
    const int aoff  = (lane & 15) * ROWS + (lane >> 4) * 8;
    const int cbase = w * 64 + (lane & 15);
    const int rbase = (lane >> 4) * 4;

    if (tid < 32) {
        const int p = min(b0 + tid, kTaug - 1);
        s_src[tid] = csr_src[p];
        s_dst[tid] = csr_dst[p];
    }
    {
        const int j = tid >> 3, q = tid & 7;
        const int eid = csr_eid[min(b0 + j, kTaug - 1)];
        const float4* srcp = (eid < kE) ? (const float4*)(ea + (size_t)eid * 32)
                                        : (const float4*)eamean;
        const float4 f = srcp[q];
        const unsigned short h0 = f2bf(f.x), h1 = f2bf(f.y),
                             h2 = f2bf(f.z), h3 = f2bf(f.w);
        const unsigned short g0 = f2bf(f.x - bf2f(h0)), g1 = f2bf(f.y - bf2f(h1)),
                             g2 = f2bf(f.z - bf2f(h2)), g3 = f2bf(f.w - bf2f(h3));
        const unsigned long long ph =
            (unsigned long long)h0 | ((unsigned long long)h1 << 16) |
            ((unsigned long long)h2 << 32) | ((unsigned long long)h3 << 48);
        const unsigned long long pl =
            (unsigned long long)g0 | ((unsigned long long)g1 << 16) |
            ((unsigned long long)g2 << 32) | ((unsigned long long)g3 << 48);
        *(unsigned long long*)&ea_hi[j * ROWS + q * 4] = ph;
        *(unsigned long long*)&ea_lo[j * ROWS + q * 4] = pl;
    }
    __syncthreads();

    int   cur_dst = s_dst[0];
    float den_p = 0.f, acc_p = 0.f;

#pragma unroll
    for (int half = 0; half < 2; half++) {
        const bf16x8s ah = *(const bf16x8s*)&ea_hi[half * 16 * ROWS + aoff];
        const bf16x8s al = *(const bf16x8s*)&ea_lo[half * 16 * ROWS + aoff];
#pragma unroll
        for (int nt = 0; nt < 4; nt++) {
            f32x4 a = {0.f, 0.f, 0.f, 0.f};
            a = __builtin_amdgcn_mfma_f32_16x16x32_bf16(ah, bh[nt], a, 0, 0, 0);
            a = __builtin_amdgcn_mfma_f32_16x16x32_bf16(ah, bl[nt], a, 0, 0, 0);
            a = __builtin_amdgcn_mfma_f32_16x16x32_bf16(al, bh[nt], a, 0, 0, 0);
            const int cc = cbase + nt * 16;
#pragma unroll
            for (int r = 0; r < 4; r++)
                ep_lds[(rbase + r) * EPP + cc] = a[r];
        }
        __syncthreads();

#pragma unroll
        for (int bb = 0; bb < 2; bb++) {           // 2 batches of 8 edges per half
            const int e0 = half * 16 + bb * 8;
            int sv[8], dv[8];
            {
                const int4 ss0 = *(const int4*)&s_src[e0];
                const int4 ss1 = *(const int4*)&s_src[e0 + 4];
                sv[0]=ss0.x; sv[1]=ss0.y; sv[2]=ss0.z; sv[3]=ss0.w;
                sv[4]=ss1.x; sv[5]=ss1.y; sv[6]=ss1.z; sv[7]=ss1.w;
                const int4 dd0 = *(const int4*)&s_dst[e0];
                const int4 dd1 = *(const int4*)&s_dst[e0 + 4];
                dv[0]=dd0.x; dv[1]=dd0.y; dv[2]=dd0.z; dv[3]=dd0.w;
                dv[4]=dd1.x; dv[5]=dd1.y; dv[6]=dd1.z; dv[7]=dd1.w;
            }
            float xls[8], c[8];
#pragma unroll
            for (int u = 0; u < 8; u++) xls[u] = xl[sv[u] * 256 + tid];
#pragma unroll
            for (int u = 0; u < 8; u++) {
                const float xrr = xr[dv[u] * 256 + tid];
                float v = xls[u] + xrr + ep_lds[(bb * 8 + u) * EPP + tid];
                v = fmaxf(v, 0.2f * v);            // leaky_relu 0.2
                c[u] = att_r * v;
            }

            // multi-value exchange reduce: 8 sums in 6 cross-lane steps (R8)
            float n0, n1, n2, n3;
            {   const bool s = lane & 1;
                n0 = (s ? c[1] : c[0]) + dpp_mov<0xB1>(s ? c[0] : c[1]);
                n1 = (s ? c[3] : c[2]) + dpp_mov<0xB1>(s ? c[2] : c[3]);
                n2 = (s ? c[5] : c[4]) + dpp_mov<0xB1>(s ? c[4] : c[5]);
                n3 = (s ? c[7] : c[6]) + dpp_mov<0xB1>(s ? c[6] : c[7]);
            }
            float m0, m1;
            {   const bool s = lane & 2;
                m0 = (s ? n1 : n0) + dpp_mov<0x4E>(s ? n0 : n1);
                m1 = (s ? n3 : n2) + dpp_mov<0x4E>(s ? n2 : n3);
            }
            float r;
            {   const bool s = lane & 32;
                const float oth = __shfl_xor(s ? m0 : m1, 32);
                r = (s ? m1 : m0) + oth;
            }
            r = dpp_add<0x124>(r);                 // row_ror:4
            r = dpp_add<0x128>(r);                 // row_ror:8
            r += __shfl_xor(r, 16);
            const float pe_r = __expf(r);

            // inverse-butterfly broadcast: all lanes get pe[0..7]
            float pu[8];
            {
                const float o1 = dpp_mov<0xB1>(pe_r);
                const float a0 = (lane & 1) ? o1 : pe_r;
                const float a1 = (lane & 1) ? pe_r : o1;
                const float oa0 = dpp_mov<0x4E>(a0);
                const float oa1 = dpp_mov<0x4E>(a1);
                const float b00 = (lane & 2) ? oa0 : a0;
                const float b01 = (lane & 2) ? oa1 : a1;
                const float b10 = (lane & 2) ? a0 : oa0;
                const float b11 = (lane & 2) ? a1 : oa1;
                const float ob00 = __shfl_xor(b00, 32);
                const float ob01 = __shfl_xor(b01, 32);
                const float ob10 = __shfl_xor(b10, 32);
                const float ob11 = __shfl_xor(b11, 32);
                const bool hi = lane & 32;
                pu[0] = hi ? ob00 : b00;  pu[4] = hi ? b00 : ob00;
                pu[1] = hi ? ob01 : b01;  pu[5] = hi ? b01 : ob01;
                pu[2] = hi ? ob10 : b10;  pu[6] = hi ? b10 : ob10;
                pu[3] = hi ? ob11 : b11;  pu[7] = hi ? b11 : ob11;
            }
            if (b0 + e0 + 8 > kTaug) {
#pragma unroll
                for (int u = 0; u < 8; u++)
                    if (b0 + e0 + u >= kTaug) pu[u] = 0.f;
            }
#pragma unroll
            for (int u = 0; u < 8; u++) {
                if (dv[u] != cur_dst) {
                    atomicAdd(&accbuf[(size_t)cur_dst * 256 + tid], acc_p);
                    if (lane == 0) atomicAdd(&denbuf[cur_dst * 4 + w], den_p);
                    acc_p = 0.f; den_p = 0.f; cur_dst = dv[u];
                }
                acc_p += pu[u] * xls[u];
                den_p += pu[u];
            }
        }
        __syncthreads();                           // ep_lds reuse
    }

    atomicAdd(&accbuf[(size_t)cur_dst * 256 + tid], acc_p);
    if (lane == 0) atomicAdd(&denbuf[cur_dst * 4 + w], den_p);
}

// ---------------- finalize: h = relu(mean_h(acc/den) + bias); optionally re-zero acc/den ----------------
template<bool ZERO>
__global__ __launch_bounds__(256) void gat_finalize(
    float* __restrict__ accbuf, float* __restrict__ denbuf,
    const float* __restrict__ gbias, float* __restrict__ h_out)
{
    __shared__ float red[256];
    const int tid = threadIdx.x;
    const int n = blockIdx.x;
    red[tid] = accbuf[(size_t)n * 256 + tid] / denbuf[n * 4 + (tid >> 6)];
    if (ZERO) {
        accbuf[(size_t)n * 256 + tid] = 0.f;
        if ((tid & 63) == 0) denbuf[n * 4 + (tid >> 6)] = 0.f;
    }
    __syncthreads();
    if (tid < 64) {
        float sres = red[tid] + red[tid + 64] + red[tid + 128] + red[tid + 192];
        h_out[n * 64 + tid] = fmaxf(0.25f * sres + gbias[tid], 0.f);
    }
}

// ---------------- node head: P[n][0:16]=h@W13[0:64], P[n][16:32]=h@W13[64:128] ----------------
__global__ __launch_bounds__(256) void node_head_kernel(
    const float* __restrict__ h, const float* __restrict__ intW,
    const float* __restrict__ impW, float* __restrict__ P)
{
    const int tid = threadIdx.x;
    const int w = tid >> 6, lane = tid & 63;
    const int row0 = blockIdx.x * 64 + w * 16;
    const int rr = lane & 15;
    const int kg = lane >> 4;

    bf16x8s Bh[2][2], Bl[2][2];
#pragma unroll
    for (int ct = 0; ct < 2; ct++) {
#pragma unroll
        for (int kk = 0; kk < 2; kk++) {
            const int kbase = ct * 64 + kk * 32 + kg * 8;
#pragma unroll
            for (int j = 0; j < 8; j++) {
                const int k = kbase + j;
                float wv;
                if (rr < 12)       wv = intW[k * 12 + rr];
                else if (rr == 12) wv = impW[k];
                else               wv = 0.f;
                const unsigned short hb = f2bf(wv);
                Bh[ct][kk][j] = (short)hb;
                Bl[ct][kk][j] = (short)f2bf(wv - bf2f(hb));
            }
        }
    }

    const int arow = min(row0 + rr, kN - 1);
    bf16x8s Ah[2], Al[2];
#pragma unroll
    for (int kk = 0; kk < 2; kk++) {
        const float4 f0 = *(const float4*)&h[arow * 64 + kk * 32 + kg * 8];
        const float4 f1 = *(const float4*)&h[arow * 64 + kk * 32 + kg * 8 + 4];
        const float fv[8] = {f0.x, f0.y, f0.z, f0.w, f1.x, f1.y, f1.z, f1.w};
#pragma unroll
        for (int j = 0; j < 8; j++) {
            const unsigned short hb = f2bf(fv[j]);
            Ah[kk][j] = (short)hb;
            Al[kk][j] = (short)f2bf(fv[j] - bf2f(hb));
        }
    }

#pragma unroll
    for (int ct = 0; ct < 2; ct++) {
        f32x4 acc = {0.f, 0.f, 0.f, 0.f};
#pragma unroll
        for (int kk = 0; kk < 2; kk++) {
            acc = __builtin_amdgcn_mfma_f32_16x16x32_bf16(Ah[kk], Bh[ct][kk], acc, 0, 0, 0);
            acc = __builtin_amdgcn_mfma_f32_16x16x32_bf16(Ah[kk], Bl[ct][kk], acc, 0, 0, 0);
            acc = __builtin_amdgcn_mfma_f32_16x16x32_bf16(Al[kk], Bh[ct][kk], acc, 0, 0, 0);
        }
        const int crow0 = kg * 4;
#pragma unroll
        for (int r = 0; r < 4; r++) {
            const int row = row0 + crow0 + r;
            if (row < kN) P[row * 32 + ct * 16 + rr] = acc[r];
        }
    }
}

// ---------------- edge out: Q = relu(ea)@W13[128:160]; out = Q + P_src + P_dst + b ----------------
__global__ __launch_bounds__(256) void edge_out_kernel(
    const float* __restrict__ ea, const int* __restrict__ ei,
    const float* __restrict__ P,
    const float* __restrict__ intW, const float* __restrict__ intb,
    const float* __restrict__ impW, const float* __restrict__ impb,
    float* __restrict__ out)
{
    constexpr int ROWS = 40;
    __shared__ __align__(16) unsigned short ehi[4][16 * ROWS];
    __shared__ __align__(16) unsigned short elo[4][16 * ROWS];
    const int tid = threadIdx.x;
    const int w = tid >> 6, lane = tid & 63;
    const int e0 = blockIdx.x * 64 + w * 16;
    const int rr = lane & 15, kg = lane >> 4;

    bf16x8s Bh, Bl;
#pragma unroll
    for (int j = 0; j < 8; j++) {
        const int k = 128 + kg * 8 + j;
        float wv;
        if (rr < 12)       wv = intW[k * 12 + rr];
        else if (rr == 12) wv = impW[k];
        else               wv = 0.f;
        const unsigned short hb = f2bf(wv);
        Bh[j] = (short)hb;
        Bl[j] = (short)f2bf(wv - bf2f(hb));
    }

    {
        const int j = lane >> 2, q = lane & 3;
        const float4* src = (const float4*)&ea[(size_t)(e0 + j) * 32 + q * 8];
        const float4 f0 = src[0], f1 = src[1];
        const float fv[8] = {fmaxf(f0.x, 0.f), fmaxf(f0.y, 0.f), fmaxf(f0.z, 0.f), fmaxf(f0.w, 0.f),
                             fmaxf(f1.x, 0.f), fmaxf(f1.y, 0.f), fmaxf(f1.z, 0.f), fmaxf(f1.w, 0.f)};
        unsigned long long ph0 = 0, pl0 = 0, ph1 = 0, pl1 = 0;
#pragma unroll
        for (int t = 0; t < 4; t++) {
            const unsigned short hb = f2bf(fv[t]);
            const unsigned short lb = f2bf(fv[t] - bf2f(hb));
            ph0 |= (unsigned long long)hb << (16 * t);
            pl0 |= (unsigned long long)lb << (16 * t);
        }
#pragma unroll
        for (int t = 0; t < 4; t++) {
            const unsigned short hb = f2bf(fv[4 + t]);
            const unsigned short lb = f2bf(fv[4 + t] - bf2f(hb));
            ph1 |= (unsigned long long)hb << (16 * t);
            pl1 |= (unsigned long long)lb << (16 * t);
        }
        *(unsigned long long*)&ehi[w][j * ROWS + q * 8]     = ph0;
        *(unsigned long long*)&ehi[w][j * ROWS + q * 8 + 4] = ph1;
        *(unsigned long long*)&elo[w][j * ROWS + q * 8]     = pl0;
        *(unsigned long long*)&elo[w][j * ROWS + q * 8 + 4] = pl1;
    }
    __syncthreads();

    const int aoff = rr * ROWS + kg * 8;
    const bf16x8s Ah = *(const bf16x8s*)&ehi[w][aoff];
    const bf16x8s Al = *(const bf16x8s*)&elo[w][aoff];
    f32x4 q = {0.f, 0.f, 0.f, 0.f};
    q = __builtin_amdgcn_mfma_f32_16x16x32_bf16(Ah, Bh, q, 0, 0, 0);
    q = __builtin_amdgcn_mfma_f32_16x16x32_bf16(Ah, Bl, q, 0, 0, 0);
    q = __builtin_amdgcn_mfma_f32_16x16x32_bf16(Al, Bh, q, 0, 0, 0);

    if (rr < 13) {
        const float bv = (rr < 12) ? intb[rr] : impb[0];
#pragma unroll
        for (int r = 0; r < 4; r++) {
            const int e = e0 + kg * 4 + r;
            const int s = ei[e], d = ei[kE + e];
            const float val = q[r] + P[s * 32 + rr] + P[d * 32 + 16 + rr] + bv;
            if (rr < 12) out[(size_t)e * 12 + rr] = val;
            else         out[(size_t)kE * 12 + e] = 1.f / (1.f + __expf(-val));
        }
    }
}

// ---------------- launch ----------------
extern "C" void kernel_launch(void* const* d_in, const int* in_sizes, int n_in,
                              void* d_out, int out_size, void* d_ws, size_t ws_size,
                              hipStream_t stream)
{
    (void)in_sizes; (void)n_in; (void)out_size; (void)ws_size;

    const float* x      = (const float*)d_in[0];
    const int*   ei     = (const int*)d_in[1];
    const float* ea     = (const float*)d_in[2];
    const float* emb_W  = (const float*)d_in[3];
    const float* emb_b  = (const float*)d_in[4];
    const float* g1_Wl  = (const float*)d_in[5];
    const float* g1_bl  = (const float*)d_in[6];
    const float* g1_Wr  = (const float*)d_in[7];
    const float* g1_br  = (const float*)d_in[8];
    const float* g1_We  = (const float*)d_in[9];
    const float* g1_att = (const float*)d_in[10];
    const float* g1_bias= (const float*)d_in[11];
    const float* g2_Wl  = (const float*)d_in[12];
    const float* g2_bl  = (const float*)d_in[13];
    const float* g2_Wr  = (const float*)d_in[14];
    const float* g2_br  = (const float*)d_in[15];
    const float* g2_We  = (const float*)d_in[16];
    const float* g2_att = (const float*)d_in[17];
    const float* g2_bias= (const float*)d_in[18];
    const float* int_W  = (const float*)d_in[19];
    const float* int_b  = (const float*)d_in[20];
    const float* imp_W  = (const float*)d_in[21];
    const float* imp_b  = (const float*)d_in[22];

    char* ws = (char*)d_ws;
    float* eapart  = (float*)(ws + OFF_EAPART);
    float* eamean  = (float*)(ws + OFF_EAMEAN);
    int*   partials= (int*)  (ws + OFF_PART);
    int*   cursor  = (int*)  (ws + OFF_CURSOR);
    int*   csrsrc  = (int*)  (ws + OFF_CSRSRC);
    int*   csreid  = (int*)  (ws + OFF_CSREID);
    int*   csrdst  = (int*)  (ws + OFF_CSRDST);
    float* accbuf  = (float*)(ws + OFF_ACC);
    float* denbuf  = (float*)(ws + OFF_DEN);
    int*   counts  = (int*)  (ws + OFF_COUNTS);
    float* h_a     = (float*)(ws + OFF_HA);
    float* h_b     = (float*)(ws + OFF_HB);
    float* xl      = (float*)(ws + OFF_XL);
    float* xr      = (float*)(ws + OFF_XR);
    unsigned short* tab = (unsigned short*)(ws + OFF_TAB);
    float* P       = accbuf;                  // reuse acc region after finalize2
    float* outp    = (float*)d_out;

    constexpr int NT = (kTaug + 31) / 32;     // 13282 edge tiles
    constexpr int NGB = (kN + 63) / 64;       // 391 row blocks for MFMA gemms

    // zero acc + den + counts (one contiguous memset)
    hipMemsetAsync(ws + OFF_ACC, 0, MEMSET_BYTES, stream);

    // edge_attr mean + all weight-frag tables (2 launches)
    ea_colsum_part<<<1024, 256, 0, stream>>>(ea, eapart);
    ea_colsum_final<<<1, 256, 0, stream>>>(eapart, eamean);
    we_swizzle<<<32, 256, 0, stream>>>(g1_We, g2_We, tab);
    w_tables<<<288, 256, 0, stream>>>(emb_W, g1_Wl, g1_Wr, g2_Wl, g2_Wr, tab);

    // CSR by destination (self-loops included); counts pre-zeroed by memset
    count_edges<<<(kE + 255) / 256, 256, 0, stream>>>(ei, counts);
    scan_part<<<kNBLK, 256, 0, stream>>>(counts, cursor, partials);
    scan_mid<<<1, 128, 0, stream>>>(partials);
    scan_add<<<kNBLK, 256, 0, stream>>>(cursor, partials);
    scatter_kernel<<<(kE + kN + 255) / 256, 256, 0, stream>>>(ei, cursor, csrsrc, csreid, csrdst);

    // node embedding (MFMA split-bf16, col-split grid)
    mfma_gemm_bias<128, 64, 2><<<NGB * 2, 256, 0, stream>>>(
        x, tab + T_EMBH, tab + T_EMBL, emb_b, h_a, kN);

    // ---- GAT layer 1 ----
    mfma_gemm_bias2<64, 256, 4><<<NGB * 4, 256, 0, stream>>>(
        h_a, tab + T_L1H, tab + T_L1L, tab + T_R1H, tab + T_R1L,
        g1_bl, g1_br, xl, xr, kN);
    edge_logit_aggr_kernel<<<NT, 256, 0, stream>>>(xl, xr, ea, eamean,
        tab + T_F1H, tab + T_F1L, g1_att, csrsrc, csrdst, csreid, accbuf, denbuf);
    gat_finalize<true><<<kN, 256, 0, stream>>>(accbuf, denbuf, g1_bias, h_b);

    // ---- GAT layer 2 (acc/den re-zeroed by finalize<true>) ----
    mfma_gemm_bias2<64, 256, 4><<<NGB * 4, 256, 0, stream>>>(
        h_b, tab + T_L2H, tab + T_L2L, tab + T_R2H, tab + T_R2L,
        g2_bl, g2_br, xl, xr, kN);
    edge_logit_aggr_kernel<<<NT, 256, 0, stream>>>(xl, xr, ea, eamean,
        tab + T_F2H, tab + T_F2L, g2_att, csrsrc, csrdst, csreid, accbuf, denbuf);
    gat_finalize<false><<<kN, 256, 0, stream>>>(accbuf, denbuf, g2_bias, h_a);

    // ---- edge heads (decomposed) ----
    node_head_kernel<<<(kN + 63) / 64, 256, 0, stream>>>(h_a, int_W, imp_W, P);
    edge_out_kernel<<<kE / 64, 256, 0, stream>>>(ea, ei, P, int_W, int_b, imp_W, imp_b, outp);
}

// Round 13
// 418.112 us; speedup vs baseline: 1.7351x; 1.0107x over previous
//
#include <hip/hip_runtime.h>
#include <math.h>

// Problem constants
constexpr int kN = 25000;
constexpr int kE = 400000;
constexpr int kTaug = kE + kN;        // CSR slots incl self-loops = 425000
constexpr int kTpad = 425024;         // padded to tile boundary (13282*32)
constexpr int kNBLK = (kN + 255) / 256;   // 98 scan blocks

typedef __attribute__((ext_vector_type(8))) short bf16x8s;   // 8 bf16 (4 VGPRs)
typedef __attribute__((ext_vector_type(4))) float f32x4;

__device__ __forceinline__ unsigned short f2bf(float f) {
    unsigned u = __builtin_bit_cast(unsigned, f);
    unsigned r = (u + 0x7FFFu + ((u >> 16) & 1u)) >> 16;     // RNE
    return (unsigned short)r;
}
__device__ __forceinline__ float bf2f(unsigned short h) {
    unsigned u = ((unsigned)h) << 16;
    return __builtin_bit_cast(float, u);
}

// DPP helpers (CTRL must be compile-time constant)
template<int CTRL>
__device__ __forceinline__ float dpp_mov(float x) {
    int yi = __builtin_amdgcn_update_dpp(0, __builtin_bit_cast(int, x), CTRL, 0xF, 0xF, true);
    return __builtin_bit_cast(float, yi);
}
template<int CTRL>
__device__ __forceinline__ float dpp_add(float x) {
    return x + dpp_mov<CTRL>(x);
}

// ---------------- workspace layout (256B aligned) ----------------
constexpr size_t OFF_EAPART = 0;            // 1024*32 f32
constexpr size_t OFF_EAMEAN = 131072;       // 32 f32
constexpr size_t OFF_PART   = 131328;       // 98 i32 (scan partials)
constexpr size_t OFF_CURSOR = 131840;       // N i32
constexpr size_t OFF_CSRSRC = 231936;       // kTpad i32 (425024*4 = 1700096)
constexpr size_t OFF_CSREID = 1932032;      // kTpad i32
constexpr size_t OFF_CSRDST = 3632128;      // kTpad i32
constexpr size_t OFF_ACC    = 5332224;      // N*256 f32 (atomic acc; reused as P)
constexpr size_t OFF_DEN    = 30932224;     // N*4 f32
constexpr size_t OFF_COUNTS = 31332224;     // N i32 (inside the memset region)
constexpr size_t MEMSET_BYTES = 31332224 + 100000 - 5332224;   // acc+den+counts
constexpr size_t OFF_HA     = 31432448;     // N*64 f32
constexpr size_t OFF_HB     = 37832448;     // N*64 f32
constexpr size_t OFF_XL     = 44232448;     // N*256 f32
constexpr size_t OFF_XR     = 69832448;     // N*256 f32
constexpr size_t OFF_TAB    = 95432448;     // contiguous weight-frag tables (~426KB)
// element (u16) offsets within TAB:
constexpr int T_F1H = 0,      T_F1L = 8192,  T_F2H = 16384, T_F2L = 24576;
constexpr int T_EMBH = 32768, T_EMBL = 49152;
constexpr int T_L1H = 65536,  T_L1L = 81920, T_R1H = 98304, T_R1L = 114688;
constexpr int T_L2H = 131072, T_L2L = 147456, T_R2H = 163840, T_R2L = 180224;

// ---------------- edge_attr column mean ----------------
__global__ __launch_bounds__(256) void ea_colsum_part(const float* __restrict__ ea,
                                                      float* __restrict__ part)
{
    __shared__ float lds[256];
    const int tid = threadIdx.x;
    const int k = tid & 31, g = tid >> 5;
    float acc = 0.f;
    for (int r = blockIdx.x * 8 + g; r < kE; r += gridDim.x * 8)
        acc += ea[(size_t)r * 32 + k];
    lds[tid] = acc; __syncthreads();
    if (tid < 128) lds[tid] += lds[tid + 128]; __syncthreads();
    if (tid < 64)  lds[tid] += lds[tid + 64];  __syncthreads();
    if (tid < 32)  part[blockIdx.x * 32 + k] = lds[tid] + lds[tid + 32];
}

__global__ __launch_bounds__(256) void ea_colsum_final(const float* __restrict__ part,
                                                       float* __restrict__ ea_mean)
{
    __shared__ float lds[256];
    const int tid = threadIdx.x;
    const int k = tid & 31, g = tid >> 5;
    float acc = 0.f;
    for (int p = g; p < 1024; p += 8) acc += part[p * 32 + k];
    lds[tid] = acc; __syncthreads();
    if (tid < 128) lds[tid] += lds[tid + 128]; __syncthreads();
    if (tid < 64)  lds[tid] += lds[tid + 64];  __syncthreads();
    if (tid < 32)  ea_mean[k] = (lds[tid] + lds[tid + 32]) * (1.0f / (float)kE);
}

// ---------------- We -> frag-swizzled bf16 hi/lo (edge_logit tables) ----------------
__global__ __launch_bounds__(256) void we_swizzle(const float* __restrict__ W1,
                                                  const float* __restrict__ W2,
                                                  unsigned short* __restrict__ tab)
{
    const int b = blockIdx.x;                 // 32 blocks: layer*16 + nt*4 + w
    const int layer = b >> 4, nt = (b >> 2) & 3, w = b & 3;
    const float* W = layer ? W2 : W1;
    unsigned short* H = tab + (layer ? T_F2H : T_F1H);
    unsigned short* L = tab + (layer ? T_F2L : T_F1L);
    const int tid = threadIdx.x;
    const int lane = tid & 63, jh = tid >> 6;
    const int c = w * 64 + nt * 16 + (lane & 15);
    const int kbase = (lane >> 4) * 8;
#pragma unroll
    for (int t = 0; t < 2; t++) {
        const int j = jh * 2 + t;
        const float f = W[(kbase + j) * 256 + c];
        const unsigned short hb = f2bf(f);
        const int idx = ((nt * 4 + w) * 64 + lane) * 8 + j;
        H[idx] = hb;
        L[idx] = f2bf(f - bf2f(hb));
    }
}

// ---------------- merged GEMM-weight frag tables (emb + 4 layer weights) ----------------
__global__ __launch_bounds__(256) void w_tables(const float* __restrict__ embW,
                                                const float* __restrict__ wl1,
                                                const float* __restrict__ wr1,
                                                const float* __restrict__ wl2,
                                                const float* __restrict__ wr2,
                                                unsigned short* __restrict__ tab)
{
    const int b = blockIdx.x, tid = threadIdx.x;
    const float* W; int KO, KCH, idx; unsigned short *H, *L;
    if (b < 32) {                 // emb: 4 ctiles x 4 kchunks = 8192 elems
        W = embW; KO = 64; KCH = 4; idx = b * 256 + tid;
        H = tab + T_EMBH; L = tab + T_EMBL;
    } else {                      // 4 tables of 16 ctiles x 2 kchunks = 16384 elems
        const int t = (b - 32) >> 6, r = (b - 32) & 63;
        idx = r * 256 + tid; KO = 256; KCH = 2;
        if      (t == 0) { W = wl1; H = tab + T_L1H; L = tab + T_L1L; }
        else if (t == 1) { W = wr1; H = tab + T_R1H; L = tab + T_R1L; }
        else if (t == 2) { W = wl2; H = tab + T_L2H; L = tab + T_L2L; }
        else             { W = wr2; H = tab + T_R2H; L = tab + T_R2L; }
    }
    const int j = idx & 7;
    const int lane = (idx >> 3) & 63;
    const int t2 = idx >> 9;
    const int ct = t2 / KCH;
    const int c = ct * 16 + (lane & 15);
    const int k = (t2 - ct * KCH) * 32 + (lane >> 4) * 8 + j;
    const float f = W[k * KO + c];
    const unsigned short hb = f2bf(f);
    H[idx] = hb;
    L[idx] = f2bf(f - bf2f(hb));
}

// ---------------- MFMA dense GEMM (single output) ----------------
template<int KI, int KO, int CSPLIT>
__global__ __launch_bounds__(256) void mfma_gemm_bias(
    const float* __restrict__ A,
    const unsigned short* __restrict__ WH, const unsigned short* __restrict__ WL,
    const float* __restrict__ bias, float* __restrict__ out, int M)
{
    constexpr int KCH = KI / 32;
    constexpr int CT  = KO / 16;
    constexpr int CTP = CT / CSPLIT;
    const int tid = threadIdx.x;
    const int w = tid >> 6, lane = tid & 63;
    const int rowblk = blockIdx.x / CSPLIT;
    const int csel   = blockIdx.x % CSPLIT;
    const int row0 = rowblk * 64 + w * 16;
    const int rr = lane & 15, kg = lane >> 4;
    const int arow = min(row0 + rr, M - 1);

    bf16x8s Ah[KCH], Al[KCH];
#pragma unroll
    for (int kk = 0; kk < KCH; kk++) {
        const float4 f0 = *(const float4*)&A[(size_t)arow * KI + kk * 32 + kg * 8];
        const float4 f1 = *(const float4*)&A[(size_t)arow * KI + kk * 32 + kg * 8 + 4];
        const float fv[8] = {f0.x, f0.y, f0.z, f0.w, f1.x, f1.y, f1.z, f1.w};
#pragma unroll
        for (int j = 0; j < 8; j++) {
            const unsigned short hb = f2bf(fv[j]);
            Ah[kk][j] = (short)hb;
            Al[kk][j] = (short)f2bf(fv[j] - bf2f(hb));
        }
    }
    const int rbase = kg * 4;
#pragma unroll
    for (int cti = 0; cti < CTP; cti++) {
        const int ct = csel * CTP + cti;
        f32x4 acc = {0.f, 0.f, 0.f, 0.f};
#pragma unroll
        for (int kk = 0; kk < KCH; kk++) {
            const int bidx = ((ct * KCH + kk) * 64 + lane) * 8;
            const bf16x8s Bh = *(const bf16x8s*)&WH[bidx];
            const bf16x8s Bl = *(const bf16x8s*)&WL[bidx];
            acc = __builtin_amdgcn_mfma_f32_16x16x32_bf16(Ah[kk], Bh, acc, 0, 0, 0);
            acc = __builtin_amdgcn_mfma_f32_16x16x32_bf16(Ah[kk], Bl, acc, 0, 0, 0);
            acc = __builtin_amdgcn_mfma_f32_16x16x32_bf16(Al[kk], Bh, acc, 0, 0, 0);
        }
        const float bv = bias[ct * 16 + rr];
#pragma unroll
        for (int r = 0; r < 4; r++) {
            const int row = row0 + rbase + r;
            if (row < M) out[(size_t)row * KO + ct * 16 + rr] = acc[r] + bv;
        }
    }
}

// ---------------- MFMA dense GEMM, dual output (Wl,Wr share A; A staged once) ----------------
template<int KI, int KO, int CSPLIT>
__global__ __launch_bounds__(256) void mfma_gemm_bias2(
    const float* __restrict__ A,
    const unsigned short* __restrict__ WHa, const unsigned short* __restrict__ WLa,
    const unsigned short* __restrict__ WHb, const unsigned short* __restrict__ WLb,
    const float* __restrict__ biasA, const float* __restrict__ biasB,
    float* __restrict__ outA, float* __restrict__ outB, int M)
{
    constexpr int KCH = KI / 32;
    constexpr int CT  = KO / 16;
    constexpr int CTP = CT / CSPLIT;
    const int tid = threadIdx.x;
    const int w = tid >> 6, lane = tid & 63;
    const int rowblk = blockIdx.x / CSPLIT;
    const int csel   = blockIdx.x % CSPLIT;
    const int row0 = rowblk * 64 + w * 16;
    const int rr = lane & 15, kg = lane >> 4;
    const int arow = min(row0 + rr, M - 1);

    bf16x8s Ah[KCH], Al[KCH];
#pragma unroll
    for (int kk = 0; kk < KCH; kk++) {
        const float4 f0 = *(const float4*)&A[(size_t)arow * KI + kk * 32 + kg * 8];
        const float4 f1 = *(const float4*)&A[(size_t)arow * KI + kk * 32 + kg * 8 + 4];
        const float fv[8] = {f0.x, f0.y, f0.z, f0.w, f1.x, f1.y, f1.z, f1.w};
#pragma unroll
        for (int j = 0; j < 8; j++) {
            const unsigned short hb = f2bf(fv[j]);
            Ah[kk][j] = (short)hb;
            Al[kk][j] = (short)f2bf(fv[j] - bf2f(hb));
        }
    }
    const int rbase = kg * 4;
#pragma unroll
    for (int cti = 0; cti < CTP; cti++) {
        const int ct = csel * CTP + cti;
#pragma unroll
        for (int which = 0; which < 2; which++) {
            const unsigned short* WH = which ? WHb : WHa;
            const unsigned short* WL = which ? WLb : WLa;
            const float* bias = which ? biasB : biasA;
            float* out = which ? outB : outA;
            f32x4 acc = {0.f, 0.f, 0.f, 0.f};
#pragma unroll
            for (int kk = 0; kk < KCH; kk++) {
                const int bidx = ((ct * KCH + kk) * 64 + lane) * 8;
                const bf16x8s Bh = *(const bf16x8s*)&WH[bidx];
                const bf16x8s Bl = *(const bf16x8s*)&WL[bidx];
                acc = __builtin_amdgcn_mfma_f32_16x16x32_bf16(Ah[kk], Bh, acc, 0, 0, 0);
                acc = __builtin_amdgcn_mfma_f32_16x16x32_bf16(Ah[kk], Bl, acc, 0, 0, 0);
                acc = __builtin_amdgcn_mfma_f32_16x16x32_bf16(Al[kk], Bh, acc, 0, 0, 0);
            }
            const float bv = bias[ct * 16 + rr];
#pragma unroll
            for (int r = 0; r < 4; r++) {
                const int row = row0 + rbase + r;
                if (row < M) out[(size_t)row * KO + ct * 16 + rr] = acc[r] + bv;
            }
        }
    }
}

// ---------------- CSR build ----------------
__global__ __launch_bounds__(256) void count_edges(const int* __restrict__ ei,
                                                   int* __restrict__ counts)
{
    int e = blockIdx.x * 256 + threadIdx.x;
    if (e < kE) atomicAdd(&counts[ei[kE + e]], 1);
}

// 3-phase parallel scan: counts(+1 self-loop) -> exclusive prefix in cursor
__global__ __launch_bounds__(256) void scan_part(const int* __restrict__ counts,
                                                 int* __restrict__ cursor,
                                                 int* __restrict__ partials)
{
    __shared__ int lds[256];
    const int tid = threadIdx.x;
    const int i = blockIdx.x * 256 + tid;
    const int v = (i < kN) ? counts[i] + 1 : 0;   // +1 = self-loop slot
    lds[tid] = v; __syncthreads();
    for (int d = 1; d < 256; d <<= 1) {
        int t = (tid >= d) ? lds[tid - d] : 0;
        __syncthreads();
        lds[tid] += t;
        __syncthreads();
    }
    if (i < kN) cursor[i] = lds[tid] - v;          // block-local exclusive
    if (tid == 255) partials[blockIdx.x] = lds[255];
}

__global__ __launch_bounds__(128) void scan_mid(int* __restrict__ partials)
{
    __shared__ int lds[128];
    const int tid = threadIdx.x;
    const int v = (tid < kNBLK) ? partials[tid] : 0;
    lds[tid] = v; __syncthreads();
    for (int d = 1; d < 128; d <<= 1) {
        int t = (tid >= d) ? lds[tid - d] : 0;
        __syncthreads();
        lds[tid] += t;
        __syncthreads();
    }
    if (tid < kNBLK) partials[tid] = lds[tid] - v; // exclusive block prefix
}

__global__ __launch_bounds__(256) void scan_add(int* __restrict__ cursor,
                                                const int* __restrict__ partials)
{
    const int i = blockIdx.x * 256 + threadIdx.x;
    if (i < kN) cursor[i] += partials[blockIdx.x];
}

// scatter + pad slots [kTaug, kTpad) with inert entries (src=0, dst=kN-1, eid=sentinel)
__global__ __launch_bounds__(256) void scatter_kernel(const int* __restrict__ ei,
                                                      int* __restrict__ cursor,
                                                      int* __restrict__ csr_src,
                                                      int* __restrict__ csr_eid,
                                                      int* __restrict__ csr_dst)
{
    int gid = blockIdx.x * 256 + threadIdx.x;
    if (gid < kE) {
        int s = ei[gid];
        int d = ei[kE + gid];
        int p = atomicAdd(&cursor[d], 1);
        csr_src[p] = s;
        csr_eid[p] = gid;
        csr_dst[p] = d;
    } else if (gid < kTaug) {
        int n = gid - kE;
        int p = atomicAdd(&cursor[n], 1);
        csr_src[p] = n;
        csr_eid[p] = kE;   // sentinel: self-loop
        csr_dst[p] = n;
    } else if (gid < kTpad) {
        csr_src[gid] = 0;
        csr_eid[gid] = kE;       // sentinel (reads eamean; contribution masked to 0)
        csr_dst[gid] = kN - 1;
    }
}

// ---------------- Fused pass: per-edge attention + per-node aggregation ----------------
// R12: scalar (SGPR) index loads + SGPR-base gathers; scalar flush compares;
// pe broadcast via LDS (1 ds_write + 2 ds_read_b128) instead of 14-VALU butterfly.
// Dataflow identical to R10's validated kernel.
__global__ __launch_bounds__(256) void edge_logit_aggr_kernel(
    const float* __restrict__ xl, const float* __restrict__ xr,
    const float* __restrict__ ea, const float* __restrict__ eamean,
    const unsigned short* __restrict__ fragh, const unsigned short* __restrict__ fragl,
    const float* __restrict__ att,
    const int* __restrict__ csr_src, const int* __restrict__ csr_dst,
    const int* __restrict__ csr_eid,
    float* __restrict__ accbuf, float* __restrict__ denbuf)
{
    constexpr int ROWS = 40;                       // padded ea row (shorts), 80B
    constexpr int EPP  = 257;                      // padded ep row (floats), 16-edge half
    __shared__ __align__(16) unsigned short ea_hi[32 * ROWS];
    __shared__ __align__(16) unsigned short ea_lo[32 * ROWS];
    __shared__ __align__(16) float ep_lds[16 * EPP];
    __shared__ __align__(16) float lds_pe[4][8];
    const int tid  = threadIdx.x;
    const int w    = tid >> 6;
    const int lane = tid & 63;
    const int b0   = blockIdx.x * 32;

    // B fragments: 8 coalesced b128 loads from pre-swizzled tables
    bf16x8s bh[4], bl[4];
#pragma unroll
    for (int nt = 0; nt < 4; nt++) {
        const int idx = ((nt * 4 + w) * 64 + lane) * 8;
        bh[nt] = *(const bf16x8s*)&fragh[idx];
        bl[nt] = *(const bf16x8s*)&fragl[idx];
    }
    const float att_r = att[tid];
    const int aoff  = (lane & 15) * ROWS + (lane >> 4) * 8;
    const int cbase = w * 64 + (lane & 15);
    const int rbase = (lane >> 4) * 4;

    // stage ea rows (csr padded to kTpad: no clamp needed)
    {
        const int j = tid >> 3, q = tid & 7;
        const int eid = csr_eid[b0 + j];
        const float4* srcp = (eid < kE) ? (const float4*)(ea + (size_t)eid * 32)
                                        : (const float4*)eamean;
        const float4 f = srcp[q];
        const unsigned short h0 = f2bf(f.x), h1 = f2bf(f.y),
                             h2 = f2bf(f.z), h3 = f2bf(f.w);
        const unsigned short g0 = f2bf(f.x - bf2f(h0)), g1 = f2bf(f.y - bf2f(h1)),
                             g2 = f2bf(f.z - bf2f(h2)), g3 = f2bf(f.w - bf2f(h3));
        const unsigned long long ph =
            (unsigned long long)h0 | ((unsigned long long)h1 << 16) |
            ((unsigned long long)h2 << 32) | ((unsigned long long)h3 << 48);
        const unsigned long long pl =
            (unsigned long long)g0 | ((unsigned long long)g1 << 16) |
            ((unsigned long long)g2 << 32) | ((unsigned long long)g3 << 48);
        *(unsigned long long*)&ea_hi[j * ROWS + q * 4] = ph;
        *(unsigned long long*)&ea_lo[j * ROWS + q * 4] = pl;
    }
    __syncthreads();

    int   cur_dst = csr_dst[b0];                   // wave-uniform scalar
    float den_p = 0.f, acc_p = 0.f;

#pragma unroll
    for (int half = 0; half < 2; half++) {
        const bf16x8s ah = *(const bf16x8s*)&ea_hi[half * 16 * ROWS + aoff];
        const bf16x8s al = *(const bf16x8s*)&ea_lo[half * 16 * ROWS + aoff];
#pragma unroll
        for (int nt = 0; nt < 4; nt++) {
            f32x4 a = {0.f, 0.f, 0.f, 0.f};
            a = __builtin_amdgcn_mfma_f32_16x16x32_bf16(ah, bh[nt], a, 0, 0, 0);
            a = __builtin_amdgcn_mfma_f32_16x16x32_bf16(ah, bl[nt], a, 0, 0, 0);
            a = __builtin_amdgcn_mfma_f32_16x16x32_bf16(al, bh[nt], a, 0, 0, 0);
            const int cc = cbase + nt * 16;
#pragma unroll
            for (int r = 0; r < 4; r++)
                ep_lds[(rbase + r) * EPP + cc] = a[r];
        }
        __syncthreads();

#pragma unroll
        for (int bb = 0; bb < 2; bb++) {           // 2 batches of 8 edges per half
            const int e0g = b0 + half * 16 + bb * 8;
            // uniform-address index loads -> scalar (SMEM) pipe
            int sv_s[8], dv_s[8];
#pragma unroll
            for (int u = 0; u < 8; u++) {
                sv_s[u] = csr_src[e0g + u];
                dv_s[u] = csr_dst[e0g + u];
            }
            float xls[8], c[8];
#pragma unroll
            for (int u = 0; u < 8; u++) {
                const float* __restrict__ xlp = xl + (size_t)sv_s[u] * 256;
                xls[u] = xlp[tid];                 // SGPR base + tid offset
            }
#pragma unroll
            for (int u = 0; u < 8; u++) {
                const float* __restrict__ xrp = xr + (size_t)dv_s[u] * 256;
                const float xrr = xrp[tid];
                float v = xls[u] + xrr + ep_lds[(bb * 8 + u) * EPP + tid];
                v = fmaxf(v, 0.2f * v);            // leaky_relu 0.2
                c[u] = att_r * v;
            }

            // multi-value exchange reduce: 8 sums in 6 cross-lane steps (R8)
            float n0, n1, n2, n3;
            {   const bool s = lane & 1;
                n0 = (s ? c[1] : c[0]) + dpp_mov<0xB1>(s ? c[0] : c[1]);
                n1 = (s ? c[3] : c[2]) + dpp_mov<0xB1>(s ? c[2] : c[3]);
                n2 = (s ? c[5] : c[4]) + dpp_mov<0xB1>(s ? c[4] : c[5]);
                n3 = (s ? c[7] : c[6]) + dpp_mov<0xB1>(s ? c[6] : c[7]);
            }
            float m0, m1;
            {   const bool s = lane & 2;
                m0 = (s ? n1 : n0) + dpp_mov<0x4E>(s ? n0 : n1);
                m1 = (s ? n3 : n2) + dpp_mov<0x4E>(s ? n2 : n3);
            }
            float r;
            {   const bool s = lane & 32;
                const float oth = __shfl_xor(s ? m0 : m1, 32);
                r = (s ? m1 : m0) + oth;
            }
            r = dpp_add<0x124>(r);                 // row_ror:4
            r = dpp_add<0x128>(r);                 // row_ror:8
            r += __shfl_xor(r, 16);
            // lane holds full logit for edge u0 = (l&3)|((l>>3)&4)
            const float pe_r = __expf(r);

            // pe broadcast via LDS: lanes {0..3,32..35} publish their value
            if ((lane & 0x1C) == 0)
                lds_pe[w][(lane & 3) | ((lane >> 3) & 4)] = pe_r;
            float pu[8];
            {
                const float4 p0 = *(const float4*)&lds_pe[w][0];
                const float4 p1 = *(const float4*)&lds_pe[w][4];
                pu[0] = p0.x; pu[1] = p0.y; pu[2] = p0.z; pu[3] = p0.w;
                pu[4] = p1.x; pu[5] = p1.y; pu[6] = p1.z; pu[7] = p1.w;
            }
            if (e0g + 8 > kTaug) {                 // tail: zero padded edges
#pragma unroll
                for (int u = 0; u < 8; u++)
                    if (e0g + u >= kTaug) pu[u] = 0.f;
            }
            // segmented accumulate; dv_s scalar -> uniform scc branch
#pragma unroll
            for (int u = 0; u < 8; u++) {
                if (dv_s[u] != cur_dst) {
                    atomicAdd(&accbuf[(size_t)cur_dst * 256 + tid], acc_p);
                    if (lane == 0) atomicAdd(&denbuf[cur_dst * 4 + w], den_p);
                    acc_p = 0.f; den_p = 0.f; cur_dst = dv_s[u];
                }
                acc_p += pu[u] * xls[u];
                den_p += pu[u];
            }
        }
        __syncthreads();                           // ep_lds reuse
    }

    atomicAdd(&accbuf[(size_t)cur_dst * 256 + tid], acc_p);
    if (lane == 0) atomicAdd(&denbuf[cur_dst * 4 + w], den_p);
}

// ---------------- finalize: h = relu(mean_h(acc/den) + bias); optionally re-zero acc/den ----------------
template<bool ZERO>
__global__ __launch_bounds__(256) void gat_finalize(
    float* __restrict__ accbuf, float* __restrict__ denbuf,
    const float* __restrict__ gbias, float* __restrict__ h_out)
{
    __shared__ float red[256];
    const int tid = threadIdx.x;
    const int n = blockIdx.x;
    red[tid] = accbuf[(size_t)n * 256 + tid] / denbuf[n * 4 + (tid >> 6)];
    if (ZERO) {
        accbuf[(size_t)n * 256 + tid] = 0.f;
        if ((tid & 63) == 0) denbuf[n * 4 + (tid >> 6)] = 0.f;
    }
    __syncthreads();
    if (tid < 64) {
        float sres = red[tid] + red[tid + 64] + red[tid + 128] + red[tid + 192];
        h_out[n * 64 + tid] = fmaxf(0.25f * sres + gbias[tid], 0.f);
    }
}

// ---------------- node head: P[n][0:16]=h@W13[0:64], P[n][16:32]=h@W13[64:128] ----------------
__global__ __launch_bounds__(256) void node_head_kernel(
    const float* __restrict__ h, const float* __restrict__ intW,
    const float* __restrict__ impW, float* __restrict__ P)
{
    const int tid = threadIdx.x;
    const int w = tid >> 6, lane = tid & 63;
    const int row0 = blockIdx.x * 64 + w * 16;
    const int rr = lane & 15;
    const int kg = lane >> 4;

    bf16x8s Bh[2][2], Bl[2][2];
#pragma unroll
    for (int ct = 0; ct < 2; ct++) {
#pragma unroll
        for (int kk = 0; kk < 2; kk++) {
            const int kbase = ct * 64 + kk * 32 + kg * 8;
#pragma unroll
            for (int j = 0; j < 8; j++) {
                const int k = kbase + j;
                float wv;
                if (rr < 12)       wv = intW[k * 12 + rr];
                else if (rr == 12) wv = impW[k];
                else               wv = 0.f;
                const unsigned short hb = f2bf(wv);
                Bh[ct][kk][j] = (short)hb;
                Bl[ct][kk][j] = (short)f2bf(wv - bf2f(hb));
            }
        }
    }

    const int arow = min(row0 + rr, kN - 1);
    bf16x8s Ah[2], Al[2];
#pragma unroll
    for (int kk = 0; kk < 2; kk++) {
        const float4 f0 = *(const float4*)&h[arow * 64 + kk * 32 + kg * 8];
        const float4 f1 = *(const float4*)&h[arow * 64 + kk * 32 + kg * 8 + 4];
        const float fv[8] = {f0.x, f0.y, f0.z, f0.w, f1.x, f1.y, f1.z, f1.w};
#pragma unroll
        for (int j = 0; j < 8; j++) {
            const unsigned short hb = f2bf(fv[j]);
            Ah[kk][j] = (short)hb;
            Al[kk][j] = (short)f2bf(fv[j] - bf2f(hb));
        }
    }

#pragma unroll
    for (int ct = 0; ct < 2; ct++) {
        f32x4 acc = {0.f, 0.f, 0.f, 0.f};
#pragma unroll
        for (int kk = 0; kk < 2; kk++) {
            acc = __builtin_amdgcn_mfma_f32_16x16x32_bf16(Ah[kk], Bh[ct][kk], acc, 0, 0, 0);
            acc = __builtin_amdgcn_mfma_f32_16x16x32_bf16(Ah[kk], Bl[ct][kk], acc, 0, 0, 0);
            acc = __builtin_amdgcn_mfma_f32_16x16x32_bf16(Al[kk], Bh[ct][kk], acc, 0, 0, 0);
        }
        const int crow0 = kg * 4;
#pragma unroll
        for (int r = 0; r < 4; r++) {
            const int row = row0 + crow0 + r;
            if (row < kN) P[row * 32 + ct * 16 + rr] = acc[r];
        }
    }
}

// ---------------- edge out: Q = relu(ea)@W13[128:160]; out = Q + P_src + P_dst + b ----------------
__global__ __launch_bounds__(256) void edge_out_kernel(
    const float* __restrict__ ea, const int* __restrict__ ei,
    const float* __restrict__ P,
    const float* __restrict__ intW, const float* __restrict__ intb,
    const float* __restrict__ impW, const float* __restrict__ impb,
    float* __restrict__ out)
{
    constexpr int ROWS = 40;
    __shared__ __align__(16) unsigned short ehi[4][16 * ROWS];
    __shared__ __align__(16) unsigned short elo[4][16 * ROWS];
    const int tid = threadIdx.x;
    const int w = tid >> 6, lane = tid & 63;
    const int e0 = blockIdx.x * 64 + w * 16;
    const int rr = lane & 15, kg = lane >> 4;

    bf16x8s Bh, Bl;
#pragma unroll
    for (int j = 0; j < 8; j++) {
        const int k = 128 + kg * 8 + j;
        float wv;
        if (rr < 12)       wv = intW[k * 12 + rr];
        else if (rr == 12) wv = impW[k];
        else               wv = 0.f;
        const unsigned short hb = f2bf(wv);
        Bh[j] = (short)hb;
        Bl[j] = (short)f2bf(wv - bf2f(hb));
    }

    {
        const int j = lane >> 2, q = lane & 3;
        const float4* src = (const float4*)&ea[(size_t)(e0 + j) * 32 + q * 8];
        const float4 f0 = src[0], f1 = src[1];
        const float fv[8] = {fmaxf(f0.x, 0.f), fmaxf(f0.y, 0.f), fmaxf(f0.z, 0.f), fmaxf(f0.w, 0.f),
                             fmaxf(f1.x, 0.f), fmaxf(f1.y, 0.f), fmaxf(f1.z, 0.f), fmaxf(f1.w, 0.f)};
        unsigned long long ph0 = 0, pl0 = 0, ph1 = 0, pl1 = 0;
#pragma unroll
        for (int t = 0; t < 4; t++) {
            const unsigned short hb = f2bf(fv[t]);
            const unsigned short lb = f2bf(fv[t] - bf2f(hb));
            ph0 |= (unsigned long long)hb << (16 * t);
            pl0 |= (unsigned long long)lb << (16 * t);
        }
#pragma unroll
        for (int t = 0; t < 4; t++) {
            const unsigned short hb = f2bf(fv[4 + t]);
            const unsigned short lb = f2bf(fv[4 + t] - bf2f(hb));
            ph1 |= (unsigned long long)hb << (16 * t);
            pl1 |= (unsigned long long)lb << (16 * t);
        }
        *(unsigned long long*)&ehi[w][j * ROWS + q * 8]     = ph0;
        *(unsigned long long*)&ehi[w][j * ROWS + q * 8 + 4] = ph1;
        *(unsigned long long*)&elo[w][j * ROWS + q * 8]     = pl0;
        *(unsigned long long*)&elo[w][j * ROWS + q * 8 + 4] = pl1;
    }
    __syncthreads();

    const int aoff = rr * ROWS + kg * 8;
    const bf16x8s Ah = *(const bf16x8s*)&ehi[w][aoff];
    const bf16x8s Al = *(const bf16x8s*)&elo[w][aoff];
    f32x4 q = {0.f, 0.f, 0.f, 0.f};
    q = __builtin_amdgcn_mfma_f32_16x16x32_bf16(Ah, Bh, q, 0, 0, 0);
    q = __builtin_amdgcn_mfma_f32_16x16x32_bf16(Ah, Bl, q, 0, 0, 0);
    q = __builtin_amdgcn_mfma_f32_16x16x32_bf16(Al, Bh, q, 0, 0, 0);

    if (rr < 13) {
        const float bv = (rr < 12) ? intb[rr] : impb[0];
#pragma unroll
        for (int r = 0; r < 4; r++) {
            const int e = e0 + kg * 4 + r;
            const int s = ei[e], d = ei[kE + e];
            const float val = q[r] + P[s * 32 + rr] + P[d * 32 + 16 + rr] + bv;
            if (rr < 12) out[(size_t)e * 12 + rr] = val;
            else         out[(size_t)kE * 12 + e] = 1.f / (1.f + __expf(-val));
        }
    }
}

// ---------------- launch ----------------
extern "C" void kernel_launch(void* const* d_in, const int* in_sizes, int n_in,
                              void* d_out, int out_size, void* d_ws, size_t ws_size,
                              hipStream_t stream)
{
    (void)in_sizes; (void)n_in; (void)out_size; (void)ws_size;

    const float* x      = (const float*)d_in[0];
    const int*   ei     = (const int*)d_in[1];
    const float* ea     = (const float*)d_in[2];
    const float* emb_W  = (const float*)d_in[3];
    const float* emb_b  = (const float*)d_in[4];
    const float* g1_Wl  = (const float*)d_in[5];
    const float* g1_bl  = (const float*)d_in[6];
    const float* g1_Wr  = (const float*)d_in[7];
    const float* g1_br  = (const float*)d_in[8];
    const float* g1_We  = (const float*)d_in[9];
    const float* g1_att = (const float*)d_in[10];
    const float* g1_bias= (const float*)d_in[11];
    const float* g2_Wl  = (const float*)d_in[12];
    const float* g2_bl  = (const float*)d_in[13];
    const float* g2_Wr  = (const float*)d_in[14];
    const float* g2_br  = (const float*)d_in[15];
    const float* g2_We  = (const float*)d_in[16];
    const float* g2_att = (const float*)d_in[17];
    const float* g2_bias= (const float*)d_in[18];
    const float* int_W  = (const float*)d_in[19];
    const float* int_b  = (const float*)d_in[20];
    const float* imp_W  = (const float*)d_in[21];
    const float* imp_b  = (const float*)d_in[22];

    char* ws = (char*)d_ws;
    float* eapart  = (float*)(ws + OFF_EAPART);
    float* eamean  = (float*)(ws + OFF_EAMEAN);
    int*   partials= (int*)  (ws + OFF_PART);
    int*   cursor  = (int*)  (ws + OFF_CURSOR);
    int*   csrsrc  = (int*)  (ws + OFF_CSRSRC);
    int*   csreid  = (int*)  (ws + OFF_CSREID);
    int*   csrdst  = (int*)  (ws + OFF_CSRDST);
    float* accbuf  = (float*)(ws + OFF_ACC);
    float* denbuf  = (float*)(ws + OFF_DEN);
    int*   counts  = (int*)  (ws + OFF_COUNTS);
    float* h_a     = (float*)(ws + OFF_HA);
    float* h_b     = (float*)(ws + OFF_HB);
    float* xl      = (float*)(ws + OFF_XL);
    float* xr      = (float*)(ws + OFF_XR);
    unsigned short* tab = (unsigned short*)(ws + OFF_TAB);
    float* P       = accbuf;                  // reuse acc region after finalize2
    float* outp    = (float*)d_out;

    constexpr int NT = (kTaug + 31) / 32;     // 13282 edge tiles
    constexpr int NGB = (kN + 63) / 64;       // 391 row blocks for MFMA gemms

    // zero acc + den + counts (one contiguous memset)
    hipMemsetAsync(ws + OFF_ACC, 0, MEMSET_BYTES, stream);

    // edge_attr mean + all weight-frag tables (2 launches)
    ea_colsum_part<<<1024, 256, 0, stream>>>(ea, eapart);
    ea_colsum_final<<<1, 256, 0, stream>>>(eapart, eamean);
    we_swizzle<<<32, 256, 0, stream>>>(g1_We, g2_We, tab);
    w_tables<<<288, 256, 0, stream>>>(emb_W, g1_Wl, g1_Wr, g2_Wl, g2_Wr, tab);

    // CSR by destination (self-loops included); counts pre-zeroed by memset
    count_edges<<<(kE + 255) / 256, 256, 0, stream>>>(ei, counts);
    scan_part<<<kNBLK, 256, 0, stream>>>(counts, cursor, partials);
    scan_mid<<<1, 128, 0, stream>>>(partials);
    scan_add<<<kNBLK, 256, 0, stream>>>(cursor, partials);
    scatter_kernel<<<(kTpad + 255) / 256, 256, 0, stream>>>(ei, cursor, csrsrc, csreid, csrdst);

    // node embedding (MFMA split-bf16, col-split grid)
    mfma_gemm_bias<128, 64, 2><<<NGB * 2, 256, 0, stream>>>(
        x, tab + T_EMBH, tab + T_EMBL, emb_b, h_a, kN);

    // ---- GAT layer 1 ----
    mfma_gemm_bias2<64, 256, 4><<<NGB * 4, 256, 0, stream>>>(
        h_a, tab + T_L1H, tab + T_L1L, tab + T_R1H, tab + T_R1L,
        g1_bl, g1_br, xl, xr, kN);
    edge_logit_aggr_kernel<<<NT, 256, 0, stream>>>(xl, xr, ea, eamean,
        tab + T_F1H, tab + T_F1L, g1_att, csrsrc, csrdst, csreid, accbuf, denbuf);
    gat_finalize<true><<<kN, 256, 0, stream>>>(accbuf, denbuf, g1_bias, h_b);

    // ---- GAT layer 2 (acc/den re-zeroed by finalize<true>) ----
    mfma_gemm_bias2<64, 256, 4><<<NGB * 4, 256, 0, stream>>>(
        h_b, tab + T_L2H, tab + T_L2L, tab + T_R2H, tab + T_R2L,
        g2_bl, g2_br, xl, xr, kN);
    edge_logit_aggr_kernel<<<NT, 256, 0, stream>>>(xl, xr, ea, eamean,
        tab + T_F2H, tab + T_F2L, g2_att, csrsrc, csrdst, csreid, accbuf, denbuf);
    gat_finalize<false><<<kN, 256, 0, stream>>>(accbuf, denbuf, g2_bias, h_a);

    // ---- edge heads (decomposed) ----
    node_head_kernel<<<(kN + 63) / 64, 256, 0, stream>>>(h_a, int_W, imp_W, P);
    edge_out_kernel<<<kE / 64, 256, 0, stream>>>(ea, ei, P, int_W, int_b, imp_W, imp_b, outp);
}

// Round 14
// 400.762 us; speedup vs baseline: 1.8102x; 1.0433x over previous
//
#include <hip/hip_runtime.h>
#include <math.h>

// Problem constants
constexpr int kN = 25000;
constexpr int kE = 400000;
constexpr int kTaug = kE + kN;        // CSR slots incl self-loops = 425000
constexpr int kTpad = 425024;         // padded to tile boundary (13282*32)
constexpr int kNBLK = (kN + 255) / 256;   // 98 scan blocks

typedef __attribute__((ext_vector_type(8))) short bf16x8s;   // 8 bf16 (4 VGPRs)
typedef __attribute__((ext_vector_type(4))) float f32x4;

__device__ __forceinline__ unsigned short f2bf(float f) {
    unsigned u = __builtin_bit_cast(unsigned, f);
    unsigned r = (u + 0x7FFFu + ((u >> 16) & 1u)) >> 16;     // RNE
    return (unsigned short)r;
}
__device__ __forceinline__ float bf2f(unsigned short h) {
    unsigned u = ((unsigned)h) << 16;
    return __builtin_bit_cast(float, u);
}

// DPP helpers (CTRL must be compile-time constant)
template<int CTRL>
__device__ __forceinline__ float dpp_mov(float x) {
    int yi = __builtin_amdgcn_update_dpp(0, __builtin_bit_cast(int, x), CTRL, 0xF, 0xF, true);
    return __builtin_bit_cast(float, yi);
}
template<int CTRL>
__device__ __forceinline__ float dpp_add(float x) {
    return x + dpp_mov<CTRL>(x);
}

// ---------------- workspace layout (256B aligned) ----------------
constexpr size_t OFF_EAPART = 0;            // 1024*32 f32
constexpr size_t OFF_EAMEAN = 131072;       // 32 f32
constexpr size_t OFF_PART   = 131328;       // 98 i32 (scan partials)
constexpr size_t OFF_CURSOR = 131840;       // N i32
constexpr size_t OFF_CSRSRC = 231936;       // kTpad i32
constexpr size_t OFF_CSREID = 1932032;      // kTpad i32
constexpr size_t OFF_CSRDST = 3632128;      // kTpad i32
constexpr size_t OFF_ACC    = 5332224;      // N*256 f32 (atomic acc; reused as P)
constexpr size_t OFF_DEN    = 30932224;     // N*4 f32
constexpr size_t OFF_COUNTS = 31332224;     // N i32 (inside the memset region)
constexpr size_t MEMSET_BYTES = 31332224 + 100000 - 5332224;   // acc+den+counts
constexpr size_t OFF_HA     = 31432448;     // N*64 f32
constexpr size_t OFF_HB     = 37832448;     // N*64 f32
constexpr size_t OFF_XL     = 44232448;     // N*256 f32
constexpr size_t OFF_XR     = 69832448;     // N*256 f32
constexpr size_t OFF_TAB    = 95432448;     // contiguous weight-frag tables (~426KB)
// element (u16) offsets within TAB:
constexpr int T_F1H = 0,      T_F1L = 8192,  T_F2H = 16384, T_F2L = 24576;
constexpr int T_EMBH = 32768, T_EMBL = 49152;
constexpr int T_L1H = 65536,  T_L1L = 81920, T_R1H = 98304, T_R1L = 114688;
constexpr int T_L2H = 131072, T_L2L = 147456, T_R2H = 163840, T_R2L = 180224;

// ---------------- edge_attr column mean ----------------
__global__ __launch_bounds__(256) void ea_colsum_part(const float* __restrict__ ea,
                                                      float* __restrict__ part)
{
    __shared__ float lds[256];
    const int tid = threadIdx.x;
    const int k = tid & 31, g = tid >> 5;
    float acc = 0.f;
    for (int r = blockIdx.x * 8 + g; r < kE; r += gridDim.x * 8)
        acc += ea[(size_t)r * 32 + k];
    lds[tid] = acc; __syncthreads();
    if (tid < 128) lds[tid] += lds[tid + 128]; __syncthreads();
    if (tid < 64)  lds[tid] += lds[tid + 64];  __syncthreads();
    if (tid < 32)  part[blockIdx.x * 32 + k] = lds[tid] + lds[tid + 32];
}

__global__ __launch_bounds__(256) void ea_colsum_final(const float* __restrict__ part,
                                                       float* __restrict__ ea_mean)
{
    __shared__ float lds[256];
    const int tid = threadIdx.x;
    const int k = tid & 31, g = tid >> 5;
    float acc = 0.f;
    for (int p = g; p < 1024; p += 8) acc += part[p * 32 + k];
    lds[tid] = acc; __syncthreads();
    if (tid < 128) lds[tid] += lds[tid + 128]; __syncthreads();
    if (tid < 64)  lds[tid] += lds[tid + 64];  __syncthreads();
    if (tid < 32)  ea_mean[k] = (lds[tid] + lds[tid + 32]) * (1.0f / (float)kE);
}

// ---------------- We -> frag-swizzled bf16 hi/lo (edge_logit tables) ----------------
__global__ __launch_bounds__(256) void we_swizzle(const float* __restrict__ W1,
                                                  const float* __restrict__ W2,
                                                  unsigned short* __restrict__ tab)
{
    const int b = blockIdx.x;                 // 32 blocks: layer*16 + nt*4 + w
    const int layer = b >> 4, nt = (b >> 2) & 3, w = b & 3;
    const float* W = layer ? W2 : W1;
    unsigned short* H = tab + (layer ? T_F2H : T_F1H);
    unsigned short* L = tab + (layer ? T_F2L : T_F1L);
    const int tid = threadIdx.x;
    const int lane = tid & 63, jh = tid >> 6;
    const int c = w * 64 + nt * 16 + (lane & 15);
    const int kbase = (lane >> 4) * 8;
#pragma unroll
    for (int t = 0; t < 2; t++) {
        const int j = jh * 2 + t;
        const float f = W[(kbase + j) * 256 + c];
        const unsigned short hb = f2bf(f);
        const int idx = ((nt * 4 + w) * 64 + lane) * 8 + j;
        H[idx] = hb;
        L[idx] = f2bf(f - bf2f(hb));
    }
}

// ---------------- merged GEMM-weight frag tables (emb + 4 layer weights) ----------------
__global__ __launch_bounds__(256) void w_tables(const float* __restrict__ embW,
                                                const float* __restrict__ wl1,
                                                const float* __restrict__ wr1,
                                                const float* __restrict__ wl2,
                                                const float* __restrict__ wr2,
                                                unsigned short* __restrict__ tab)
{
    const int b = blockIdx.x, tid = threadIdx.x;
    const float* W; int KO, KCH, idx; unsigned short *H, *L;
    if (b < 32) {                 // emb: 4 ctiles x 4 kchunks = 8192 elems
        W = embW; KO = 64; KCH = 4; idx = b * 256 + tid;
        H = tab + T_EMBH; L = tab + T_EMBL;
    } else {                      // 4 tables of 16 ctiles x 2 kchunks = 16384 elems
        const int t = (b - 32) >> 6, r = (b - 32) & 63;
        idx = r * 256 + tid; KO = 256; KCH = 2;
        if      (t == 0) { W = wl1; H = tab + T_L1H; L = tab + T_L1L; }
        else if (t == 1) { W = wr1; H = tab + T_R1H; L = tab + T_R1L; }
        else if (t == 2) { W = wl2; H = tab + T_L2H; L = tab + T_L2L; }
        else             { W = wr2; H = tab + T_R2H; L = tab + T_R2L; }
    }
    const int j = idx & 7;
    const int lane = (idx >> 3) & 63;
    const int t2 = idx >> 9;
    const int ct = t2 / KCH;
    const int c = ct * 16 + (lane & 15);
    const int k = (t2 - ct * KCH) * 32 + (lane >> 4) * 8 + j;
    const float f = W[k * KO + c];
    const unsigned short hb = f2bf(f);
    H[idx] = hb;
    L[idx] = f2bf(f - bf2f(hb));
}

// ---------------- MFMA dense GEMM (single output) ----------------
template<int KI, int KO, int CSPLIT>
__global__ __launch_bounds__(256) void mfma_gemm_bias(
    const float* __restrict__ A,
    const unsigned short* __restrict__ WH, const unsigned short* __restrict__ WL,
    const float* __restrict__ bias, float* __restrict__ out, int M)
{
    constexpr int KCH = KI / 32;
    constexpr int CT  = KO / 16;
    constexpr int CTP = CT / CSPLIT;
    const int tid = threadIdx.x;
    const int w = tid >> 6, lane = tid & 63;
    const int rowblk = blockIdx.x / CSPLIT;
    const int csel   = blockIdx.x % CSPLIT;
    const int row0 = rowblk * 64 + w * 16;
    const int rr = lane & 15, kg = lane >> 4;
    const int arow = min(row0 + rr, M - 1);

    bf16x8s Ah[KCH], Al[KCH];
#pragma unroll
    for (int kk = 0; kk < KCH; kk++) {
        const float4 f0 = *(const float4*)&A[(size_t)arow * KI + kk * 32 + kg * 8];
        const float4 f1 = *(const float4*)&A[(size_t)arow * KI + kk * 32 + kg * 8 + 4];
        const float fv[8] = {f0.x, f0.y, f0.z, f0.w, f1.x, f1.y, f1.z, f1.w};
#pragma unroll
        for (int j = 0; j < 8; j++) {
            const unsigned short hb = f2bf(fv[j]);
            Ah[kk][j] = (short)hb;
            Al[kk][j] = (short)f2bf(fv[j] - bf2f(hb));
        }
    }
    const int rbase = kg * 4;
#pragma unroll
    for (int cti = 0; cti < CTP; cti++) {
        const int ct = csel * CTP + cti;
        f32x4 acc = {0.f, 0.f, 0.f, 0.f};
#pragma unroll
        for (int kk = 0; kk < KCH; kk++) {
            const int bidx = ((ct * KCH + kk) * 64 + lane) * 8;
            const bf16x8s Bh = *(const bf16x8s*)&WH[bidx];
            const bf16x8s Bl = *(const bf16x8s*)&WL[bidx];
            acc = __builtin_amdgcn_mfma_f32_16x16x32_bf16(Ah[kk], Bh, acc, 0, 0, 0);
            acc = __builtin_amdgcn_mfma_f32_16x16x32_bf16(Ah[kk], Bl, acc, 0, 0, 0);
            acc = __builtin_amdgcn_mfma_f32_16x16x32_bf16(Al[kk], Bh, acc, 0, 0, 0);
        }
        const float bv = bias[ct * 16 + rr];
#pragma unroll
        for (int r = 0; r < 4; r++) {
            const int row = row0 + rbase + r;
            if (row < M) out[(size_t)row * KO + ct * 16 + rr] = acc[r] + bv;
        }
    }
}

// ---------------- MFMA dense GEMM, dual output (Wl,Wr share A; A staged once) ----------------
template<int KI, int KO, int CSPLIT>
__global__ __launch_bounds__(256) void mfma_gemm_bias2(
    const float* __restrict__ A,
    const unsigned short* __restrict__ WHa, const unsigned short* __restrict__ WLa,
    const unsigned short* __restrict__ WHb, const unsigned short* __restrict__ WLb,
    const float* __restrict__ biasA, const float* __restrict__ biasB,
    float* __restrict__ outA, float* __restrict__ outB, int M)
{
    constexpr int KCH = KI / 32;
    constexpr int CT  = KO / 16;
    constexpr int CTP = CT / CSPLIT;
    const int tid = threadIdx.x;
    const int w = tid >> 6, lane = tid & 63;
    const int rowblk = blockIdx.x / CSPLIT;
    const int csel   = blockIdx.x % CSPLIT;
    const int row0 = rowblk * 64 + w * 16;
    const int rr = lane & 15, kg = lane >> 4;
    const int arow = min(row0 + rr, M - 1);

    bf16x8s Ah[KCH], Al[KCH];
#pragma unroll
    for (int kk = 0; kk < KCH; kk++) {
        const float4 f0 = *(const float4*)&A[(size_t)arow * KI + kk * 32 + kg * 8];
        const float4 f1 = *(const float4*)&A[(size_t)arow * KI + kk * 32 + kg * 8 + 4];
        const float fv[8] = {f0.x, f0.y, f0.z, f0.w, f1.x, f1.y, f1.z, f1.w};
#pragma unroll
        for (int j = 0; j < 8; j++) {
            const unsigned short hb = f2bf(fv[j]);
            Ah[kk][j] = (short)hb;
            Al[kk][j] = (short)f2bf(fv[j] - bf2f(hb));
        }
    }
    const int rbase = kg * 4;
#pragma unroll
    for (int cti = 0; cti < CTP; cti++) {
        const int ct = csel * CTP + cti;
#pragma unroll
        for (int which = 0; which < 2; which++) {
            const unsigned short* WH = which ? WHb : WHa;
            const unsigned short* WL = which ? WLb : WLa;
            const float* bias = which ? biasB : biasA;
            float* out = which ? outB : outA;
            f32x4 acc = {0.f, 0.f, 0.f, 0.f};
#pragma unroll
            for (int kk = 0; kk < KCH; kk++) {
                const int bidx = ((ct * KCH + kk) * 64 + lane) * 8;
                const bf16x8s Bh = *(const bf16x8s*)&WH[bidx];
                const bf16x8s Bl = *(const bf16x8s*)&WL[bidx];
                acc = __builtin_amdgcn_mfma_f32_16x16x32_bf16(Ah[kk], Bh, acc, 0, 0, 0);
                acc = __builtin_amdgcn_mfma_f32_16x16x32_bf16(Ah[kk], Bl, acc, 0, 0, 0);
                acc = __builtin_amdgcn_mfma_f32_16x16x32_bf16(Al[kk], Bh, acc, 0, 0, 0);
            }
            const float bv = bias[ct * 16 + rr];
#pragma unroll
            for (int r = 0; r < 4; r++) {
                const int row = row0 + rbase + r;
                if (row < M) out[(size_t)row * KO + ct * 16 + rr] = acc[r] + bv;
            }
        }
    }
}

// ---------------- CSR build ----------------
__global__ __launch_bounds__(256) void count_edges(const int* __restrict__ ei,
                                                   int* __restrict__ counts)
{
    int e = blockIdx.x * 256 + threadIdx.x;
    if (e < kE) atomicAdd(&counts[ei[kE + e]], 1);
}

// 3-phase parallel scan: counts(+1 self-loop) -> exclusive prefix in cursor
__global__ __launch_bounds__(256) void scan_part(const int* __restrict__ counts,
                                                 int* __restrict__ cursor,
                                                 int* __restrict__ partials)
{
    __shared__ int lds[256];
    const int tid = threadIdx.x;
    const int i = blockIdx.x * 256 + tid;
    const int v = (i < kN) ? counts[i] + 1 : 0;   // +1 = self-loop slot
    lds[tid] = v; __syncthreads();
    for (int d = 1; d < 256; d <<= 1) {
        int t = (tid >= d) ? lds[tid - d] : 0;
        __syncthreads();
        lds[tid] += t;
        __syncthreads();
    }
    if (i < kN) cursor[i] = lds[tid] - v;          // block-local exclusive
    if (tid == 255) partials[blockIdx.x] = lds[255];
}

__global__ __launch_bounds__(128) void scan_mid(int* __restrict__ partials)
{
    __shared__ int lds[128];
    const int tid = threadIdx.x;
    const int v = (tid < kNBLK) ? partials[tid] : 0;
    lds[tid] = v; __syncthreads();
    for (int d = 1; d < 128; d <<= 1) {
        int t = (tid >= d) ? lds[tid - d] : 0;
        __syncthreads();
        lds[tid] += t;
        __syncthreads();
    }
    if (tid < kNBLK) partials[tid] = lds[tid] - v; // exclusive block prefix
}

__global__ __launch_bounds__(256) void scan_add(int* __restrict__ cursor,
                                                const int* __restrict__ partials)
{
    const int i = blockIdx.x * 256 + threadIdx.x;
    if (i < kN) cursor[i] += partials[blockIdx.x];
}

// scatter + pad slots [kTaug, kTpad) with inert entries
__global__ __launch_bounds__(256) void scatter_kernel(const int* __restrict__ ei,
                                                      int* __restrict__ cursor,
                                                      int* __restrict__ csr_src,
                                                      int* __restrict__ csr_eid,
                                                      int* __restrict__ csr_dst)
{
    int gid = blockIdx.x * 256 + threadIdx.x;
    if (gid < kE) {
        int s = ei[gid];
        int d = ei[kE + gid];
        int p = atomicAdd(&cursor[d], 1);
        csr_src[p] = s;
        csr_eid[p] = gid;
        csr_dst[p] = d;
    } else if (gid < kTaug) {
        int n = gid - kE;
        int p = atomicAdd(&cursor[n], 1);
        csr_src[p] = n;
        csr_eid[p] = kE;   // sentinel: self-loop
        csr_dst[p] = n;
    } else if (gid < kTpad) {
        csr_src[gid] = 0;
        csr_eid[gid] = kE;       // sentinel (reads eamean; contribution masked to 0)
        csr_dst[gid] = kN - 1;
    }
}

// ---------------- Fused pass: per-edge attention + per-node aggregation ----------------
// R13: both 8-edge batches of a half interleaved — 32 gathers in flight, two
// lockstep reduce chains, one LDS pe round-trip for 16 values, single ordered
// accumulate. Chain traversals per tile: 4 -> 2 (was latency-bound at VALU 48%).
__global__ __launch_bounds__(256) void edge_logit_aggr_kernel(
    const float* __restrict__ xl, const float* __restrict__ xr,
    const float* __restrict__ ea, const float* __restrict__ eamean,
    const unsigned short* __restrict__ fragh, const unsigned short* __restrict__ fragl,
    const float* __restrict__ att,
    const int* __restrict__ csr_src, const int* __restrict__ csr_dst,
    const int* __restrict__ csr_eid,
    float* __restrict__ accbuf, float* __restrict__ denbuf)
{
    constexpr int ROWS = 40;                       // padded ea row (shorts), 80B
    constexpr int EPP  = 257;                      // padded ep row (floats), 16-edge half
    __shared__ __align__(16) unsigned short ea_hi[32 * ROWS];
    __shared__ __align__(16) unsigned short ea_lo[32 * ROWS];
    __shared__ __align__(16) float ep_lds[16 * EPP];
    __shared__ __align__(16) float lds_pe[4][16];
    const int tid  = threadIdx.x;
    const int w    = tid >> 6;
    const int lane = tid & 63;
    const int b0   = blockIdx.x * 32;

    // B fragments: 8 coalesced b128 loads from pre-swizzled tables
    bf16x8s bh[4], bl[4];
#pragma unroll
    for (int nt = 0; nt < 4; nt++) {
        const int idx = ((nt * 4 + w) * 64 + lane) * 8;
        bh[nt] = *(const bf16x8s*)&fragh[idx];
        bl[nt] = *(const bf16x8s*)&fragl[idx];
    }
    const float att_r = att[tid];
    const int aoff  = (lane & 15) * ROWS + (lane >> 4) * 8;
    const int cbase = w * 64 + (lane & 15);
    const int rbase = (lane >> 4) * 4;

    // stage ea rows (csr padded to kTpad: no clamp needed)
    {
        const int j = tid >> 3, q = tid & 7;
        const int eid = csr_eid[b0 + j];
        const float4* srcp = (eid < kE) ? (const float4*)(ea + (size_t)eid * 32)
                                        : (const float4*)eamean;
        const float4 f = srcp[q];
        const unsigned short h0 = f2bf(f.x), h1 = f2bf(f.y),
                             h2 = f2bf(f.z), h3 = f2bf(f.w);
        const unsigned short g0 = f2bf(f.x - bf2f(h0)), g1 = f2bf(f.y - bf2f(h1)),
                             g2 = f2bf(f.z - bf2f(h2)), g3 = f2bf(f.w - bf2f(h3));
        const unsigned long long ph =
            (unsigned long long)h0 | ((unsigned long long)h1 << 16) |
            ((unsigned long long)h2 << 32) | ((unsigned long long)h3 << 48);
        const unsigned long long pl =
            (unsigned long long)g0 | ((unsigned long long)g1 << 16) |
            ((unsigned long long)g2 << 32) | ((unsigned long long)g3 << 48);
        *(unsigned long long*)&ea_hi[j * ROWS + q * 4] = ph;
        *(unsigned long long*)&ea_lo[j * ROWS + q * 4] = pl;
    }
    __syncthreads();

    int   cur_dst = csr_dst[b0];                   // wave-uniform scalar
    float den_p = 0.f, acc_p = 0.f;

#pragma unroll
    for (int half = 0; half < 2; half++) {
        const bf16x8s ah = *(const bf16x8s*)&ea_hi[half * 16 * ROWS + aoff];
        const bf16x8s al = *(const bf16x8s*)&ea_lo[half * 16 * ROWS + aoff];
#pragma unroll
        for (int nt = 0; nt < 4; nt++) {
            f32x4 a = {0.f, 0.f, 0.f, 0.f};
            a = __builtin_amdgcn_mfma_f32_16x16x32_bf16(ah, bh[nt], a, 0, 0, 0);
            a = __builtin_amdgcn_mfma_f32_16x16x32_bf16(ah, bl[nt], a, 0, 0, 0);
            a = __builtin_amdgcn_mfma_f32_16x16x32_bf16(al, bh[nt], a, 0, 0, 0);
            const int cc = cbase + nt * 16;
#pragma unroll
            for (int r = 0; r < 4; r++)
                ep_lds[(rbase + r) * EPP + cc] = a[r];
        }
        __syncthreads();

        // ---- both 8-edge batches of this half, interleaved ----
        const int e0g = b0 + half * 16;
        int sv_s[16], dv_s[16];
#pragma unroll
        for (int u = 0; u < 16; u++) {
            sv_s[u] = csr_src[e0g + u];            // uniform -> scalar pipe
            dv_s[u] = csr_dst[e0g + u];
        }
        float xls[16], c[16];
#pragma unroll
        for (int u = 0; u < 16; u++) {
            const float* __restrict__ xlp = xl + (size_t)sv_s[u] * 256;
            xls[u] = xlp[tid];                     // 16 gathers in flight
        }
#pragma unroll
        for (int u = 0; u < 16; u++) {
            const float* __restrict__ xrp = xr + (size_t)dv_s[u] * 256;
            const float xrr = xrp[tid];
            float v = xls[u] + xrr + ep_lds[u * EPP + tid];
            v = fmaxf(v, 0.2f * v);                // leaky_relu 0.2
            c[u] = att_r * v;
        }

        // two lockstep multi-value exchange reduces (groups: c[0..7], c[8..15])
        float n[8];
        {   const bool s = lane & 1;
#pragma unroll
            for (int p = 0; p < 8; p++) {
                const float x0 = s ? c[2 * p + 1] : c[2 * p];
                const float x1 = s ? c[2 * p] : c[2 * p + 1];
                n[p] = x0 + dpp_mov<0xB1>(x1);
            }
        }
        float m[4];
        {   const bool s = lane & 2;
#pragma unroll
            for (int p = 0; p < 4; p++) {
                const float x0 = s ? n[2 * p + 1] : n[2 * p];
                const float x1 = s ? n[2 * p] : n[2 * p + 1];
                m[p] = x0 + dpp_mov<0x4E>(x1);
            }
        }
        float r0, r1;
        {   const bool s = lane & 32;
            const float o0 = __shfl_xor(s ? m[0] : m[1], 32);
            r0 = (s ? m[1] : m[0]) + o0;
            const float o1 = __shfl_xor(s ? m[2] : m[3], 32);
            r1 = (s ? m[3] : m[2]) + o1;
        }
        r0 = dpp_add<0x124>(r0);  r1 = dpp_add<0x124>(r1);   // row_ror:4
        r0 = dpp_add<0x128>(r0);  r1 = dpp_add<0x128>(r1);   // row_ror:8
        r0 += __shfl_xor(r0, 16); r1 += __shfl_xor(r1, 16);
        // lane holds logits for edges u0=(l&3)|((l>>3)&4) and 8+u0
        const float pe0 = __expf(r0);
        const float pe1 = __expf(r1);

        // pe broadcast via LDS: lanes {0..3,32..35} publish both groups
        if ((lane & 0x1C) == 0) {
            const int slot = (lane & 3) | ((lane >> 3) & 4);
            lds_pe[w][slot]     = pe0;
            lds_pe[w][8 + slot] = pe1;
        }
        float pu[16];
        {
            const float4 p0 = *(const float4*)&lds_pe[w][0];
            const float4 p1 = *(const float4*)&lds_pe[w][4];
            const float4 p2 = *(const float4*)&lds_pe[w][8];
            const float4 p3 = *(const float4*)&lds_pe[w][12];
            pu[0]=p0.x; pu[1]=p0.y; pu[2]=p0.z; pu[3]=p0.w;
            pu[4]=p1.x; pu[5]=p1.y; pu[6]=p1.z; pu[7]=p1.w;
            pu[8]=p2.x; pu[9]=p2.y; pu[10]=p2.z; pu[11]=p2.w;
            pu[12]=p3.x; pu[13]=p3.y; pu[14]=p3.z; pu[15]=p3.w;
        }
        if (e0g + 16 > kTaug) {                    // tail: zero padded edges
#pragma unroll
            for (int u = 0; u < 16; u++)
                if (e0g + u >= kTaug) pu[u] = 0.f;
        }
        // single ordered segmented accumulate over 16 edges (dv_s scalar)
#pragma unroll
        for (int u = 0; u < 16; u++) {
            if (dv_s[u] != cur_dst) {
                atomicAdd(&accbuf[(size_t)cur_dst * 256 + tid], acc_p);
                if (lane == 0) atomicAdd(&denbuf[cur_dst * 4 + w], den_p);
                acc_p = 0.f; den_p = 0.f; cur_dst = dv_s[u];
            }
            acc_p += pu[u] * xls[u];
            den_p += pu[u];
        }
        __syncthreads();                           // ep_lds reuse
    }

    atomicAdd(&accbuf[(size_t)cur_dst * 256 + tid], acc_p);
    if (lane == 0) atomicAdd(&denbuf[cur_dst * 4 + w], den_p);
}

// ---------------- finalize: h = relu(mean_h(acc/den) + bias); optionally re-zero acc/den ----------------
template<bool ZERO>
__global__ __launch_bounds__(256) void gat_finalize(
    float* __restrict__ accbuf, float* __restrict__ denbuf,
    const float* __restrict__ gbias, float* __restrict__ h_out)
{
    __shared__ float red[256];
    const int tid = threadIdx.x;
    const int n = blockIdx.x;
    red[tid] = accbuf[(size_t)n * 256 + tid] / denbuf[n * 4 + (tid >> 6)];
    if (ZERO) {
        accbuf[(size_t)n * 256 + tid] = 0.f;
        if ((tid & 63) == 0) denbuf[n * 4 + (tid >> 6)] = 0.f;
    }
    __syncthreads();
    if (tid < 64) {
        float sres = red[tid] + red[tid + 64] + red[tid + 128] + red[tid + 192];
        h_out[n * 64 + tid] = fmaxf(0.25f * sres + gbias[tid], 0.f);
    }
}

// ---------------- node head: P[n][0:16]=h@W13[0:64], P[n][16:32]=h@W13[64:128] ----------------
__global__ __launch_bounds__(256) void node_head_kernel(
    const float* __restrict__ h, const float* __restrict__ intW,
    const float* __restrict__ impW, float* __restrict__ P)
{
    const int tid = threadIdx.x;
    const int w = tid >> 6, lane = tid & 63;
    const int row0 = blockIdx.x * 64 + w * 16;
    const int rr = lane & 15;
    const int kg = lane >> 4;

    bf16x8s Bh[2][2], Bl[2][2];
#pragma unroll
    for (int ct = 0; ct < 2; ct++) {
#pragma unroll
        for (int kk = 0; kk < 2; kk++) {
            const int kbase = ct * 64 + kk * 32 + kg * 8;
#pragma unroll
            for (int j = 0; j < 8; j++) {
                const int k = kbase + j;
                float wv;
                if (rr < 12)       wv = intW[k * 12 + rr];
                else if (rr == 12) wv = impW[k];
                else               wv = 0.f;
                const unsigned short hb = f2bf(wv);
                Bh[ct][kk][j] = (short)hb;
                Bl[ct][kk][j] = (short)f2bf(wv - bf2f(hb));
            }
        }
    }

    const int arow = min(row0 + rr, kN - 1);
    bf16x8s Ah[2], Al[2];
#pragma unroll
    for (int kk = 0; kk < 2; kk++) {
        const float4 f0 = *(const float4*)&h[arow * 64 + kk * 32 + kg * 8];
        const float4 f1 = *(const float4*)&h[arow * 64 + kk * 32 + kg * 8 + 4];
        const float fv[8] = {f0.x, f0.y, f0.z, f0.w, f1.x, f1.y, f1.z, f1.w};
#pragma unroll
        for (int j = 0; j < 8; j++) {
            const unsigned short hb = f2bf(fv[j]);
            Ah[kk][j] = (short)hb;
            Al[kk][j] = (short)f2bf(fv[j] - bf2f(hb));
        }
    }

#pragma unroll
    for (int ct = 0; ct < 2; ct++) {
        f32x4 acc = {0.f, 0.f, 0.f, 0.f};
#pragma unroll
        for (int kk = 0; kk < 2; kk++) {
            acc = __builtin_amdgcn_mfma_f32_16x16x32_bf16(Ah[kk], Bh[ct][kk], acc, 0, 0, 0);
            acc = __builtin_amdgcn_mfma_f32_16x16x32_bf16(Ah[kk], Bl[ct][kk], acc, 0, 0, 0);
            acc = __builtin_amdgcn_mfma_f32_16x16x32_bf16(Al[kk], Bh[ct][kk], acc, 0, 0, 0);
        }
        const int crow0 = kg * 4;
#pragma unroll
        for (int r = 0; r < 4; r++) {
            const int row = row0 + crow0 + r;
            if (row < kN) P[row * 32 + ct * 16 + rr] = acc[r];
        }
    }
}

// ---------------- edge out: Q = relu(ea)@W13[128:160]; out = Q + P_src + P_dst + b ----------------
__global__ __launch_bounds__(256) void edge_out_kernel(
    const float* __restrict__ ea, const int* __restrict__ ei,
    const float* __restrict__ P,
    const float* __restrict__ intW, const float* __restrict__ intb,
    const float* __restrict__ impW, const float* __restrict__ impb,
    float* __restrict__ out)
{
    constexpr int ROWS = 40;
    __shared__ __align__(16) unsigned short ehi[4][16 * ROWS];
    __shared__ __align__(16) unsigned short elo[4][16 * ROWS];
    const int tid = threadIdx.x;
    const int w = tid >> 6, lane = tid & 63;
    const int e0 = blockIdx.x * 64 + w * 16;
    const int rr = lane & 15, kg = lane >> 4;

    bf16x8s Bh, Bl;
#pragma unroll
    for (int j = 0; j < 8; j++) {
        const int k = 128 + kg * 8 + j;
        float wv;
        if (rr < 12)       wv = intW[k * 12 + rr];
        else if (rr == 12) wv = impW[k];
        else               wv = 0.f;
        const unsigned short hb = f2bf(wv);
        Bh[j] = (short)hb;
        Bl[j] = (short)f2bf(wv - bf2f(hb));
    }

    {
        const int j = lane >> 2, q = lane & 3;
        const float4* src = (const float4*)&ea[(size_t)(e0 + j) * 32 + q * 8];
        const float4 f0 = src[0], f1 = src[1];
        const float fv[8] = {fmaxf(f0.x, 0.f), fmaxf(f0.y, 0.f), fmaxf(f0.z, 0.f), fmaxf(f0.w, 0.f),
                             fmaxf(f1.x, 0.f), fmaxf(f1.y, 0.f), fmaxf(f1.z, 0.f), fmaxf(f1.w, 0.f)};
        unsigned long long ph0 = 0, pl0 = 0, ph1 = 0, pl1 = 0;
#pragma unroll
        for (int t = 0; t < 4; t++) {
            const unsigned short hb = f2bf(fv[t]);
            const unsigned short lb = f2bf(fv[t] - bf2f(hb));
            ph0 |= (unsigned long long)hb << (16 * t);
            pl0 |= (unsigned long long)lb << (16 * t);
        }
#pragma unroll
        for (int t = 0; t < 4; t++) {
            const unsigned short hb = f2bf(fv[4 + t]);
            const unsigned short lb = f2bf(fv[4 + t] - bf2f(hb));
            ph1 |= (unsigned long long)hb << (16 * t);
            pl1 |= (unsigned long long)lb << (16 * t);
        }
        *(unsigned long long*)&ehi[w][j * ROWS + q * 8]     = ph0;
        *(unsigned long long*)&ehi[w][j * ROWS + q * 8 + 4] = ph1;
        *(unsigned long long*)&elo[w][j * ROWS + q * 8]     = pl0;
        *(unsigned long long*)&elo[w][j * ROWS + q * 8 + 4] = pl1;
    }
    __syncthreads();

    const int aoff = rr * ROWS + kg * 8;
    const bf16x8s Ah = *(const bf16x8s*)&ehi[w][aoff];
    const bf16x8s Al = *(const bf16x8s*)&elo[w][aoff];
    f32x4 q = {0.f, 0.f, 0.f, 0.f};
    q = __builtin_amdgcn_mfma_f32_16x16x32_bf16(Ah, Bh, q, 0, 0, 0);
    q = __builtin_amdgcn_mfma_f32_16x16x32_bf16(Ah, Bl, q, 0, 0, 0);
    q = __builtin_amdgcn_mfma_f32_16x16x32_bf16(Al, Bh, q, 0, 0, 0);

    if (rr < 13) {
        const float bv = (rr < 12) ? intb[rr] : impb[0];
#pragma unroll
        for (int r = 0; r < 4; r++) {
            const int e = e0 + kg * 4 + r;
            const int s = ei[e], d = ei[kE + e];
            const float val = q[r] + P[s * 32 + rr] + P[d * 32 + 16 + rr] + bv;
            if (rr < 12) out[(size_t)e * 12 + rr] = val;
            else         out[(size_t)kE * 12 + e] = 1.f / (1.f + __expf(-val));
        }
    }
}

// ---------------- launch ----------------
extern "C" void kernel_launch(void* const* d_in, const int* in_sizes, int n_in,
                              void* d_out, int out_size, void* d_ws, size_t ws_size,
                              hipStream_t stream)
{
    (void)in_sizes; (void)n_in; (void)out_size; (void)ws_size;

    const float* x      = (const float*)d_in[0];
    const int*   ei     = (const int*)d_in[1];
    const float* ea     = (const float*)d_in[2];
    const float* emb_W  = (const float*)d_in[3];
    const float* emb_b  = (const float*)d_in[4];
    const float* g1_Wl  = (const float*)d_in[5];
    const float* g1_bl  = (const float*)d_in[6];
    const float* g1_Wr  = (const float*)d_in[7];
    const float* g1_br  = (const float*)d_in[8];
    const float* g1_We  = (const float*)d_in[9];
    const float* g1_att = (const float*)d_in[10];
    const float* g1_bias= (const float*)d_in[11];
    const float* g2_Wl  = (const float*)d_in[12];
    const float* g2_bl  = (const float*)d_in[13];
    const float* g2_Wr  = (const float*)d_in[14];
    const float* g2_br  = (const float*)d_in[15];
    const float* g2_We  = (const float*)d_in[16];
    const float* g2_att = (const float*)d_in[17];
    const float* g2_bias= (const float*)d_in[18];
    const float* int_W  = (const float*)d_in[19];
    const float* int_b  = (const float*)d_in[20];
    const float* imp_W  = (const float*)d_in[21];
    const float* imp_b  = (const float*)d_in[22];

    char* ws = (char*)d_ws;
    float* eapart  = (float*)(ws + OFF_EAPART);
    float* eamean  = (float*)(ws + OFF_EAMEAN);
    int*   partials= (int*)  (ws + OFF_PART);
    int*   cursor  = (int*)  (ws + OFF_CURSOR);
    int*   csrsrc  = (int*)  (ws + OFF_CSRSRC);
    int*   csreid  = (int*)  (ws + OFF_CSREID);
    int*   csrdst  = (int*)  (ws + OFF_CSRDST);
    float* accbuf  = (float*)(ws + OFF_ACC);
    float* denbuf  = (float*)(ws + OFF_DEN);
    int*   counts  = (int*)  (ws + OFF_COUNTS);
    float* h_a     = (float*)(ws + OFF_HA);
    float* h_b     = (float*)(ws + OFF_HB);
    float* xl      = (float*)(ws + OFF_XL);
    float* xr      = (float*)(ws + OFF_XR);
    unsigned short* tab = (unsigned short*)(ws + OFF_TAB);
    float* P       = accbuf;                  // reuse acc region after finalize2
    float* outp    = (float*)d_out;

    constexpr int NT = (kTaug + 31) / 32;     // 13282 edge tiles
    constexpr int NGB = (kN + 63) / 64;       // 391 row blocks for MFMA gemms

    // zero acc + den + counts (one contiguous memset)
    hipMemsetAsync(ws + OFF_ACC, 0, MEMSET_BYTES, stream);

    // edge_attr mean + all weight-frag tables (2 launches)
    ea_colsum_part<<<1024, 256, 0, stream>>>(ea, eapart);
    ea_colsum_final<<<1, 256, 0, stream>>>(eapart, eamean);
    we_swizzle<<<32, 256, 0, stream>>>(g1_We, g2_We, tab);
    w_tables<<<288, 256, 0, stream>>>(emb_W, g1_Wl, g1_Wr, g2_Wl, g2_Wr, tab);

    // CSR by destination (self-loops included); counts pre-zeroed by memset
    count_edges<<<(kE + 255) / 256, 256, 0, stream>>>(ei, counts);
    scan_part<<<kNBLK, 256, 0, stream>>>(counts, cursor, partials);
    scan_mid<<<1, 128, 0, stream>>>(partials);
    scan_add<<<kNBLK, 256, 0, stream>>>(cursor, partials);
    scatter_kernel<<<(kTpad + 255) / 256, 256, 0, stream>>>(ei, cursor, csrsrc, csreid, csrdst);

    // node embedding (MFMA split-bf16, col-split grid)
    mfma_gemm_bias<128, 64, 2><<<NGB * 2, 256, 0, stream>>>(
        x, tab + T_EMBH, tab + T_EMBL, emb_b, h_a, kN);

    // ---- GAT layer 1 ----
    mfma_gemm_bias2<64, 256, 4><<<NGB * 4, 256, 0, stream>>>(
        h_a, tab + T_L1H, tab + T_L1L, tab + T_R1H, tab + T_R1L,
        g1_bl, g1_br, xl, xr, kN);
    edge_logit_aggr_kernel<<<NT, 256, 0, stream>>>(xl, xr, ea, eamean,
        tab + T_F1H, tab + T_F1L, g1_att, csrsrc, csrdst, csreid, accbuf, denbuf);
    gat_finalize<true><<<kN, 256, 0, stream>>>(accbuf, denbuf, g1_bias, h_b);

    // ---- GAT layer 2 (acc/den re-zeroed by finalize<true>) ----
    mfma_gemm_bias2<64, 256, 4><<<NGB * 4, 256, 0, stream>>>(
        h_b, tab + T_L2H, tab + T_L2L, tab + T_R2H, tab + T_R2L,
        g2_bl, g2_br, xl, xr, kN);
    edge_logit_aggr_kernel<<<NT, 256, 0, stream>>>(xl, xr, ea, eamean,
        tab + T_F2H, tab + T_F2L, g2_att, csrsrc, csrdst, csreid, accbuf, denbuf);
    gat_finalize<false><<<kN, 256, 0, stream>>>(accbuf, denbuf, g2_bias, h_a);

    // ---- edge heads (decomposed) ----
    node_head_kernel<<<(kN + 63) / 64, 256, 0, stream>>>(h_a, int_W, imp_W, P);
    edge_out_kernel<<<kE / 64, 256, 0, stream>>>(ea, ei, P, int_W, int_b, imp_W, imp_b, outp);
}

// Round 15
// 391.796 us; speedup vs baseline: 1.8516x; 1.0229x over previous
//
#include <hip/hip_runtime.h>
#include <math.h>

// Problem constants
constexpr int kN = 25000;
constexpr int kE = 400000;
constexpr int kTaug = kE + kN;        // CSR slots incl self-loops = 425000
constexpr int kTpad = 425024;         // padded to tile boundary (13282*32)
constexpr int kNBLK = (kN + 255) / 256;   // 98 scan blocks

typedef __attribute__((ext_vector_type(8))) short bf16x8s;   // 8 bf16 (4 VGPRs)
typedef __attribute__((ext_vector_type(4))) float f32x4;

__device__ __forceinline__ unsigned short f2bf(float f) {
    unsigned u = __builtin_bit_cast(unsigned, f);
    unsigned r = (u + 0x7FFFu + ((u >> 16) & 1u)) >> 16;     // RNE
    return (unsigned short)r;
}
__device__ __forceinline__ float bf2f(unsigned short h) {
    unsigned u = ((unsigned)h) << 16;
    return __builtin_bit_cast(float, u);
}

// DPP helpers (CTRL must be compile-time constant)
template<int CTRL>
__device__ __forceinline__ float dpp_mov(float x) {
    int yi = __builtin_amdgcn_update_dpp(0, __builtin_bit_cast(int, x), CTRL, 0xF, 0xF, true);
    return __builtin_bit_cast(float, yi);
}
template<int CTRL>
__device__ __forceinline__ float dpp_add(float x) {
    return x + dpp_mov<CTRL>(x);
}

// ---------------- workspace layout (256B aligned) ----------------
constexpr size_t OFF_EAPART = 0;            // 1024*32 f32
constexpr size_t OFF_EAMEAN = 131072;       // 32 f32
constexpr size_t OFF_PART   = 131328;       // 98 i32 (scan partials)
constexpr size_t OFF_CURSOR = 131840;       // N i32
constexpr size_t OFF_CSRSRC = 231936;       // kTpad i32
constexpr size_t OFF_CSREID = 1932032;      // kTpad i32
constexpr size_t OFF_CSRDST = 3632128;      // kTpad i32
constexpr size_t OFF_ACC    = 5332224;      // N*256 f32 (atomic acc; reused as P)
constexpr size_t OFF_DEN    = 30932224;     // N*4 f32
constexpr size_t OFF_COUNTS = 31332224;     // N i32 (inside the memset region)
constexpr size_t MEMSET_BYTES = 31332224 + 100000 - 5332224;   // acc+den+counts
constexpr size_t OFF_HA     = 31432448;     // N*64 f32
constexpr size_t OFF_HB     = 37832448;     // N*64 f32
constexpr size_t OFF_XL     = 44232448;     // N*256 f32
constexpr size_t OFF_XR     = 69832448;     // N*256 f32
constexpr size_t OFF_TAB    = 95432448;     // contiguous weight-frag tables (~426KB)
// element (u16) offsets within TAB:
constexpr int T_F1H = 0,      T_F1L = 8192,  T_F2H = 16384, T_F2L = 24576;
constexpr int T_EMBH = 32768, T_EMBL = 49152;
constexpr int T_L1H = 65536,  T_L1L = 81920, T_R1H = 98304, T_R1L = 114688;
constexpr int T_L2H = 131072, T_L2L = 147456, T_R2H = 163840, T_R2L = 180224;

// ---------------- edge_attr column mean ----------------
__global__ __launch_bounds__(256) void ea_colsum_part(const float* __restrict__ ea,
                                                      float* __restrict__ part)
{
    __shared__ float lds[256];
    const int tid = threadIdx.x;
    const int k = tid & 31, g = tid >> 5;
    float acc = 0.f;
    for (int r = blockIdx.x * 8 + g; r < kE; r += gridDim.x * 8)
        acc += ea[(size_t)r * 32 + k];
    lds[tid] = acc; __syncthreads();
    if (tid < 128) lds[tid] += lds[tid + 128]; __syncthreads();
    if (tid < 64)  lds[tid] += lds[tid + 64];  __syncthreads();
    if (tid < 32)  part[blockIdx.x * 32 + k] = lds[tid] + lds[tid + 32];
}

__global__ __launch_bounds__(256) void ea_colsum_final(const float* __restrict__ part,
                                                       float* __restrict__ ea_mean)
{
    __shared__ float lds[256];
    const int tid = threadIdx.x;
    const int k = tid & 31, g = tid >> 5;
    float acc = 0.f;
    for (int p = g; p < 1024; p += 8) acc += part[p * 32 + k];
    lds[tid] = acc; __syncthreads();
    if (tid < 128) lds[tid] += lds[tid + 128]; __syncthreads();
    if (tid < 64)  lds[tid] += lds[tid + 64];  __syncthreads();
    if (tid < 32)  ea_mean[k] = (lds[tid] + lds[tid + 32]) * (1.0f / (float)kE);
}

// ---------------- We -> frag-swizzled bf16 hi/lo (edge_logit tables) ----------------
__global__ __launch_bounds__(256) void we_swizzle(const float* __restrict__ W1,
                                                  const float* __restrict__ W2,
                                                  unsigned short* __restrict__ tab)
{
    const int b = blockIdx.x;                 // 32 blocks: layer*16 + nt*4 + w
    const int layer = b >> 4, nt = (b >> 2) & 3, w = b & 3;
    const float* W = layer ? W2 : W1;
    unsigned short* H = tab + (layer ? T_F2H : T_F1H);
    unsigned short* L = tab + (layer ? T_F2L : T_F1L);
    const int tid = threadIdx.x;
    const int lane = tid & 63, jh = tid >> 6;
    const int c = w * 64 + nt * 16 + (lane & 15);
    const int kbase = (lane >> 4) * 8;
#pragma unroll
    for (int t = 0; t < 2; t++) {
        const int j = jh * 2 + t;
        const float f = W[(kbase + j) * 256 + c];
        const unsigned short hb = f2bf(f);
        const int idx = ((nt * 4 + w) * 64 + lane) * 8 + j;
        H[idx] = hb;
        L[idx] = f2bf(f - bf2f(hb));
    }
}

// ---------------- merged GEMM-weight frag tables (emb + 4 layer weights) ----------------
__global__ __launch_bounds__(256) void w_tables(const float* __restrict__ embW,
                                                const float* __restrict__ wl1,
                                                const float* __restrict__ wr1,
                                                const float* __restrict__ wl2,
                                                const float* __restrict__ wr2,
                                                unsigned short* __restrict__ tab)
{
    const int b = blockIdx.x, tid = threadIdx.x;
    const float* W; int KO, KCH, idx; unsigned short *H, *L;
    if (b < 32) {                 // emb: 4 ctiles x 4 kchunks = 8192 elems
        W = embW; KO = 64; KCH = 4; idx = b * 256 + tid;
        H = tab + T_EMBH; L = tab + T_EMBL;
    } else {                      // 4 tables of 16 ctiles x 2 kchunks = 16384 elems
        const int t = (b - 32) >> 6, r = (b - 32) & 63;
        idx = r * 256 + tid; KO = 256; KCH = 2;
        if      (t == 0) { W = wl1; H = tab + T_L1H; L = tab + T_L1L; }
        else if (t == 1) { W = wr1; H = tab + T_R1H; L = tab + T_R1L; }
        else if (t == 2) { W = wl2; H = tab + T_L2H; L = tab + T_L2L; }
        else             { W = wr2; H = tab + T_R2H; L = tab + T_R2L; }
    }
    const int j = idx & 7;
    const int lane = (idx >> 3) & 63;
    const int t2 = idx >> 9;
    const int ct = t2 / KCH;
    const int c = ct * 16 + (lane & 15);
    const int k = (t2 - ct * KCH) * 32 + (lane >> 4) * 8 + j;
    const float f = W[k * KO + c];
    const unsigned short hb = f2bf(f);
    H[idx] = hb;
    L[idx] = f2bf(f - bf2f(hb));
}

// ---------------- MFMA dense GEMM (single output) ----------------
template<int KI, int KO, int CSPLIT>
__global__ __launch_bounds__(256) void mfma_gemm_bias(
    const float* __restrict__ A,
    const unsigned short* __restrict__ WH, const unsigned short* __restrict__ WL,
    const float* __restrict__ bias, float* __restrict__ out, int M)
{
    constexpr int KCH = KI / 32;
    constexpr int CT  = KO / 16;
    constexpr int CTP = CT / CSPLIT;
    const int tid = threadIdx.x;
    const int w = tid >> 6, lane = tid & 63;
    const int rowblk = blockIdx.x / CSPLIT;
    const int csel   = blockIdx.x % CSPLIT;
    const int row0 = rowblk * 64 + w * 16;
    const int rr = lane & 15, kg = lane >> 4;
    const int arow = min(row0 + rr, M - 1);

    bf16x8s Ah[KCH], Al[KCH];
#pragma unroll
    for (int kk = 0; kk < KCH; kk++) {
        const float4 f0 = *(const float4*)&A[(size_t)arow * KI + kk * 32 + kg * 8];
        const float4 f1 = *(const float4*)&A[(size_t)arow * KI + kk * 32 + kg * 8 + 4];
        const float fv[8] = {f0.x, f0.y, f0.z, f0.w, f1.x, f1.y, f1.z, f1.w};
#pragma unroll
        for (int j = 0; j < 8; j++) {
            const unsigned short hb = f2bf(fv[j]);
            Ah[kk][j] = (short)hb;
            Al[kk][j] = (short)f2bf(fv[j] - bf2f(hb));
        }
    }
    const int rbase = kg * 4;
#pragma unroll
    for (int cti = 0; cti < CTP; cti++) {
        const int ct = csel * CTP + cti;
        f32x4 acc = {0.f, 0.f, 0.f, 0.f};
#pragma unroll
        for (int kk = 0; kk < KCH; kk++) {
            const int bidx = ((ct * KCH + kk) * 64 + lane) * 8;
            const bf16x8s Bh = *(const bf16x8s*)&WH[bidx];
            const bf16x8s Bl = *(const bf16x8s*)&WL[bidx];
            acc = __builtin_amdgcn_mfma_f32_16x16x32_bf16(Ah[kk], Bh, acc, 0, 0, 0);
            acc = __builtin_amdgcn_mfma_f32_16x16x32_bf16(Ah[kk], Bl, acc, 0, 0, 0);
            acc = __builtin_amdgcn_mfma_f32_16x16x32_bf16(Al[kk], Bh, acc, 0, 0, 0);
        }
        const float bv = bias[ct * 16 + rr];
#pragma unroll
        for (int r = 0; r < 4; r++) {
            const int row = row0 + rbase + r;
            if (row < M) out[(size_t)row * KO + ct * 16 + rr] = acc[r] + bv;
        }
    }
}

// ---------------- MFMA dense GEMM, dual output (Wl,Wr share A; A staged once) ----------------
template<int KI, int KO, int CSPLIT>
__global__ __launch_bounds__(256) void mfma_gemm_bias2(
    const float* __restrict__ A,
    const unsigned short* __restrict__ WHa, const unsigned short* __restrict__ WLa,
    const unsigned short* __restrict__ WHb, const unsigned short* __restrict__ WLb,
    const float* __restrict__ biasA, const float* __restrict__ biasB,
    float* __restrict__ outA, float* __restrict__ outB, int M)
{
    constexpr int KCH = KI / 32;
    constexpr int CT  = KO / 16;
    constexpr int CTP = CT / CSPLIT;
    const int tid = threadIdx.x;
    const int w = tid >> 6, lane = tid & 63;
    const int rowblk = blockIdx.x / CSPLIT;
    const int csel   = blockIdx.x % CSPLIT;
    const int row0 = rowblk * 64 + w * 16;
    const int rr = lane & 15, kg = lane >> 4;
    const int arow = min(row0 + rr, M - 1);

    bf16x8s Ah[KCH], Al[KCH];
#pragma unroll
    for (int kk = 0; kk < KCH; kk++) {
        const float4 f0 = *(const float4*)&A[(size_t)arow * KI + kk * 32 + kg * 8];
        const float4 f1 = *(const float4*)&A[(size_t)arow * KI + kk * 32 + kg * 8 + 4];
        const float fv[8] = {f0.x, f0.y, f0.z, f0.w, f1.x, f1.y, f1.z, f1.w};
#pragma unroll
        for (int j = 0; j < 8; j++) {
            const unsigned short hb = f2bf(fv[j]);
            Ah[kk][j] = (short)hb;
            Al[kk][j] = (short)f2bf(fv[j] - bf2f(hb));
        }
    }
    const int rbase = kg * 4;
#pragma unroll
    for (int cti = 0; cti < CTP; cti++) {
        const int ct = csel * CTP + cti;
#pragma unroll
        for (int which = 0; which < 2; which++) {
            const unsigned short* WH = which ? WHb : WHa;
            const unsigned short* WL = which ? WLb : WLa;
            const float* bias = which ? biasB : biasA;
            float* out = which ? outB : outA;
            f32x4 acc = {0.f, 0.f, 0.f, 0.f};
#pragma unroll
            for (int kk = 0; kk < KCH; kk++) {
                const int bidx = ((ct * KCH + kk) * 64 + lane) * 8;
                const bf16x8s Bh = *(const bf16x8s*)&WH[bidx];
                const bf16x8s Bl = *(const bf16x8s*)&WL[bidx];
                acc = __builtin_amdgcn_mfma_f32_16x16x32_bf16(Ah[kk], Bh, acc, 0, 0, 0);
                acc = __builtin_amdgcn_mfma_f32_16x16x32_bf16(Ah[kk], Bl, acc, 0, 0, 0);
                acc = __builtin_amdgcn_mfma_f32_16x16x32_bf16(Al[kk], Bh, acc, 0, 0, 0);
            }
            const float bv = bias[ct * 16 + rr];
#pragma unroll
            for (int r = 0; r < 4; r++) {
                const int row = row0 + rbase + r;
                if (row < M) out[(size_t)row * KO + ct * 16 + rr] = acc[r] + bv;
            }
        }
    }
}

// ---------------- CSR build ----------------
__global__ __launch_bounds__(256) void count_edges(const int* __restrict__ ei,
                                                   int* __restrict__ counts)
{
    int e = blockIdx.x * 256 + threadIdx.x;
    if (e < kE) atomicAdd(&counts[ei[kE + e]], 1);
}

// 3-phase parallel scan: counts(+1 self-loop) -> exclusive prefix in cursor
__global__ __launch_bounds__(256) void scan_part(const int* __restrict__ counts,
                                                 int* __restrict__ cursor,
                                                 int* __restrict__ partials)
{
    __shared__ int lds[256];
    const int tid = threadIdx.x;
    const int i = blockIdx.x * 256 + tid;
    const int v = (i < kN) ? counts[i] + 1 : 0;   // +1 = self-loop slot
    lds[tid] = v; __syncthreads();
    for (int d = 1; d < 256; d <<= 1) {
        int t = (tid >= d) ? lds[tid - d] : 0;
        __syncthreads();
        lds[tid] += t;
        __syncthreads();
    }
    if (i < kN) cursor[i] = lds[tid] - v;          // block-local exclusive
    if (tid == 255) partials[blockIdx.x] = lds[255];
}

__global__ __launch_bounds__(128) void scan_mid(int* __restrict__ partials)
{
    __shared__ int lds[128];
    const int tid = threadIdx.x;
    const int v = (tid < kNBLK) ? partials[tid] : 0;
    lds[tid] = v; __syncthreads();
    for (int d = 1; d < 128; d <<= 1) {
        int t = (tid >= d) ? lds[tid - d] : 0;
        __syncthreads();
        lds[tid] += t;
        __syncthreads();
    }
    if (tid < kNBLK) partials[tid] = lds[tid] - v; // exclusive block prefix
}

__global__ __launch_bounds__(256) void scan_add(int* __restrict__ cursor,
                                                const int* __restrict__ partials)
{
    const int i = blockIdx.x * 256 + threadIdx.x;
    if (i < kN) cursor[i] += partials[blockIdx.x];
}

// scatter + pad slots [kTaug, kTpad) with inert entries
__global__ __launch_bounds__(256) void scatter_kernel(const int* __restrict__ ei,
                                                      int* __restrict__ cursor,
                                                      int* __restrict__ csr_src,
                                                      int* __restrict__ csr_eid,
                                                      int* __restrict__ csr_dst)
{
    int gid = blockIdx.x * 256 + threadIdx.x;
    if (gid < kE) {
        int s = ei[gid];
        int d = ei[kE + gid];
        int p = atomicAdd(&cursor[d], 1);
        csr_src[p] = s;
        csr_eid[p] = gid;
        csr_dst[p] = d;
    } else if (gid < kTaug) {
        int n = gid - kE;
        int p = atomicAdd(&cursor[n], 1);
        csr_src[p] = n;
        csr_eid[p] = kE;   // sentinel: self-loop
        csr_dst[p] = n;
    } else if (gid < kTpad) {
        csr_src[gid] = 0;
        csr_eid[gid] = kE;       // sentinel (reads eamean; contribution masked to 0)
        csr_dst[gid] = kN - 1;
    }
}

// ---------------- Fused pass: per-edge attention + per-node aggregation ----------------
// R14: single barrier. All post-staging LDS traffic is wave-disjoint:
// wave w writes/reads ep_lds columns [w*64, w*64+64) and lds_pe[w] only —
// same-wave ds ordering is guaranteed by compiler lgkmcnt waits, so the 4
// per-half __syncthreads were pure lockstep overhead (waves now slip freely).
__global__ __launch_bounds__(256) void edge_logit_aggr_kernel(
    const float* __restrict__ xl, const float* __restrict__ xr,
    const float* __restrict__ ea, const float* __restrict__ eamean,
    const unsigned short* __restrict__ fragh, const unsigned short* __restrict__ fragl,
    const float* __restrict__ att,
    const int* __restrict__ csr_src, const int* __restrict__ csr_dst,
    const int* __restrict__ csr_eid,
    float* __restrict__ accbuf, float* __restrict__ denbuf)
{
    constexpr int ROWS = 40;                       // padded ea row (shorts), 80B
    constexpr int EPP  = 257;                      // padded ep row (floats), 16-edge half
    __shared__ __align__(16) unsigned short ea_hi[32 * ROWS];
    __shared__ __align__(16) unsigned short ea_lo[32 * ROWS];
    __shared__ __align__(16) float ep_lds[16 * EPP];
    __shared__ __align__(16) float lds_pe[4][16];
    const int tid  = threadIdx.x;
    const int w    = tid >> 6;
    const int lane = tid & 63;
    const int b0   = blockIdx.x * 32;

    // B fragments: 8 coalesced b128 loads from pre-swizzled tables
    bf16x8s bh[4], bl[4];
#pragma unroll
    for (int nt = 0; nt < 4; nt++) {
        const int idx = ((nt * 4 + w) * 64 + lane) * 8;
        bh[nt] = *(const bf16x8s*)&fragh[idx];
        bl[nt] = *(const bf16x8s*)&fragl[idx];
    }
    const float att_r = att[tid];
    const int aoff  = (lane & 15) * ROWS + (lane >> 4) * 8;
    const int cbase = w * 64 + (lane & 15);
    const int rbase = (lane >> 4) * 4;

    // stage ea rows (csr padded to kTpad: no clamp needed)
    {
        const int j = tid >> 3, q = tid & 7;
        const int eid = csr_eid[b0 + j];
        const float4* srcp = (eid < kE) ? (const float4*)(ea + (size_t)eid * 32)
                                        : (const float4*)eamean;
        const float4 f = srcp[q];
        const unsigned short h0 = f2bf(f.x), h1 = f2bf(f.y),
                             h2 = f2bf(f.z), h3 = f2bf(f.w);
        const unsigned short g0 = f2bf(f.x - bf2f(h0)), g1 = f2bf(f.y - bf2f(h1)),
                             g2 = f2bf(f.z - bf2f(h2)), g3 = f2bf(f.w - bf2f(h3));
        const unsigned long long ph =
            (unsigned long long)h0 | ((unsigned long long)h1 << 16) |
            ((unsigned long long)h2 << 32) | ((unsigned long long)h3 << 48);
        const unsigned long long pl =
            (unsigned long long)g0 | ((unsigned long long)g1 << 16) |
            ((unsigned long long)g2 << 32) | ((unsigned long long)g3 << 48);
        *(unsigned long long*)&ea_hi[j * ROWS + q * 4] = ph;
        *(unsigned long long*)&ea_lo[j * ROWS + q * 4] = pl;
    }
    __syncthreads();   // the ONLY cross-wave dependency: staging -> MFMA A-reads

    int   cur_dst = csr_dst[b0];                   // wave-uniform scalar
    float den_p = 0.f, acc_p = 0.f;

#pragma unroll
    for (int half = 0; half < 2; half++) {
        const bf16x8s ah = *(const bf16x8s*)&ea_hi[half * 16 * ROWS + aoff];
        const bf16x8s al = *(const bf16x8s*)&ea_lo[half * 16 * ROWS + aoff];
#pragma unroll
        for (int nt = 0; nt < 4; nt++) {
            f32x4 a = {0.f, 0.f, 0.f, 0.f};
            a = __builtin_amdgcn_mfma_f32_16x16x32_bf16(ah, bh[nt], a, 0, 0, 0);
            a = __builtin_amdgcn_mfma_f32_16x16x32_bf16(ah, bl[nt], a, 0, 0, 0);
            a = __builtin_amdgcn_mfma_f32_16x16x32_bf16(al, bh[nt], a, 0, 0, 0);
            const int cc = cbase + nt * 16;
#pragma unroll
            for (int r = 0; r < 4; r++)
                ep_lds[(rbase + r) * EPP + cc] = a[r];
        }
        // no barrier: wave w reads only the ep_lds columns it wrote

        // ---- both 8-edge batches of this half, interleaved ----
        const int e0g = b0 + half * 16;
        int sv_s[16], dv_s[16];
#pragma unroll
        for (int u = 0; u < 16; u++) {
            sv_s[u] = csr_src[e0g + u];            // uniform -> scalar pipe
            dv_s[u] = csr_dst[e0g + u];
        }
        float xls[16], c[16];
#pragma unroll
        for (int u = 0; u < 16; u++) {
            const float* __restrict__ xlp = xl + (size_t)sv_s[u] * 256;
            xls[u] = xlp[tid];                     // 16 gathers in flight
        }
#pragma unroll
        for (int u = 0; u < 16; u++) {
            const float* __restrict__ xrp = xr + (size_t)dv_s[u] * 256;
            const float xrr = xrp[tid];
            float v = xls[u] + xrr + ep_lds[u * EPP + tid];
            v = fmaxf(v, 0.2f * v);                // leaky_relu 0.2
            c[u] = att_r * v;
        }

        // two lockstep multi-value exchange reduces (groups: c[0..7], c[8..15])
        float n[8];
        {   const bool s = lane & 1;
#pragma unroll
            for (int p = 0; p < 8; p++) {
                const float x0 = s ? c[2 * p + 1] : c[2 * p];
                const float x1 = s ? c[2 * p] : c[2 * p + 1];
                n[p] = x0 + dpp_mov<0xB1>(x1);
            }
        }
        float m[4];
        {   const bool s = lane & 2;
#pragma unroll
            for (int p = 0; p < 4; p++) {
                const float x0 = s ? n[2 * p + 1] : n[2 * p];
                const float x1 = s ? n[2 * p] : n[2 * p + 1];
                m[p] = x0 + dpp_mov<0x4E>(x1);
            }
        }
        float r0, r1;
        {   const bool s = lane & 32;
            const float o0 = __shfl_xor(s ? m[0] : m[1], 32);
            r0 = (s ? m[1] : m[0]) + o0;
            const float o1 = __shfl_xor(s ? m[2] : m[3], 32);
            r1 = (s ? m[3] : m[2]) + o1;
        }
        r0 = dpp_add<0x124>(r0);  r1 = dpp_add<0x124>(r1);   // row_ror:4
        r0 = dpp_add<0x128>(r0);  r1 = dpp_add<0x128>(r1);   // row_ror:8
        r0 += __shfl_xor(r0, 16); r1 += __shfl_xor(r1, 16);
        // lane holds logits for edges u0=(l&3)|((l>>3)&4) and 8+u0
        const float pe0 = __expf(r0);
        const float pe1 = __expf(r1);

        // pe broadcast via LDS (lds_pe[w] is wave-private: no barrier)
        if ((lane & 0x1C) == 0) {
            const int slot = (lane & 3) | ((lane >> 3) & 4);
            lds_pe[w][slot]     = pe0;
            lds_pe[w][8 + slot] = pe1;
        }
        float pu[16];
        {
            const float4 p0 = *(const float4*)&lds_pe[w][0];
            const float4 p1 = *(const float4*)&lds_pe[w][4];
            const float4 p2 = *(const float4*)&lds_pe[w][8];
            const float4 p3 = *(const float4*)&lds_pe[w][12];
            pu[0]=p0.x; pu[1]=p0.y; pu[2]=p0.z; pu[3]=p0.w;
            pu[4]=p1.x; pu[5]=p1.y; pu[6]=p1.z; pu[7]=p1.w;
            pu[8]=p2.x; pu[9]=p2.y; pu[10]=p2.z; pu[11]=p2.w;
            pu[12]=p3.x; pu[13]=p3.y; pu[14]=p3.z; pu[15]=p3.w;
        }
        if (e0g + 16 > kTaug) {                    // tail: zero padded edges
#pragma unroll
            for (int u = 0; u < 16; u++)
                if (e0g + u >= kTaug) pu[u] = 0.f;
        }
        // single ordered segmented accumulate over 16 edges (dv_s scalar)
#pragma unroll
        for (int u = 0; u < 16; u++) {
            if (dv_s[u] != cur_dst) {
                atomicAdd(&accbuf[(size_t)cur_dst * 256 + tid], acc_p);
                if (lane == 0) atomicAdd(&denbuf[cur_dst * 4 + w], den_p);
                acc_p = 0.f; den_p = 0.f; cur_dst = dv_s[u];
            }
            acc_p += pu[u] * xls[u];
            den_p += pu[u];
        }
        // no barrier: ep_lds rewrite next half is by the same wave
    }

    atomicAdd(&accbuf[(size_t)cur_dst * 256 + tid], acc_p);
    if (lane == 0) atomicAdd(&denbuf[cur_dst * 4 + w], den_p);
}

// ---------------- finalize: h = relu(mean_h(acc/den) + bias); optionally re-zero acc/den ----------------
template<bool ZERO>
__global__ __launch_bounds__(256) void gat_finalize(
    float* __restrict__ accbuf, float* __restrict__ denbuf,
    const float* __restrict__ gbias, float* __restrict__ h_out)
{
    __shared__ float red[256];
    const int tid = threadIdx.x;
    const int n = blockIdx.x;
    red[tid] = accbuf[(size_t)n * 256 + tid] / denbuf[n * 4 + (tid >> 6)];
    if (ZERO) {
        accbuf[(size_t)n * 256 + tid] = 0.f;
        if ((tid & 63) == 0) denbuf[n * 4 + (tid >> 6)] = 0.f;
    }
    __syncthreads();
    if (tid < 64) {
        float sres = red[tid] + red[tid + 64] + red[tid + 128] + red[tid + 192];
        h_out[n * 64 + tid] = fmaxf(0.25f * sres + gbias[tid], 0.f);
    }
}

// ---------------- node head: P[n][0:16]=h@W13[0:64], P[n][16:32]=h@W13[64:128] ----------------
__global__ __launch_bounds__(256) void node_head_kernel(
    const float* __restrict__ h, const float* __restrict__ intW,
    const float* __restrict__ impW, float* __restrict__ P)
{
    const int tid = threadIdx.x;
    const int w = tid >> 6, lane = tid & 63;
    const int row0 = blockIdx.x * 64 + w * 16;
    const int rr = lane & 15;
    const int kg = lane >> 4;

    bf16x8s Bh[2][2], Bl[2][2];
#pragma unroll
    for (int ct = 0; ct < 2; ct++) {
#pragma unroll
        for (int kk = 0; kk < 2; kk++) {
            const int kbase = ct * 64 + kk * 32 + kg * 8;
#pragma unroll
            for (int j = 0; j < 8; j++) {
                const int k = kbase + j;
                float wv;
                if (rr < 12)       wv = intW[k * 12 + rr];
                else if (rr == 12) wv = impW[k];
                else               wv = 0.f;
                const unsigned short hb = f2bf(wv);
                Bh[ct][kk][j] = (short)hb;
                Bl[ct][kk][j] = (short)f2bf(wv - bf2f(hb));
            }
        }
    }

    const int arow = min(row0 + rr, kN - 1);
    bf16x8s Ah[2], Al[2];
#pragma unroll
    for (int kk = 0; kk < 2; kk++) {
        const float4 f0 = *(const float4*)&h[arow * 64 + kk * 32 + kg * 8];
        const float4 f1 = *(const float4*)&h[arow * 64 + kk * 32 + kg * 8 + 4];
        const float fv[8] = {f0.x, f0.y, f0.z, f0.w, f1.x, f1.y, f1.z, f1.w};
#pragma unroll
        for (int j = 0; j < 8; j++) {
            const unsigned short hb = f2bf(fv[j]);
            Ah[kk][j] = (short)hb;
            Al[kk][j] = (short)f2bf(fv[j] - bf2f(hb));
        }
    }

#pragma unroll
    for (int ct = 0; ct < 2; ct++) {
        f32x4 acc = {0.f, 0.f, 0.f, 0.f};
#pragma unroll
        for (int kk = 0; kk < 2; kk++) {
            acc = __builtin_amdgcn_mfma_f32_16x16x32_bf16(Ah[kk], Bh[ct][kk], acc, 0, 0, 0);
            acc = __builtin_amdgcn_mfma_f32_16x16x32_bf16(Ah[kk], Bl[ct][kk], acc, 0, 0, 0);
            acc = __builtin_amdgcn_mfma_f32_16x16x32_bf16(Al[kk], Bh[ct][kk], acc, 0, 0, 0);
        }
        const int crow0 = kg * 4;
#pragma unroll
        for (int r = 0; r < 4; r++) {
            const int row = row0 + crow0 + r;
            if (row < kN) P[row * 32 + ct * 16 + rr] = acc[r];
        }
    }
}

// ---------------- edge out: Q = relu(ea)@W13[128:160]; out = Q + P_src + P_dst + b ----------------
__global__ __launch_bounds__(256) void edge_out_kernel(
    const float* __restrict__ ea, const int* __restrict__ ei,
    const float* __restrict__ P,
    const float* __restrict__ intW, const float* __restrict__ intb,
    const float* __restrict__ impW, const float* __restrict__ impb,
    float* __restrict__ out)
{
    constexpr int ROWS = 40;
    __shared__ __align__(16) unsigned short ehi[4][16 * ROWS];
    __shared__ __align__(16) unsigned short elo[4][16 * ROWS];
    const int tid = threadIdx.x;
    const int w = tid >> 6, lane = tid & 63;
    const int e0 = blockIdx.x * 64 + w * 16;
    const int rr = lane & 15, kg = lane >> 4;

    bf16x8s Bh, Bl;
#pragma unroll
    for (int j = 0; j < 8; j++) {
        const int k = 128 + kg * 8 + j;
        float wv;
        if (rr < 12)       wv = intW[k * 12 + rr];
        else if (rr == 12) wv = impW[k];
        else               wv = 0.f;
        const unsigned short hb = f2bf(wv);
        Bh[j] = (short)hb;
        Bl[j] = (short)f2bf(wv - bf2f(hb));
    }

    {
        const int j = lane >> 2, q = lane & 3;
        const float4* src = (const float4*)&ea[(size_t)(e0 + j) * 32 + q * 8];
        const float4 f0 = src[0], f1 = src[1];
        const float fv[8] = {fmaxf(f0.x, 0.f), fmaxf(f0.y, 0.f), fmaxf(f0.z, 0.f), fmaxf(f0.w, 0.f),
                             fmaxf(f1.x, 0.f), fmaxf(f1.y, 0.f), fmaxf(f1.z, 0.f), fmaxf(f1.w, 0.f)};
        unsigned long long ph0 = 0, pl0 = 0, ph1 = 0, pl1 = 0;
#pragma unroll
        for (int t = 0; t < 4; t++) {
            const unsigned short hb = f2bf(fv[t]);
            const unsigned short lb = f2bf(fv[t] - bf2f(hb));
            ph0 |= (unsigned long long)hb << (16 * t);
            pl0 |= (unsigned long long)lb << (16 * t);
        }
#pragma unroll
        for (int t = 0; t < 4; t++) {
            const unsigned short hb = f2bf(fv[4 + t]);
            const unsigned short lb = f2bf(fv[4 + t] - bf2f(hb));
            ph1 |= (unsigned long long)hb << (16 * t);
            pl1 |= (unsigned long long)lb << (16 * t);
        }
        *(unsigned long long*)&ehi[w][j * ROWS + q * 8]     = ph0;
        *(unsigned long long*)&ehi[w][j * ROWS + q * 8 + 4] = ph1;
        *(unsigned long long*)&elo[w][j * ROWS + q * 8]     = pl0;
        *(unsigned long long*)&elo[w][j * ROWS + q * 8 + 4] = pl1;
    }
    __syncthreads();

    const int aoff = rr * ROWS + kg * 8;
    const bf16x8s Ah = *(const bf16x8s*)&ehi[w][aoff];
    const bf16x8s Al = *(const bf16x8s*)&elo[w][aoff];
    f32x4 q = {0.f, 0.f, 0.f, 0.f};
    q = __builtin_amdgcn_mfma_f32_16x16x32_bf16(Ah, Bh, q, 0, 0, 0);
    q = __builtin_amdgcn_mfma_f32_16x16x32_bf16(Ah, Bl, q, 0, 0, 0);
    q = __builtin_amdgcn_mfma_f32_16x16x32_bf16(Al, Bh, q, 0, 0, 0);

    if (rr < 13) {
        const float bv = (rr < 12) ? intb[rr] : impb[0];
#pragma unroll
        for (int r = 0; r < 4; r++) {
            const int e = e0 + kg * 4 + r;
            const int s = ei[e], d = ei[kE + e];
            const float val = q[r] + P[s * 32 + rr] + P[d * 32 + 16 + rr] + bv;
            if (rr < 12) out[(size_t)e * 12 + rr] = val;
            else         out[(size_t)kE * 12 + e] = 1.f / (1.f + __expf(-val));
        }
    }
}

// ---------------- launch ----------------
extern "C" void kernel_launch(void* const* d_in, const int* in_sizes, int n_in,
                              void* d_out, int out_size, void* d_ws, size_t ws_size,
                              hipStream_t stream)
{
    (void)in_sizes; (void)n_in; (void)out_size; (void)ws_size;

    const float* x      = (const float*)d_in[0];
    const int*   ei     = (const int*)d_in[1];
    const float* ea     = (const float*)d_in[2];
    const float* emb_W  = (const float*)d_in[3];
    const float* emb_b  = (const float*)d_in[4];
    const float* g1_Wl  = (const float*)d_in[5];
    const float* g1_bl  = (const float*)d_in[6];
    const float* g1_Wr  = (const float*)d_in[7];
    const float* g1_br  = (const float*)d_in[8];
    const float* g1_We  = (const float*)d_in[9];
    const float* g1_att = (const float*)d_in[10];
    const float* g1_bias= (const float*)d_in[11];
    const float* g2_Wl  = (const float*)d_in[12];
    const float* g2_bl  = (const float*)d_in[13];
    const float* g2_Wr  = (const float*)d_in[14];
    const float* g2_br  = (const float*)d_in[15];
    const float* g2_We  = (const float*)d_in[16];
    const float* g2_att = (const float*)d_in[17];
    const float* g2_bias= (const float*)d_in[18];
    const float* int_W  = (const float*)d_in[19];
    const float* int_b  = (const float*)d_in[20];
    const float* imp_W  = (const float*)d_in[21];
    const float* imp_b  = (const float*)d_in[22];

    char* ws = (char*)d_ws;
    float* eapart  = (float*)(ws + OFF_EAPART);
    float* eamean  = (float*)(ws + OFF_EAMEAN);
    int*   partials= (int*)  (ws + OFF_PART);
    int*   cursor  = (int*)  (ws + OFF_CURSOR);
    int*   csrsrc  = (int*)  (ws + OFF_CSRSRC);
    int*   csreid  = (int*)  (ws + OFF_CSREID);
    int*   csrdst  = (int*)  (ws + OFF_CSRDST);
    float* accbuf  = (float*)(ws + OFF_ACC);
    float* denbuf  = (float*)(ws + OFF_DEN);
    int*   counts  = (int*)  (ws + OFF_COUNTS);
    float* h_a     = (float*)(ws + OFF_HA);
    float* h_b     = (float*)(ws + OFF_HB);
    float* xl      = (float*)(ws + OFF_XL);
    float* xr      = (float*)(ws + OFF_XR);
    unsigned short* tab = (unsigned short*)(ws + OFF_TAB);
    float* P       = accbuf;                  // reuse acc region after finalize2
    float* outp    = (float*)d_out;

    constexpr int NT = (kTaug + 31) / 32;     // 13282 edge tiles
    constexpr int NGB = (kN + 63) / 64;       // 391 row blocks for MFMA gemms

    // zero acc + den + counts (one contiguous memset)
    hipMemsetAsync(ws + OFF_ACC, 0, MEMSET_BYTES, stream);

    // edge_attr mean + all weight-frag tables (2 launches)
    ea_colsum_part<<<1024, 256, 0, stream>>>(ea, eapart);
    ea_colsum_final<<<1, 256, 0, stream>>>(eapart, eamean);
    we_swizzle<<<32, 256, 0, stream>>>(g1_We, g2_We, tab);
    w_tables<<<288, 256, 0, stream>>>(emb_W, g1_Wl, g1_Wr, g2_Wl, g2_Wr, tab);

    // CSR by destination (self-loops included); counts pre-zeroed by memset
    count_edges<<<(kE + 255) / 256, 256, 0, stream>>>(ei, counts);
    scan_part<<<kNBLK, 256, 0, stream>>>(counts, cursor, partials);
    scan_mid<<<1, 128, 0, stream>>>(partials);
    scan_add<<<kNBLK, 256, 0, stream>>>(cursor, partials);
    scatter_kernel<<<(kTpad + 255) / 256, 256, 0, stream>>>(ei, cursor, csrsrc, csreid, csrdst);

    // node embedding (MFMA split-bf16, col-split grid)
    mfma_gemm_bias<128, 64, 2><<<NGB * 2, 256, 0, stream>>>(
        x, tab + T_EMBH, tab + T_EMBL, emb_b, h_a, kN);

    // ---- GAT layer 1 ----
    mfma_gemm_bias2<64, 256, 4><<<NGB * 4, 256, 0, stream>>>(
        h_a, tab + T_L1H, tab + T_L1L, tab + T_R1H, tab + T_R1L,
        g1_bl, g1_br, xl, xr, kN);
    edge_logit_aggr_kernel<<<NT, 256, 0, stream>>>(xl, xr, ea, eamean,
        tab + T_F1H, tab + T_F1L, g1_att, csrsrc, csrdst, csreid, accbuf, denbuf);
    gat_finalize<true><<<kN, 256, 0, stream>>>(accbuf, denbuf, g1_bias, h_b);

    // ---- GAT layer 2 (acc/den re-zeroed by finalize<true>) ----
    mfma_gemm_bias2<64, 256, 4><<<NGB * 4, 256, 0, stream>>>(
        h_b, tab + T_L2H, tab + T_L2L, tab + T_R2H, tab + T_R2L,
        g2_bl, g2_br, xl, xr, kN);
    edge_logit_aggr_kernel<<<NT, 256, 0, stream>>>(xl, xr, ea, eamean,
        tab + T_F2H, tab + T_F2L, g2_att, csrsrc, csrdst, csreid, accbuf, denbuf);
    gat_finalize<false><<<kN, 256, 0, stream>>>(accbuf, denbuf, g2_bias, h_a);

    // ---- edge heads (decomposed) ----
    node_head_kernel<<<(kN + 63) / 64, 256, 0, stream>>>(h_a, int_W, imp_W, P);
    edge_out_kernel<<<kE / 64, 256, 0, stream>>>(ea, ei, P, int_W, int_b, imp_W, imp_b, outp);
}

// Round 16
// 385.601 us; speedup vs baseline: 1.8814x; 1.0161x over previous
//
#include <hip/hip_runtime.h>
#include <math.h>

// Problem constants
constexpr int kN = 25000;
constexpr int kE = 400000;
constexpr int kTaug = kE + kN;        // CSR slots incl self-loops = 425000
constexpr int kTpad = 425024;         // padded to tile boundary (13282*32)
constexpr int kNBLK = (kN + 255) / 256;   // 98 scan blocks

typedef __attribute__((ext_vector_type(8))) short bf16x8s;   // 8 bf16 (4 VGPRs)
typedef __attribute__((ext_vector_type(4))) float f32x4;

__device__ __forceinline__ unsigned short f2bf(float f) {
    unsigned u = __builtin_bit_cast(unsigned, f);
    unsigned r = (u + 0x7FFFu + ((u >> 16) & 1u)) >> 16;     // RNE
    return (unsigned short)r;
}
__device__ __forceinline__ float bf2f(unsigned short h) {
    unsigned u = ((unsigned)h) << 16;
    return __builtin_bit_cast(float, u);
}

// DPP helpers (CTRL must be compile-time constant)
template<int CTRL>
__device__ __forceinline__ float dpp_mov(float x) {
    int yi = __builtin_amdgcn_update_dpp(0, __builtin_bit_cast(int, x), CTRL, 0xF, 0xF, true);
    return __builtin_bit_cast(float, yi);
}
template<int CTRL>
__device__ __forceinline__ float dpp_add(float x) {
    return x + dpp_mov<CTRL>(x);
}

// ---------------- workspace layout (256B aligned) ----------------
constexpr size_t OFF_EAPART = 0;            // 1024*32 f32
constexpr size_t OFF_EAMEAN = 131072;       // 32 f32
constexpr size_t OFF_PART   = 131328;       // 98 i32 (scan partials)
constexpr size_t OFF_CURSOR = 131840;       // N i32
constexpr size_t OFF_CSRSRC = 231936;       // kTpad i32
constexpr size_t OFF_CSREID = 1932032;      // kTpad i32
constexpr size_t OFF_CSRDST = 3632128;      // kTpad i32
constexpr size_t OFF_ACC    = 5332224;      // N*256 f32 (atomic acc; reused as P)
constexpr size_t OFF_DEN    = 30932224;     // N*4 f32
constexpr size_t OFF_COUNTS = 31332224;     // N i32 (inside the memset region)
constexpr size_t MEMSET_BYTES = 31332224 + 100000 - 5332224;   // acc+den+counts
constexpr size_t OFF_HA     = 31432448;     // N*64 f32
constexpr size_t OFF_HB     = 37832448;     // N*64 f32
constexpr size_t OFF_XL     = 44232448;     // N*256 bf16 = 12.8MB (was f32)
constexpr size_t OFF_XR     = 69832448;     // N*256 f32
constexpr size_t OFF_TAB    = 95432448;     // contiguous weight-frag tables (~426KB)
// element (u16) offsets within TAB:
constexpr int T_F1H = 0,      T_F1L = 8192,  T_F2H = 16384, T_F2L = 24576;
constexpr int T_EMBH = 32768, T_EMBL = 49152;
constexpr int T_L1H = 65536,  T_L1L = 81920, T_R1H = 98304, T_R1L = 114688;
constexpr int T_L2H = 131072, T_L2L = 147456, T_R2H = 163840, T_R2L = 180224;

// ---------------- edge_attr column mean ----------------
__global__ __launch_bounds__(256) void ea_colsum_part(const float* __restrict__ ea,
                                                      float* __restrict__ part)
{
    __shared__ float lds[256];
    const int tid = threadIdx.x;
    const int k = tid & 31, g = tid >> 5;
    float acc = 0.f;
    for (int r = blockIdx.x * 8 + g; r < kE; r += gridDim.x * 8)
        acc += ea[(size_t)r * 32 + k];
    lds[tid] = acc; __syncthreads();
    if (tid < 128) lds[tid] += lds[tid + 128]; __syncthreads();
    if (tid < 64)  lds[tid] += lds[tid + 64];  __syncthreads();
    if (tid < 32)  part[blockIdx.x * 32 + k] = lds[tid] + lds[tid + 32];
}

__global__ __launch_bounds__(256) void ea_colsum_final(const float* __restrict__ part,
                                                       float* __restrict__ ea_mean)
{
    __shared__ float lds[256];
    const int tid = threadIdx.x;
    const int k = tid & 31, g = tid >> 5;
    float acc = 0.f;
    for (int p = g; p < 1024; p += 8) acc += part[p * 32 + k];
    lds[tid] = acc; __syncthreads();
    if (tid < 128) lds[tid] += lds[tid + 128]; __syncthreads();
    if (tid < 64)  lds[tid] += lds[tid + 64];  __syncthreads();
    if (tid < 32)  ea_mean[k] = (lds[tid] + lds[tid + 32]) * (1.0f / (float)kE);
}

// ---------------- We -> frag-swizzled bf16 hi/lo (edge_logit tables) ----------------
__global__ __launch_bounds__(256) void we_swizzle(const float* __restrict__ W1,
                                                  const float* __restrict__ W2,
                                                  unsigned short* __restrict__ tab)
{
    const int b = blockIdx.x;                 // 32 blocks: layer*16 + nt*4 + w
    const int layer = b >> 4, nt = (b >> 2) & 3, w = b & 3;
    const float* W = layer ? W2 : W1;
    unsigned short* H = tab + (layer ? T_F2H : T_F1H);
    unsigned short* L = tab + (layer ? T_F2L : T_F1L);
    const int tid = threadIdx.x;
    const int lane = tid & 63, jh = tid >> 6;
    const int c = w * 64 + nt * 16 + (lane & 15);
    const int kbase = (lane >> 4) * 8;
#pragma unroll
    for (int t = 0; t < 2; t++) {
        const int j = jh * 2 + t;
        const float f = W[(kbase + j) * 256 + c];
        const unsigned short hb = f2bf(f);
        const int idx = ((nt * 4 + w) * 64 + lane) * 8 + j;
        H[idx] = hb;
        L[idx] = f2bf(f - bf2f(hb));
    }
}

// ---------------- merged GEMM-weight frag tables (emb + 4 layer weights) ----------------
__global__ __launch_bounds__(256) void w_tables(const float* __restrict__ embW,
                                                const float* __restrict__ wl1,
                                                const float* __restrict__ wr1,
                                                const float* __restrict__ wl2,
                                                const float* __restrict__ wr2,
                                                unsigned short* __restrict__ tab)
{
    const int b = blockIdx.x, tid = threadIdx.x;
    const float* W; int KO, KCH, idx; unsigned short *H, *L;
    if (b < 32) {                 // emb: 4 ctiles x 4 kchunks = 8192 elems
        W = embW; KO = 64; KCH = 4; idx = b * 256 + tid;
        H = tab + T_EMBH; L = tab + T_EMBL;
    } else {                      // 4 tables of 16 ctiles x 2 kchunks = 16384 elems
        const int t = (b - 32) >> 6, r = (b - 32) & 63;
        idx = r * 256 + tid; KO = 256; KCH = 2;
        if      (t == 0) { W = wl1; H = tab + T_L1H; L = tab + T_L1L; }
        else if (t == 1) { W = wr1; H = tab + T_R1H; L = tab + T_R1L; }
        else if (t == 2) { W = wl2; H = tab + T_L2H; L = tab + T_L2L; }
        else             { W = wr2; H = tab + T_R2H; L = tab + T_R2L; }
    }
    const int j = idx & 7;
    const int lane = (idx >> 3) & 63;
    const int t2 = idx >> 9;
    const int ct = t2 / KCH;
    const int c = ct * 16 + (lane & 15);
    const int k = (t2 - ct * KCH) * 32 + (lane >> 4) * 8 + j;
    const float f = W[k * KO + c];
    const unsigned short hb = f2bf(f);
    H[idx] = hb;
    L[idx] = f2bf(f - bf2f(hb));
}

// ---------------- MFMA dense GEMM (single output, fp32 out) ----------------
template<int KI, int KO, int CSPLIT>
__global__ __launch_bounds__(256) void mfma_gemm_bias(
    const float* __restrict__ A,
    const unsigned short* __restrict__ WH, const unsigned short* __restrict__ WL,
    const float* __restrict__ bias, float* __restrict__ out, int M)
{
    constexpr int KCH = KI / 32;
    constexpr int CT  = KO / 16;
    constexpr int CTP = CT / CSPLIT;
    const int tid = threadIdx.x;
    const int w = tid >> 6, lane = tid & 63;
    const int rowblk = blockIdx.x / CSPLIT;
    const int csel   = blockIdx.x % CSPLIT;
    const int row0 = rowblk * 64 + w * 16;
    const int rr = lane & 15, kg = lane >> 4;
    const int arow = min(row0 + rr, M - 1);

    bf16x8s Ah[KCH], Al[KCH];
#pragma unroll
    for (int kk = 0; kk < KCH; kk++) {
        const float4 f0 = *(const float4*)&A[(size_t)arow * KI + kk * 32 + kg * 8];
        const float4 f1 = *(const float4*)&A[(size_t)arow * KI + kk * 32 + kg * 8 + 4];
        const float fv[8] = {f0.x, f0.y, f0.z, f0.w, f1.x, f1.y, f1.z, f1.w};
#pragma unroll
        for (int j = 0; j < 8; j++) {
            const unsigned short hb = f2bf(fv[j]);
            Ah[kk][j] = (short)hb;
            Al[kk][j] = (short)f2bf(fv[j] - bf2f(hb));
        }
    }
    const int rbase = kg * 4;
#pragma unroll
    for (int cti = 0; cti < CTP; cti++) {
        const int ct = csel * CTP + cti;
        f32x4 acc = {0.f, 0.f, 0.f, 0.f};
#pragma unroll
        for (int kk = 0; kk < KCH; kk++) {
            const int bidx = ((ct * KCH + kk) * 64 + lane) * 8;
            const bf16x8s Bh = *(const bf16x8s*)&WH[bidx];
            const bf16x8s Bl = *(const bf16x8s*)&WL[bidx];
            acc = __builtin_amdgcn_mfma_f32_16x16x32_bf16(Ah[kk], Bh, acc, 0, 0, 0);
            acc = __builtin_amdgcn_mfma_f32_16x16x32_bf16(Ah[kk], Bl, acc, 0, 0, 0);
            acc = __builtin_amdgcn_mfma_f32_16x16x32_bf16(Al[kk], Bh, acc, 0, 0, 0);
        }
        const float bv = bias[ct * 16 + rr];
#pragma unroll
        for (int r = 0; r < 4; r++) {
            const int row = row0 + rbase + r;
            if (row < M) out[(size_t)row * KO + ct * 16 + rr] = acc[r] + bv;
        }
    }
}

// ---------------- MFMA dense GEMM, dual output: outA = bf16 (xl), outB = fp32 (xr) ----------------
template<int KI, int KO, int CSPLIT>
__global__ __launch_bounds__(256) void mfma_gemm_bias2(
    const float* __restrict__ A,
    const unsigned short* __restrict__ WHa, const unsigned short* __restrict__ WLa,
    const unsigned short* __restrict__ WHb, const unsigned short* __restrict__ WLb,
    const float* __restrict__ biasA, const float* __restrict__ biasB,
    unsigned short* __restrict__ outA, float* __restrict__ outB, int M)
{
    constexpr int KCH = KI / 32;
    constexpr int CT  = KO / 16;
    constexpr int CTP = CT / CSPLIT;
    const int tid = threadIdx.x;
    const int w = tid >> 6, lane = tid & 63;
    const int rowblk = blockIdx.x / CSPLIT;
    const int csel   = blockIdx.x % CSPLIT;
    const int row0 = rowblk * 64 + w * 16;
    const int rr = lane & 15, kg = lane >> 4;
    const int arow = min(row0 + rr, M - 1);

    bf16x8s Ah[KCH], Al[KCH];
#pragma unroll
    for (int kk = 0; kk < KCH; kk++) {
        const float4 f0 = *(const float4*)&A[(size_t)arow * KI + kk * 32 + kg * 8];
        const float4 f1 = *(const float4*)&A[(size_t)arow * KI + kk * 32 + kg * 8 + 4];
        const float fv[8] = {f0.x, f0.y, f0.z, f0.w, f1.x, f1.y, f1.z, f1.w};
#pragma unroll
        for (int j = 0; j < 8; j++) {
            const unsigned short hb = f2bf(fv[j]);
            Ah[kk][j] = (short)hb;
            Al[kk][j] = (short)f2bf(fv[j] - bf2f(hb));
        }
    }
    const int rbase = kg * 4;
#pragma unroll
    for (int cti = 0; cti < CTP; cti++) {
        const int ct = csel * CTP + cti;
        // A output (xl, stored bf16)
        {
            f32x4 acc = {0.f, 0.f, 0.f, 0.f};
#pragma unroll
            for (int kk = 0; kk < KCH; kk++) {
                const int bidx = ((ct * KCH + kk) * 64 + lane) * 8;
                const bf16x8s Bh = *(const bf16x8s*)&WHa[bidx];
                const bf16x8s Bl = *(const bf16x8s*)&WLa[bidx];
                acc = __builtin_amdgcn_mfma_f32_16x16x32_bf16(Ah[kk], Bh, acc, 0, 0, 0);
                acc = __builtin_amdgcn_mfma_f32_16x16x32_bf16(Ah[kk], Bl, acc, 0, 0, 0);
                acc = __builtin_amdgcn_mfma_f32_16x16x32_bf16(Al[kk], Bh, acc, 0, 0, 0);
            }
            const float bv = biasA[ct * 16 + rr];
#pragma unroll
            for (int r = 0; r < 4; r++) {
                const int row = row0 + rbase + r;
                if (row < M) outA[(size_t)row * KO + ct * 16 + rr] = f2bf(acc[r] + bv);
            }
        }
        // B output (xr, fp32)
        {
            f32x4 acc = {0.f, 0.f, 0.f, 0.f};
#pragma unroll
            for (int kk = 0; kk < KCH; kk++) {
                const int bidx = ((ct * KCH + kk) * 64 + lane) * 8;
                const bf16x8s Bh = *(const bf16x8s*)&WHb[bidx];
                const bf16x8s Bl = *(const bf16x8s*)&WLb[bidx];
                acc = __builtin_amdgcn_mfma_f32_16x16x32_bf16(Ah[kk], Bh, acc, 0, 0, 0);
                acc = __builtin_amdgcn_mfma_f32_16x16x32_bf16(Ah[kk], Bl, acc, 0, 0, 0);
                acc = __builtin_amdgcn_mfma_f32_16x16x32_bf16(Al[kk], Bh, acc, 0, 0, 0);
            }
            const float bv = biasB[ct * 16 + rr];
#pragma unroll
            for (int r = 0; r < 4; r++) {
                const int row = row0 + rbase + r;
                if (row < M) outB[(size_t)row * KO + ct * 16 + rr] = acc[r] + bv;
            }
        }
    }
}

// ---------------- CSR build ----------------
__global__ __launch_bounds__(256) void count_edges(const int* __restrict__ ei,
                                                   int* __restrict__ counts)
{
    int e = blockIdx.x * 256 + threadIdx.x;
    if (e < kE) atomicAdd(&counts[ei[kE + e]], 1);
}

// 3-phase parallel scan: counts(+1 self-loop) -> exclusive prefix in cursor
__global__ __launch_bounds__(256) void scan_part(const int* __restrict__ counts,
                                                 int* __restrict__ cursor,
                                                 int* __restrict__ partials)
{
    __shared__ int lds[256];
    const int tid = threadIdx.x;
    const int i = blockIdx.x * 256 + tid;
    const int v = (i < kN) ? counts[i] + 1 : 0;   // +1 = self-loop slot
    lds[tid] = v; __syncthreads();
    for (int d = 1; d < 256; d <<= 1) {
        int t = (tid >= d) ? lds[tid - d] : 0;
        __syncthreads();
        lds[tid] += t;
        __syncthreads();
    }
    if (i < kN) cursor[i] = lds[tid] - v;          // block-local exclusive
    if (tid == 255) partials[blockIdx.x] = lds[255];
}

__global__ __launch_bounds__(128) void scan_mid(int* __restrict__ partials)
{
    __shared__ int lds[128];
    const int tid = threadIdx.x;
    const int v = (tid < kNBLK) ? partials[tid] : 0;
    lds[tid] = v; __syncthreads();
    for (int d = 1; d < 128; d <<= 1) {
        int t = (tid >= d) ? lds[tid - d] : 0;
        __syncthreads();
        lds[tid] += t;
        __syncthreads();
    }
    if (tid < kNBLK) partials[tid] = lds[tid] - v; // exclusive block prefix
}

__global__ __launch_bounds__(256) void scan_add(int* __restrict__ cursor,
                                                const int* __restrict__ partials)
{
    const int i = blockIdx.x * 256 + threadIdx.x;
    if (i < kN) cursor[i] += partials[blockIdx.x];
}

// scatter + pad slots [kTaug, kTpad) with inert entries
__global__ __launch_bounds__(256) void scatter_kernel(const int* __restrict__ ei,
                                                      int* __restrict__ cursor,
                                                      int* __restrict__ csr_src,
                                                      int* __restrict__ csr_eid,
                                                      int* __restrict__ csr_dst)
{
    int gid = blockIdx.x * 256 + threadIdx.x;
    if (gid < kE) {
        int s = ei[gid];
        int d = ei[kE + gid];
        int p = atomicAdd(&cursor[d], 1);
        csr_src[p] = s;
        csr_eid[p] = gid;
        csr_dst[p] = d;
    } else if (gid < kTaug) {
        int n = gid - kE;
        int p = atomicAdd(&cursor[n], 1);
        csr_src[p] = n;
        csr_eid[p] = kE;   // sentinel: self-loop
        csr_dst[p] = n;
    } else if (gid < kTpad) {
        csr_src[gid] = 0;
        csr_eid[gid] = kE;       // sentinel (reads eamean; contribution masked to 0)
        csr_dst[gid] = kN - 1;
    }
}

// ---------------- Fused pass: per-edge attention + per-node aggregation ----------------
// R15: xl stored/gathered as bf16 — halves the random-gather fetch traffic
// (the kernel's dominant cost per R14 counters: FETCH 234MB vs 107MB inputs).
// xr stays fp32 (dst-sequential, L2-friendly). Structure otherwise = R14.
__global__ __launch_bounds__(256) void edge_logit_aggr_kernel(
    const unsigned short* __restrict__ xl, const float* __restrict__ xr,
    const float* __restrict__ ea, const float* __restrict__ eamean,
    const unsigned short* __restrict__ fragh, const unsigned short* __restrict__ fragl,
    const float* __restrict__ att,
    const int* __restrict__ csr_src, const int* __restrict__ csr_dst,
    const int* __restrict__ csr_eid,
    float* __restrict__ accbuf, float* __restrict__ denbuf)
{
    constexpr int ROWS = 40;                       // padded ea row (shorts), 80B
    constexpr int EPP  = 257;                      // padded ep row (floats), 16-edge half
    __shared__ __align__(16) unsigned short ea_hi[32 * ROWS];
    __shared__ __align__(16) unsigned short ea_lo[32 * ROWS];
    __shared__ __align__(16) float ep_lds[16 * EPP];
    __shared__ __align__(16) float lds_pe[4][16];
    const int tid  = threadIdx.x;
    const int w    = tid >> 6;
    const int lane = tid & 63;
    const int b0   = blockIdx.x * 32;

    // B fragments: 8 coalesced b128 loads from pre-swizzled tables
    bf16x8s bh[4], bl[4];
#pragma unroll
    for (int nt = 0; nt < 4; nt++) {
        const int idx = ((nt * 4 + w) * 64 + lane) * 8;
        bh[nt] = *(const bf16x8s*)&fragh[idx];
        bl[nt] = *(const bf16x8s*)&fragl[idx];
    }
    const float att_r = att[tid];
    const int aoff  = (lane & 15) * ROWS + (lane >> 4) * 8;
    const int cbase = w * 64 + (lane & 15);
    const int rbase = (lane >> 4) * 4;

    // stage ea rows (csr padded to kTpad: no clamp needed)
    {
        const int j = tid >> 3, q = tid & 7;
        const int eid = csr_eid[b0 + j];
        const float4* srcp = (eid < kE) ? (const float4*)(ea + (size_t)eid * 32)
                                        : (const float4*)eamean;
        const float4 f = srcp[q];
        const unsigned short h0 = f2bf(f.x), h1 = f2bf(f.y),
                             h2 = f2bf(f.z), h3 = f2bf(f.w);
        const unsigned short g0 = f2bf(f.x - bf2f(h0)), g1 = f2bf(f.y - bf2f(h1)),
                             g2 = f2bf(f.z - bf2f(h2)), g3 = f2bf(f.w - bf2f(h3));
        const unsigned long long ph =
            (unsigned long long)h0 | ((unsigned long long)h1 << 16) |
            ((unsigned long long)h2 << 32) | ((unsigned long long)h3 << 48);
        const unsigned long long pl =
            (unsigned long long)g0 | ((unsigned long long)g1 << 16) |
            ((unsigned long long)g2 << 32) | ((unsigned long long)g3 << 48);
        *(unsigned long long*)&ea_hi[j * ROWS + q * 4] = ph;
        *(unsigned long long*)&ea_lo[j * ROWS + q * 4] = pl;
    }
    __syncthreads();   // the ONLY cross-wave dependency: staging -> MFMA A-reads

    int   cur_dst = csr_dst[b0];                   // wave-uniform scalar
    float den_p = 0.f, acc_p = 0.f;

#pragma unroll
    for (int half = 0; half < 2; half++) {
        const bf16x8s ah = *(const bf16x8s*)&ea_hi[half * 16 * ROWS + aoff];
        const bf16x8s al = *(const bf16x8s*)&ea_lo[half * 16 * ROWS + aoff];
#pragma unroll
        for (int nt = 0; nt < 4; nt++) {
            f32x4 a = {0.f, 0.f, 0.f, 0.f};
            a = __builtin_amdgcn_mfma_f32_16x16x32_bf16(ah, bh[nt], a, 0, 0, 0);
            a = __builtin_amdgcn_mfma_f32_16x16x32_bf16(ah, bl[nt], a, 0, 0, 0);
            a = __builtin_amdgcn_mfma_f32_16x16x32_bf16(al, bh[nt], a, 0, 0, 0);
            const int cc = cbase + nt * 16;
#pragma unroll
            for (int r = 0; r < 4; r++)
                ep_lds[(rbase + r) * EPP + cc] = a[r];
        }
        // no barrier: wave w reads only the ep_lds columns it wrote

        // ---- both 8-edge batches of this half, interleaved ----
        const int e0g = b0 + half * 16;
        int sv_s[16], dv_s[16];
#pragma unroll
        for (int u = 0; u < 16; u++) {
            sv_s[u] = csr_src[e0g + u];            // uniform -> scalar pipe
            dv_s[u] = csr_dst[e0g + u];
        }
        float xls[16], c[16];
#pragma unroll
        for (int u = 0; u < 16; u++) {
            const unsigned short* __restrict__ xlp = xl + (size_t)sv_s[u] * 256;
            xls[u] = bf2f(xlp[tid]);               // 16 bf16 gathers in flight
        }
#pragma unroll
        for (int u = 0; u < 16; u++) {
            const float* __restrict__ xrp = xr + (size_t)dv_s[u] * 256;
            const float xrr = xrp[tid];
            float v = xls[u] + xrr + ep_lds[u * EPP + tid];
            v = fmaxf(v, 0.2f * v);                // leaky_relu 0.2
            c[u] = att_r * v;
        }

        // two lockstep multi-value exchange reduces (groups: c[0..7], c[8..15])
        float n[8];
        {   const bool s = lane & 1;
#pragma unroll
            for (int p = 0; p < 8; p++) {
                const float x0 = s ? c[2 * p + 1] : c[2 * p];
                const float x1 = s ? c[2 * p] : c[2 * p + 1];
                n[p] = x0 + dpp_mov<0xB1>(x1);
            }
        }
        float m[4];
        {   const bool s = lane & 2;
#pragma unroll
            for (int p = 0; p < 4; p++) {
                const float x0 = s ? n[2 * p + 1] : n[2 * p];
                const float x1 = s ? n[2 * p] : n[2 * p + 1];
                m[p] = x0 + dpp_mov<0x4E>(x1);
            }
        }
        float r0, r1;
        {   const bool s = lane & 32;
            const float o0 = __shfl_xor(s ? m[0] : m[1], 32);
            r0 = (s ? m[1] : m[0]) + o0;
            const float o1 = __shfl_xor(s ? m[2] : m[3], 32);
            r1 = (s ? m[3] : m[2]) + o1;
        }
        r0 = dpp_add<0x124>(r0);  r1 = dpp_add<0x124>(r1);   // row_ror:4
        r0 = dpp_add<0x128>(r0);  r1 = dpp_add<0x128>(r1);   // row_ror:8
        r0 += __shfl_xor(r0, 16); r1 += __shfl_xor(r1, 16);
        // lane holds logits for edges u0=(l&3)|((l>>3)&4) and 8+u0
        const float pe0 = __expf(r0);
        const float pe1 = __expf(r1);

        // pe broadcast via LDS (lds_pe[w] is wave-private: no barrier)
        if ((lane & 0x1C) == 0) {
            const int slot = (lane & 3) | ((lane >> 3) & 4);
            lds_pe[w][slot]     = pe0;
            lds_pe[w][8 + slot] = pe1;
        }
        float pu[16];
        {
            const float4 p0 = *(const float4*)&lds_pe[w][0];
            const float4 p1 = *(const float4*)&lds_pe[w][4];
            const float4 p2 = *(const float4*)&lds_pe[w][8];
            const float4 p3 = *(const float4*)&lds_pe[w][12];
            pu[0]=p0.x; pu[1]=p0.y; pu[2]=p0.z; pu[3]=p0.w;
            pu[4]=p1.x; pu[5]=p1.y; pu[6]=p1.z; pu[7]=p1.w;
            pu[8]=p2.x; pu[9]=p2.y; pu[10]=p2.z; pu[11]=p2.w;
            pu[12]=p3.x; pu[13]=p3.y; pu[14]=p3.z; pu[15]=p3.w;
        }
        if (e0g + 16 > kTaug) {                    // tail: zero padded edges
#pragma unroll
            for (int u = 0; u < 16; u++)
                if (e0g + u >= kTaug) pu[u] = 0.f;
        }
        // single ordered segmented accumulate over 16 edges (dv_s scalar)
#pragma unroll
        for (int u = 0; u < 16; u++) {
            if (dv_s[u] != cur_dst) {
                atomicAdd(&accbuf[(size_t)cur_dst * 256 + tid], acc_p);
                if (lane == 0) atomicAdd(&denbuf[cur_dst * 4 + w], den_p);
                acc_p = 0.f; den_p = 0.f; cur_dst = dv_s[u];
            }
            acc_p += pu[u] * xls[u];
            den_p += pu[u];
        }
        // no barrier: ep_lds rewrite next half is by the same wave
    }

    atomicAdd(&accbuf[(size_t)cur_dst * 256 + tid], acc_p);
    if (lane == 0) atomicAdd(&denbuf[cur_dst * 4 + w], den_p);
}

// ---------------- finalize: h = relu(mean_h(acc/den) + bias); optionally re-zero acc/den ----------------
template<bool ZERO>
__global__ __launch_bounds__(256) void gat_finalize(
    float* __restrict__ accbuf, float* __restrict__ denbuf,
    const float* __restrict__ gbias, float* __restrict__ h_out)
{
    __shared__ float red[256];
    const int tid = threadIdx.x;
    const int n = blockIdx.x;
    red[tid] = accbuf[(size_t)n * 256 + tid] / denbuf[n * 4 + (tid >> 6)];
    if (ZERO) {
        accbuf[(size_t)n * 256 + tid] = 0.f;
        if ((tid & 63) == 0) denbuf[n * 4 + (tid >> 6)] = 0.f;
    }
    __syncthreads();
    if (tid < 64) {
        float sres = red[tid] + red[tid + 64] + red[tid + 128] + red[tid + 192];
        h_out[n * 64 + tid] = fmaxf(0.25f * sres + gbias[tid], 0.f);
    }
}

// ---------------- node head: P[n][0:16]=h@W13[0:64], P[n][16:32]=h@W13[64:128] ----------------
__global__ __launch_bounds__(256) void node_head_kernel(
    const float* __restrict__ h, const float* __restrict__ intW,
    const float* __restrict__ impW, float* __restrict__ P)
{
    const int tid = threadIdx.x;
    const int w = tid >> 6, lane = tid & 63;
    const int row0 = blockIdx.x * 64 + w * 16;
    const int rr = lane & 15;
    const int kg = lane >> 4;

    bf16x8s Bh[2][2], Bl[2][2];
#pragma unroll
    for (int ct = 0; ct < 2; ct++) {
#pragma unroll
        for (int kk = 0; kk < 2; kk++) {
            const int kbase = ct * 64 + kk * 32 + kg * 8;
#pragma unroll
            for (int j = 0; j < 8; j++) {
                const int k = kbase + j;
                float wv;
                if (rr < 12)       wv = intW[k * 12 + rr];
                else if (rr == 12) wv = impW[k];
                else               wv = 0.f;
                const unsigned short hb = f2bf(wv);
                Bh[ct][kk][j] = (short)hb;
                Bl[ct][kk][j] = (short)f2bf(wv - bf2f(hb));
            }
        }
    }

    const int arow = min(row0 + rr, kN - 1);
    bf16x8s Ah[2], Al[2];
#pragma unroll
    for (int kk = 0; kk < 2; kk++) {
        const float4 f0 = *(const float4*)&h[arow * 64 + kk * 32 + kg * 8];
        const float4 f1 = *(const float4*)&h[arow * 64 + kk * 32 + kg * 8 + 4];
        const float fv[8] = {f0.x, f0.y, f0.z, f0.w, f1.x, f1.y, f1.z, f1.w};
#pragma unroll
        for (int j = 0; j < 8; j++) {
            const unsigned short hb = f2bf(fv[j]);
            Ah[kk][j] = (short)hb;
            Al[kk][j] = (short)f2bf(fv[j] - bf2f(hb));
        }
    }

#pragma unroll
    for (int ct = 0; ct < 2; ct++) {
        f32x4 acc = {0.f, 0.f, 0.f, 0.f};
#pragma unroll
        for (int kk = 0; kk < 2; kk++) {
            acc = __builtin_amdgcn_mfma_f32_16x16x32_bf16(Ah[kk], Bh[ct][kk], acc, 0, 0, 0);
            acc = __builtin_amdgcn_mfma_f32_16x16x32_bf16(Ah[kk], Bl[ct][kk], acc, 0, 0, 0);
            acc = __builtin_amdgcn_mfma_f32_16x16x32_bf16(Al[kk], Bh[ct][kk], acc, 0, 0, 0);
        }
        const int crow0 = kg * 4;
#pragma unroll
        for (int r = 0; r < 4; r++) {
            const int row = row0 + crow0 + r;
            if (row < kN) P[row * 32 + ct * 16 + rr] = acc[r];
        }
    }
}

// ---------------- edge out: Q = relu(ea)@W13[128:160]; out = Q + P_src + P_dst + b ----------------
__global__ __launch_bounds__(256) void edge_out_kernel(
    const float* __restrict__ ea, const int* __restrict__ ei,
    const float* __restrict__ P,
    const float* __restrict__ intW, const float* __restrict__ intb,
    const float* __restrict__ impW, const float* __restrict__ impb,
    float* __restrict__ out)
{
    constexpr int ROWS = 40;
    __shared__ __align__(16) unsigned short ehi[4][16 * ROWS];
    __shared__ __align__(16) unsigned short elo[4][16 * ROWS];
    const int tid = threadIdx.x;
    const int w = tid >> 6, lane = tid & 63;
    const int e0 = blockIdx.x * 64 + w * 16;
    const int rr = lane & 15, kg = lane >> 4;

    bf16x8s Bh, Bl;
#pragma unroll
    for (int j = 0; j < 8; j++) {
        const int k = 128 + kg * 8 + j;
        float wv;
        if (rr < 12)       wv = intW[k * 12 + rr];
        else if (rr == 12) wv = impW[k];
        else               wv = 0.f;
        const unsigned short hb = f2bf(wv);
        Bh[j] = (short)hb;
        Bl[j] = (short)f2bf(wv - bf2f(hb));
    }

    {
        const int j = lane >> 2, q = lane & 3;
        const float4* src = (const float4*)&ea[(size_t)(e0 + j) * 32 + q * 8];
        const float4 f0 = src[0], f1 = src[1];
        const float fv[8] = {fmaxf(f0.x, 0.f), fmaxf(f0.y, 0.f), fmaxf(f0.z, 0.f), fmaxf(f0.w, 0.f),
                             fmaxf(f1.x, 0.f), fmaxf(f1.y, 0.f), fmaxf(f1.z, 0.f), fmaxf(f1.w, 0.f)};
        unsigned long long ph0 = 0, pl0 = 0, ph1 = 0, pl1 = 0;
#pragma unroll
        for (int t = 0; t < 4; t++) {
            const unsigned short hb = f2bf(fv[t]);
            const unsigned short lb = f2bf(fv[t] - bf2f(hb));
            ph0 |= (unsigned long long)hb << (16 * t);
            pl0 |= (unsigned long long)lb << (16 * t);
        }
#pragma unroll
        for (int t = 0; t < 4; t++) {
            const unsigned short hb = f2bf(fv[4 + t]);
            const unsigned short lb = f2bf(fv[4 + t] - bf2f(hb));
            ph1 |= (unsigned long long)hb << (16 * t);
            pl1 |= (unsigned long long)lb << (16 * t);
        }
        *(unsigned long long*)&ehi[w][j * ROWS + q * 8]     = ph0;
        *(unsigned long long*)&ehi[w][j * ROWS + q * 8 + 4] = ph1;
        *(unsigned long long*)&elo[w][j * ROWS + q * 8]     = pl0;
        *(unsigned long long*)&elo[w][j * ROWS + q * 8 + 4] = pl1;
    }
    __syncthreads();

    const int aoff = rr * ROWS + kg * 8;
    const bf16x8s Ah = *(const bf16x8s*)&ehi[w][aoff];
    const bf16x8s Al = *(const bf16x8s*)&elo[w][aoff];
    f32x4 q = {0.f, 0.f, 0.f, 0.f};
    q = __builtin_amdgcn_mfma_f32_16x16x32_bf16(Ah, Bh, q, 0, 0, 0);
    q = __builtin_amdgcn_mfma_f32_16x16x32_bf16(Ah, Bl, q, 0, 0, 0);
    q = __builtin_amdgcn_mfma_f32_16x16x32_bf16(Al, Bh, q, 0, 0, 0);

    if (rr < 13) {
        const float bv = (rr < 12) ? intb[rr] : impb[0];
#pragma unroll
        for (int r = 0; r < 4; r++) {
            const int e = e0 + kg * 4 + r;
            const int s = ei[e], d = ei[kE + e];
            const float val = q[r] + P[s * 32 + rr] + P[d * 32 + 16 + rr] + bv;
            if (rr < 12) out[(size_t)e * 12 + rr] = val;
            else         out[(size_t)kE * 12 + e] = 1.f / (1.f + __expf(-val));
        }
    }
}

// ---------------- launch ----------------
extern "C" void kernel_launch(void* const* d_in, const int* in_sizes, int n_in,
                              void* d_out, int out_size, void* d_ws, size_t ws_size,
                              hipStream_t stream)
{
    (void)in_sizes; (void)n_in; (void)out_size; (void)ws_size;

    const float* x      = (const float*)d_in[0];
    const int*   ei     = (const int*)d_in[1];
    const float* ea     = (const float*)d_in[2];
    const float* emb_W  = (const float*)d_in[3];
    const float* emb_b  = (const float*)d_in[4];
    const float* g1_Wl  = (const float*)d_in[5];
    const float* g1_bl  = (const float*)d_in[6];
    const float* g1_Wr  = (const float*)d_in[7];
    const float* g1_br  = (const float*)d_in[8];
    const float* g1_We  = (const float*)d_in[9];
    const float* g1_att = (const float*)d_in[10];
    const float* g1_bias= (const float*)d_in[11];
    const float* g2_Wl  = (const float*)d_in[12];
    const float* g2_bl  = (const float*)d_in[13];
    const float* g2_Wr  = (const float*)d_in[14];
    const float* g2_br  = (const float*)d_in[15];
    const float* g2_We  = (const float*)d_in[16];
    const float* g2_att = (const float*)d_in[17];
    const float* g2_bias= (const float*)d_in[18];
    const float* int_W  = (const float*)d_in[19];
    const float* int_b  = (const float*)d_in[20];
    const float* imp_W  = (const float*)d_in[21];
    const float* imp_b  = (const float*)d_in[22];

    char* ws = (char*)d_ws;
    float* eapart  = (float*)(ws + OFF_EAPART);
    float* eamean  = (float*)(ws + OFF_EAMEAN);
    int*   partials= (int*)  (ws + OFF_PART);
    int*   cursor  = (int*)  (ws + OFF_CURSOR);
    int*   csrsrc  = (int*)  (ws + OFF_CSRSRC);
    int*   csreid  = (int*)  (ws + OFF_CSREID);
    int*   csrdst  = (int*)  (ws + OFF_CSRDST);
    float* accbuf  = (float*)(ws + OFF_ACC);
    float* denbuf  = (float*)(ws + OFF_DEN);
    int*   counts  = (int*)  (ws + OFF_COUNTS);
    float* h_a     = (float*)(ws + OFF_HA);
    float* h_b     = (float*)(ws + OFF_HB);
    unsigned short* xl = (unsigned short*)(ws + OFF_XL);
    float* xr      = (float*)(ws + OFF_XR);
    unsigned short* tab = (unsigned short*)(ws + OFF_TAB);
    float* P       = accbuf;                  // reuse acc region after finalize2
    float* outp    = (float*)d_out;

    constexpr int NT = (kTaug + 31) / 32;     // 13282 edge tiles
    constexpr int NGB = (kN + 63) / 64;       // 391 row blocks for MFMA gemms

    // zero acc + den + counts (one contiguous memset)
    hipMemsetAsync(ws + OFF_ACC, 0, MEMSET_BYTES, stream);

    // edge_attr mean + all weight-frag tables (2 launches)
    ea_colsum_part<<<1024, 256, 0, stream>>>(ea, eapart);
    ea_colsum_final<<<1, 256, 0, stream>>>(eapart, eamean);
    we_swizzle<<<32, 256, 0, stream>>>(g1_We, g2_We, tab);
    w_tables<<<288, 256, 0, stream>>>(emb_W, g1_Wl, g1_Wr, g2_Wl, g2_Wr, tab);

    // CSR by destination (self-loops included); counts pre-zeroed by memset
    count_edges<<<(kE + 255) / 256, 256, 0, stream>>>(ei, counts);
    scan_part<<<kNBLK, 256, 0, stream>>>(counts, cursor, partials);
    scan_mid<<<1, 128, 0, stream>>>(partials);
    scan_add<<<kNBLK, 256, 0, stream>>>(cursor, partials);
    scatter_kernel<<<(kTpad + 255) / 256, 256, 0, stream>>>(ei, cursor, csrsrc, csreid, csrdst);

    // node embedding (MFMA split-bf16, col-split grid)
    mfma_gemm_bias<128, 64, 2><<<NGB * 2, 256, 0, stream>>>(
        x, tab + T_EMBH, tab + T_EMBL, emb_b, h_a, kN);

    // ---- GAT layer 1 ----
    mfma_gemm_bias2<64, 256, 4><<<NGB * 4, 256, 0, stream>>>(
        h_a, tab + T_L1H, tab + T_L1L, tab + T_R1H, tab + T_R1L,
        g1_bl, g1_br, xl, xr, kN);
    edge_logit_aggr_kernel<<<NT, 256, 0, stream>>>(xl, xr, ea, eamean,
        tab + T_F1H, tab + T_F1L, g1_att, csrsrc, csrdst, csreid, accbuf, denbuf);
    gat_finalize<true><<<kN, 256, 0, stream>>>(accbuf, denbuf, g1_bias, h_b);

    // ---- GAT layer 2 (acc/den re-zeroed by finalize<true>) ----
    mfma_gemm_bias2<64, 256, 4><<<NGB * 4, 256, 0, stream>>>(
        h_b, tab + T_L2H, tab + T_L2L, tab + T_R2H, tab + T_R2L,
        g2_bl, g2_br, xl, xr, kN);
    edge_logit_aggr_kernel<<<NT, 256, 0, stream>>>(xl, xr, ea, eamean,
        tab + T_F2H, tab + T_F2L, g2_att, csrsrc, csrdst, csreid, accbuf, denbuf);
    gat_finalize<false><<<kN, 256, 0, stream>>>(accbuf, denbuf, g2_bias, h_a);

    // ---- edge heads (decomposed) ----
    node_head_kernel<<<(kN + 63) / 64, 256, 0, stream>>>(h_a, int_W, imp_W, P);
    edge_out_kernel<<<kE / 64, 256, 0, stream>>>(ea, ei, P, int_W, int_b, imp_W, imp_b, outp);
}